// Round 1
// baseline (958.764 us; speedup 1.0000x reference)
//
#include <hip/hip_runtime.h>
#include <math.h>

// Problem constants
#define NN 20000          // nodes
#define FF 128            // features
#define FF2 256           // 2*F
#define TT 4              // edge types
#define NE 640000         // edges
#define NSEG (NN*TT)      // 80000 composite segments
#define EPSBN 1e-5f

__device__ __forceinline__ float sigf(float x){ return 1.0f/(1.0f+expf(-x)); }

// ---------------- zero fill ----------------
__global__ void k_zero(float* __restrict__ p, int n){
  int i = blockIdx.x*blockDim.x + threadIdx.x;
  if(i < n) p[i] = 0.0f;
}

// ---------------- oscillator LUT ----------------
__global__ void k_osc(const float* __restrict__ x, const float* __restrict__ tbl,
                      float* __restrict__ h, int total){
  int i = blockIdx.x*blockDim.x + threadIdx.x;
  if(i >= total) return;
  float xv = x[i];
  float xi = (xv < -0.5f || xv > 0.5f) ? 0.5001f : xv;
  int idx = (int)floorf((xi + 0.5f) * 10000.0f);   // add then mul, matches jnp fp32
  float v = tbl[idx];
  h[i] = (v == 0.0f) ? sigf(xv) : v;
}

// ---------------- LSTM (len-1 seq, zero state) ----------------
// gates = h @ w_ih^T + b_ih + b_hh ; c = sig(i)*tanh(g); h = sig(o)*tanh(c)
__global__ void k_lstm(const float* __restrict__ hin, const float* __restrict__ w_ih,
                       const float* __restrict__ b_ih, const float* __restrict__ b_hh,
                       float* __restrict__ h1){
  const int NPB = 8;
  __shared__ __align__(16) float sIn[NPB][FF];
  __shared__ float sG[NPB][4*FF];
  int n0 = blockIdx.x * NPB;
  int t = threadIdx.x;   // 0..511 -> gate row
  for(int i = t; i < NPB*FF; i += 512){
    int nn = i >> 7, c = i & 127;
    sIn[nn][c] = hin[(n0+nn)*FF + c];
  }
  __syncthreads();
  float acc[NPB];
  float bias = b_ih[t] + b_hh[t];
  #pragma unroll
  for(int nn=0; nn<NPB; ++nn) acc[nn] = bias;
  const float* wrow = w_ih + t*FF;
  for(int c=0; c<FF; c+=4){
    float4 w4 = *(const float4*)(wrow + c);
    #pragma unroll
    for(int nn=0; nn<NPB; ++nn){
      float4 s4 = *(const float4*)(&sIn[nn][c]);
      acc[nn] += w4.x*s4.x + w4.y*s4.y + w4.z*s4.z + w4.w*s4.w;
    }
  }
  #pragma unroll
  for(int nn=0; nn<NPB; ++nn) sG[nn][t] = acc[nn];
  __syncthreads();
  for(int i = t; i < NPB*FF; i += 512){
    int nn = i >> 7, j = i & 127;
    float ig = sG[nn][j];
    float gg = sG[nn][2*FF + j];
    float og = sG[nn][3*FF + j];
    float c  = sigf(ig) * tanhf(gg);
    float hv = sigf(og) * tanhf(c);
    h1[(n0+nn)*FF + j] = hv;
  }
}

// ---------------- CSR build over seg = dst*T + etype ----------------
__global__ void k_count(const int* __restrict__ dst, const int* __restrict__ et,
                        int* __restrict__ counts){
  int e = blockIdx.x*blockDim.x + threadIdx.x;
  if(e >= NE) return;
  int seg = dst[e]*TT + et[e];
  atomicAdd(&counts[seg], 1);
}

__global__ void k_scan_block(const int* __restrict__ in, int* __restrict__ out,
                             int* __restrict__ bsums, int n){
  __shared__ int s[256];
  int i = blockIdx.x*256 + threadIdx.x;
  int v = (i < n) ? in[i] : 0;
  s[threadIdx.x] = v; __syncthreads();
  for(int off=1; off<256; off<<=1){
    int add = (threadIdx.x >= off) ? s[threadIdx.x - off] : 0;
    __syncthreads();
    s[threadIdx.x] += add;
    __syncthreads();
  }
  if(i < n) out[i] = s[threadIdx.x];
  if(threadIdx.x == 255) bsums[blockIdx.x] = s[255];
}

__global__ void k_scan_bsums(int* __restrict__ bsums, int nb){
  __shared__ int s[512];
  int v = (threadIdx.x < nb) ? bsums[threadIdx.x] : 0;
  s[threadIdx.x] = v; __syncthreads();
  for(int off=1; off<512; off<<=1){
    int add = (threadIdx.x >= off) ? s[threadIdx.x - off] : 0;
    __syncthreads();
    s[threadIdx.x] += add;
    __syncthreads();
  }
  if(threadIdx.x < nb) bsums[threadIdx.x] = s[threadIdx.x];
}

__global__ void k_scan_add(int* __restrict__ out, const int* __restrict__ bsums, int n){
  int i = blockIdx.x*256 + threadIdx.x;
  if(i >= n || blockIdx.x == 0) return;
  out[i] += bsums[blockIdx.x - 1];
}

__global__ void k_scatter(const int* __restrict__ dst, const int* __restrict__ et,
                          const int* __restrict__ counts, const int* __restrict__ incl,
                          int* __restrict__ cursor, int* __restrict__ elist){
  int e = blockIdx.x*blockDim.x + threadIdx.x;
  if(e >= NE) return;
  int seg = dst[e]*TT + et[e];
  int base = incl[seg] - counts[seg];
  int pos = atomicAdd(&cursor[seg], 1);
  elist[base + pos] = e;
}

// ---------------- per-segment max aggregation (zero for empty) ----------------
template<int C>
__global__ void k_agg(const float* __restrict__ feat, const int* __restrict__ src,
                      const int* __restrict__ elist, const int* __restrict__ incl,
                      const int* __restrict__ counts, float* __restrict__ agg){
  int seg = blockIdx.x;
  int c = threadIdx.x;
  int cnt = counts[seg];
  float m = 0.0f;
  if(cnt > 0){
    int start = incl[seg] - cnt;
    m = -INFINITY;
    for(int k=0; k<cnt; ++k){
      int e = elist[start + k];
      int s = src[e];
      m = fmaxf(m, feat[s*C + c]);
    }
  }
  agg[seg*C + c] = m;
}

// ---------------- fused linear + edge-conv einsum ----------------
// out[n,o] = lin_b[o] + 4*conv_b[o] + dot(feat[n,:], lin_w[o,:])
//          + sum_t dot(agg[n,t,:], conv_w[t,o,:])
template<int CIN, int COUT>
__global__ void k_layer(const float* __restrict__ feat, const float* __restrict__ agg,
                        const float* __restrict__ lin_w, const float* __restrict__ lin_b,
                        const float* __restrict__ conv_w, const float* __restrict__ conv_b,
                        float* __restrict__ out){
  const int NPB = 8;
  __shared__ __align__(16) float sIn[NPB][5*CIN];
  int n0 = blockIdx.x * NPB;
  int t = threadIdx.x;       // output channel, 0..COUT-1
  for(int i = t; i < NPB*5*CIN; i += COUT){
    int nn = i / (5*CIN), r = i - nn*(5*CIN);
    float v;
    if(r < CIN) v = feat[(n0+nn)*CIN + r];
    else        v = agg[(n0+nn)*(TT*CIN) + (r - CIN)];
    sIn[nn][r] = v;
  }
  __syncthreads();
  float acc[NPB];
  float bias = lin_b[t] + 4.0f*conv_b[t];
  #pragma unroll
  for(int nn=0; nn<NPB; ++nn) acc[nn] = bias;
  for(int blkr=0; blkr<5; ++blkr){
    const float* wrow = (blkr == 0) ? (lin_w + t*CIN)
                                    : (conv_w + (((blkr-1)*COUT) + t)*CIN);
    const int sbase = blkr*CIN;
    for(int c=0; c<CIN; c+=4){
      float4 w4 = *(const float4*)(wrow + c);
      #pragma unroll
      for(int nn=0; nn<NPB; ++nn){
        float4 s4 = *(const float4*)(&sIn[nn][sbase + c]);
        acc[nn] += w4.x*s4.x + w4.y*s4.y + w4.z*s4.z + w4.w*s4.w;
      }
    }
  }
  #pragma unroll
  for(int nn=0; nn<NPB; ++nn) out[(n0+nn)*COUT + t] = acc[nn];
}

// ---------------- batchnorm ----------------
__global__ void k_bnstat(const float* __restrict__ h, int C, float* __restrict__ sums){
  int t = threadIdx.x;  // channel, block = C threads
  float s = 0.0f, s2 = 0.0f;
  for(int n = blockIdx.x; n < NN; n += gridDim.x){
    float v = h[n*C + t];
    s += v; s2 += v*v;
  }
  atomicAdd(&sums[t], s);
  atomicAdd(&sums[C + t], s2);
}

__global__ void k_bnfin(const float* __restrict__ sums, const float* __restrict__ g,
                        const float* __restrict__ b, float* __restrict__ ss, int C){
  int c = threadIdx.x;
  if(c >= C) return;
  float mean = sums[c] / (float)NN;
  float var  = sums[C + c] / (float)NN - mean*mean;
  float inv  = 1.0f / sqrtf(var + EPSBN);
  float scale = g[c] * inv;
  ss[c]     = scale;
  ss[C + c] = b[c] - mean*scale;
}

__global__ void k_bnrelu(float* __restrict__ h, const float* __restrict__ ss, int total){
  int i = blockIdx.x*blockDim.x + threadIdx.x;
  if(i >= total) return;
  int c = i & (FF2 - 1);
  float v = h[i]*ss[c] + ss[FF2 + c];
  h[i] = fmaxf(v, 0.0f);
}

__global__ void k_bnsig(const float* __restrict__ h, const float* __restrict__ ss,
                        float* __restrict__ out, int total){
  int i = blockIdx.x*blockDim.x + threadIdx.x;
  if(i >= total) return;
  int c = i & (FF - 1);
  float v = h[i]*ss[c] + ss[FF + c] - 10.0f;
  out[i] = 1.0f/(1.0f + expf(-v));
}

// ---------------- launch ----------------
extern "C" void kernel_launch(void* const* d_in, const int* in_sizes, int n_in,
                              void* d_out, int out_size, void* d_ws, size_t ws_size,
                              hipStream_t stream){
  (void)in_sizes; (void)n_in; (void)out_size; (void)ws_size;
  const float* x       = (const float*)d_in[0];
  const float* tbl     = (const float*)d_in[1];
  const int*   eidx    = (const int*)  d_in[2];
  const int*   etype   = (const int*)  d_in[3];
  const float* w_ih    = (const float*)d_in[4];
  const float* b_ih    = (const float*)d_in[6];
  const float* b_hh    = (const float*)d_in[7];
  const float* conv1_w = (const float*)d_in[8];
  const float* conv1_b = (const float*)d_in[9];
  const float* conv2_w = (const float*)d_in[10];
  const float* conv2_b = (const float*)d_in[11];
  const float* lin1_w  = (const float*)d_in[12];
  const float* lin1_b  = (const float*)d_in[13];
  const float* lin2_w  = (const float*)d_in[14];
  const float* lin2_b  = (const float*)d_in[15];
  const float* bn1_g   = (const float*)d_in[16];
  const float* bn1_b   = (const float*)d_in[17];
  const float* bn2_g   = (const float*)d_in[18];
  const float* bn2_b   = (const float*)d_in[19];
  float* out = (float*)d_out;

  float* W   = (float*)d_ws;
  float* hA  = W;                 // 2.56M floats: h_osc, later h3
  float* h1  = W + 2560000;       // 2.56M
  float* h2  = W + 5120000;       // 5.12M
  float* agg = W + 10240000;      // 20.48M (N*T*256 for conv2; conv1 uses N*T*128)
  int*   counts = (int*)(W + 30720000);
  int*   cursor = counts + NSEG;
  float* bnsum1 = (float*)(cursor + NSEG);  // 512
  float* bnsum2 = bnsum1 + 512;             // 256
  int*   incl   = (int*)(bnsum2 + 256);
  int*   bsums  = incl + NSEG;              // 512
  int*   elist  = bsums + 512;              // NE
  float* bn1ss  = (float*)(elist + NE);     // 512
  float* bn2ss  = bn1ss + 512;              // 256

  const int* src = eidx;
  const int* dst = eidx + NE;

  const int ZWORDS = NSEG + NSEG + 512 + 256;   // counts, cursor, bnsum1, bnsum2
  k_zero<<<(ZWORDS+255)/256, 256, 0, stream>>>((float*)counts, ZWORDS);

  k_osc<<<(NN*FF+255)/256, 256, 0, stream>>>(x, tbl, hA, NN*FF);
  k_lstm<<<NN/8, 512, 0, stream>>>(hA, w_ih, b_ih, b_hh, h1);

  k_count<<<(NE+255)/256, 256, 0, stream>>>(dst, etype, counts);
  k_scan_block<<<(NSEG+255)/256, 256, 0, stream>>>(counts, incl, bsums, NSEG);
  k_scan_bsums<<<1, 512, 0, stream>>>(bsums, (NSEG+255)/256);
  k_scan_add<<<(NSEG+255)/256, 256, 0, stream>>>(incl, bsums, NSEG);
  k_scatter<<<(NE+255)/256, 256, 0, stream>>>(dst, etype, counts, incl, cursor, elist);

  k_agg<FF><<<NSEG, FF, 0, stream>>>(h1, src, elist, incl, counts, agg);
  k_layer<FF, FF2><<<NN/8, FF2, 0, stream>>>(h1, agg, lin1_w, lin1_b, conv1_w, conv1_b, h2);

  k_bnstat<<<256, FF2, 0, stream>>>(h2, FF2, bnsum1);
  k_bnfin<<<1, FF2, 0, stream>>>(bnsum1, bn1_g, bn1_b, bn1ss, FF2);
  k_bnrelu<<<(NN*FF2+255)/256, 256, 0, stream>>>(h2, bn1ss, NN*FF2);

  k_agg<FF2><<<NSEG, FF2, 0, stream>>>(h2, src, elist, incl, counts, agg);
  k_layer<FF2, FF><<<NN/8, FF, 0, stream>>>(h2, agg, lin2_w, lin2_b, conv2_w, conv2_b, hA);

  k_bnstat<<<256, FF, 0, stream>>>(hA, FF, bnsum2);
  k_bnfin<<<1, FF, 0, stream>>>(bnsum2, bn2_g, bn2_b, bn2ss, FF);
  k_bnsig<<<(NN*FF+255)/256, 256, 0, stream>>>(hA, bn2ss, out, NN*FF);
}

// Round 2
// 536.376 us; speedup vs baseline: 1.7875x; 1.7875x over previous
//
#include <hip/hip_runtime.h>
#include <math.h>

#define NN 20000
#define FF 128
#define FF2 256
#define TT 4
#define NE 640000
#define NSEG (NN*TT)
#define MP 20032          // padded M (multiple of 64)
#define EPSBN 1e-5f

typedef short bf16x8 __attribute__((ext_vector_type(8)));
typedef float f32x4  __attribute__((ext_vector_type(4)));

__device__ __forceinline__ float sigf(float x){ return 1.0f/(1.0f+expf(-x)); }

__device__ __forceinline__ unsigned short f2bf(float x){
  union { float f; unsigned u; } v; v.f = x;
  unsigned r = v.u + 0x7FFF + ((v.u >> 16) & 1);
  return (unsigned short)(r >> 16);
}
__device__ __forceinline__ float bf2f(unsigned short u){
  union { float f; unsigned u; } v; v.u = ((unsigned)u) << 16; return v.f;
}
__device__ __forceinline__ size_t pidx(int k, int n){
  return ((size_t)(k >> 3) * MP + n) * 8 + (k & 7);
}

// ---------------- utility ----------------
__global__ void k_zero(int* __restrict__ p, int n){
  int i = blockIdx.x*blockDim.x + threadIdx.x;
  if(i < n) p[i] = 0;
}
// zero pad rows [20000,20032) of a packed A; one block (256 thr) per k8
__global__ void k_padz(unsigned short* __restrict__ Ap){
  int k8 = blockIdx.x;
  Ap[((size_t)k8*MP + 20000)*8 + threadIdx.x] = 0;
}

// ---------------- oscillator -> packed A0 (hi,hi,lo) ----------------
__global__ void k_osc_pack(const float* __restrict__ x, const float* __restrict__ tbl,
                           unsigned short* __restrict__ Ap0){
  int i = blockIdx.x*256 + threadIdx.x;
  if(i >= NN*FF) return;
  int n = i >> 7, j = i & 127;
  float xv = x[i];
  float xi = (xv < -0.5f || xv > 0.5f) ? 0.5001f : xv;
  int idx = (int)floorf((xi + 0.5f) * 10000.0f);
  float tv = tbl[idx];
  float hv = (tv == 0.0f) ? sigf(xv) : tv;
  unsigned short hu = f2bf(hv);
  unsigned short lu = f2bf(hv - bf2f(hu));
  Ap0[pidx(j, n)]      = hu;
  Ap0[pidx(128+j, n)]  = hu;
  Ap0[pidx(256+j, n)]  = lu;
}

// ---------------- B packing: [hiW, loW, hiW, conv_w(bf16)] ----------------
__global__ void k_packB(const float* __restrict__ lin_w, const float* __restrict__ conv_w,
                        unsigned short* __restrict__ Bp, int C, int COUT, int K){
  int i = blockIdx.x*256 + threadIdx.x;
  if(i >= K*COUT) return;
  int k = i / COUT, o = i - k*COUT;
  size_t dst = ((size_t)(k >> 3)*COUT + o)*8 + (k & 7);
  int reg = k / C;
  if(reg < 3){
    float w = lin_w[(size_t)o*C + (k - reg*C)];
    unsigned short hu = f2bf(w);
    Bp[dst] = (reg == 1) ? f2bf(w - bf2f(hu)) : hu;
  } else {
    int kk = k - 3*C; int t = kk / C; int c = kk - t*C;
    Bp[dst] = f2bf(conv_w[((size_t)t*COUT + o)*C + c]);
  }
}

__global__ void k_mkbias(float* __restrict__ dst, const float* __restrict__ b1,
                         const float* __restrict__ b2, float s, int n){
  int i = threadIdx.x;
  if(i < n) dst[i] = b1[i] + s*b2[i];
}

// ---------------- MFMA GEMM: C[n,o] = A[n,:]·B[:,o] + bias[o] ----------------
// A packed [k8][MP][8] bf16, B packed [k8][COUT][8] bf16. Block: 64 rows x 128 cols,
// 4 waves each 32x64 (2x4 fragments of 16x16x32).
template<int COUT>
__global__ __launch_bounds__(256)
void k_gemm(const unsigned short* __restrict__ Ap, const unsigned short* __restrict__ Bp,
            const float* __restrict__ bias, float* __restrict__ out, int K){
  int w  = threadIdx.x >> 6;
  int l  = threadIdx.x & 63;
  int wr = w >> 1, wc = w & 1;
  int lr = l & 15, lg = l >> 4;
  int n0 = blockIdx.x*64 + wr*32;
  int c0 = blockIdx.y*128 + wc*64;
  const unsigned short* a0 = Ap + ((size_t)lg*MP   + (n0 + lr))*8;
  const unsigned short* b0 = Bp + ((size_t)lg*COUT + (c0 + lr))*8;
  f32x4 acc[2][4] = {};
  for(int kk = 0; kk < K; kk += 32){
    bf16x8 a[2], b[4];
    a[0] = *(const bf16x8*)(a0);
    a[1] = *(const bf16x8*)(a0 + 16*8);
    #pragma unroll
    for(int j = 0; j < 4; ++j) b[j] = *(const bf16x8*)(b0 + j*16*8);
    a0 += (size_t)4*MP*8;
    b0 += (size_t)4*COUT*8;
    #pragma unroll
    for(int r = 0; r < 2; ++r)
      #pragma unroll
      for(int j = 0; j < 4; ++j)
        acc[r][j] = __builtin_amdgcn_mfma_f32_16x16x32_bf16(a[r], b[j], acc[r][j], 0, 0, 0);
  }
  #pragma unroll
  for(int r = 0; r < 2; ++r){
    int nbase = n0 + r*16 + lg*4;
    #pragma unroll
    for(int j = 0; j < 4; ++j){
      int o = c0 + j*16 + lr;
      float bs = bias[o];
      #pragma unroll
      for(int q = 0; q < 4; ++q){
        int n = nbase + q;
        if(n < NN) out[(size_t)n*COUT + o] = acc[r][j][q] + bs;
      }
    }
  }
}

// ---------------- LSTM activation -> packed A1 (hi,hi,lo) + bf16 copy ----------------
__global__ void k_act(const float* __restrict__ gates, unsigned short* __restrict__ Ap1,
                      unsigned short* __restrict__ h1b){
  int i = blockIdx.x*256 + threadIdx.x;
  if(i >= NN*FF) return;
  int n = i >> 7, j = i & 127;
  const float* g = gates + (size_t)n*512;
  float ig = g[j], gg = g[256+j], og = g[384+j];
  float c  = sigf(ig) * tanhf(gg);
  float hv = sigf(og) * tanhf(c);
  unsigned short hu = f2bf(hv);
  unsigned short lu = f2bf(hv - bf2f(hu));
  h1b[i] = hu;
  Ap1[pidx(j, n)]     = hu;
  Ap1[pidx(128+j, n)] = hu;
  Ap1[pidx(256+j, n)] = lu;
}

// ---------------- CSR build over seg = dst*T + etype ----------------
__global__ void k_count(const int* __restrict__ dst, const int* __restrict__ et,
                        int* __restrict__ counts){
  int e = blockIdx.x*blockDim.x + threadIdx.x;
  if(e >= NE) return;
  atomicAdd(&counts[dst[e]*TT + et[e]], 1);
}
__global__ void k_scan_block(const int* __restrict__ in, int* __restrict__ out,
                             int* __restrict__ bsums, int n){
  __shared__ int s[256];
  int i = blockIdx.x*256 + threadIdx.x;
  int v = (i < n) ? in[i] : 0;
  s[threadIdx.x] = v; __syncthreads();
  for(int off = 1; off < 256; off <<= 1){
    int add = (threadIdx.x >= off) ? s[threadIdx.x - off] : 0;
    __syncthreads();
    s[threadIdx.x] += add;
    __syncthreads();
  }
  if(i < n) out[i] = s[threadIdx.x];
  if(threadIdx.x == 255) bsums[blockIdx.x] = s[255];
}
__global__ void k_scan_bsums(int* __restrict__ bsums, int nb){
  __shared__ int s[512];
  int v = (threadIdx.x < nb) ? bsums[threadIdx.x] : 0;
  s[threadIdx.x] = v; __syncthreads();
  for(int off = 1; off < 512; off <<= 1){
    int add = (threadIdx.x >= off) ? s[threadIdx.x - off] : 0;
    __syncthreads();
    s[threadIdx.x] += add;
    __syncthreads();
  }
  if(threadIdx.x < nb) bsums[threadIdx.x] = s[threadIdx.x];
}
__global__ void k_scan_add(int* __restrict__ out, const int* __restrict__ bsums, int n){
  int i = blockIdx.x*256 + threadIdx.x;
  if(i >= n || blockIdx.x == 0) return;
  out[i] += bsums[blockIdx.x - 1];
}
__global__ void k_scatter(const int* __restrict__ dst, const int* __restrict__ et,
                          const int* __restrict__ counts, const int* __restrict__ incl,
                          int* __restrict__ cursor, int* __restrict__ elist){
  int e = blockIdx.x*blockDim.x + threadIdx.x;
  if(e >= NE) return;
  int seg = dst[e]*TT + et[e];
  int base = incl[seg] - counts[seg];
  int pos = atomicAdd(&cursor[seg], 1);
  elist[base + pos] = e;
}

// ---------------- per-segment max -> packed A rows [3C .. 7C) ----------------
template<int C>
__global__ void k_agg(const unsigned short* __restrict__ hb, const int* __restrict__ src,
                      const int* __restrict__ elist, const int* __restrict__ incl,
                      const int* __restrict__ counts, unsigned short* __restrict__ Ap){
  int seg = blockIdx.x;
  int c = threadIdx.x;
  int n = seg >> 2, t = seg & 3;
  int cnt = counts[seg];
  float m = 0.0f;
  if(cnt > 0){
    int start = incl[seg] - cnt;
    m = -INFINITY;
    for(int k2 = 0; k2 < cnt; ++k2){
      int s = src[elist[start + k2]];
      m = fmaxf(m, bf2f(hb[(size_t)s*C + c]));
    }
  }
  int k = 3*C + t*C + c;
  Ap[pidx(k, n)] = f2bf(m);
}

// ---------------- batchnorm ----------------
__global__ void k_bnstat(const float* __restrict__ h, int C, float* __restrict__ sums){
  int t = threadIdx.x;
  float s = 0.0f, s2 = 0.0f;
  for(int n = blockIdx.x; n < NN; n += gridDim.x){
    float v = h[(size_t)n*C + t];
    s += v; s2 += v*v;
  }
  atomicAdd(&sums[t], s);
  atomicAdd(&sums[C + t], s2);
}
__global__ void k_bnfin(const float* __restrict__ sums, const float* __restrict__ g,
                        const float* __restrict__ b, float* __restrict__ ss, int C){
  int c = threadIdx.x;
  if(c >= C) return;
  float mean = sums[c] / (float)NN;
  float var  = sums[C + c] / (float)NN - mean*mean;
  float inv  = 1.0f / sqrtf(var + EPSBN);
  float scale = g[c] * inv;
  ss[c]     = scale;
  ss[C + c] = b[c] - mean*scale;
}
// BN1 + ReLU -> packed A2 (hi,hi,lo) + bf16 copy
__global__ void k_bnrp(const float* __restrict__ h2, const float* __restrict__ ss,
                       unsigned short* __restrict__ Ap2, unsigned short* __restrict__ h2b){
  int i = blockIdx.x*256 + threadIdx.x;
  if(i >= NN*FF2) return;
  int n = i >> 8, c = i & 255;
  float v = h2[i]*ss[c] + ss[FF2 + c];
  v = fmaxf(v, 0.0f);
  unsigned short hu = f2bf(v);
  unsigned short lu = f2bf(v - bf2f(hu));
  h2b[i] = hu;
  Ap2[pidx(c, n)]     = hu;
  Ap2[pidx(256+c, n)] = hu;
  Ap2[pidx(512+c, n)] = lu;
}
// BN2 + sigmoid(x-10), in place
__global__ void k_bnsig(float* __restrict__ h, const float* __restrict__ ss, int total){
  int i = blockIdx.x*256 + threadIdx.x;
  if(i >= total) return;
  int c = i & (FF - 1);
  float v = h[i]*ss[c] + ss[FF + c] - 10.0f;
  h[i] = 1.0f/(1.0f + expf(-v));
}

// ---------------- launch ----------------
extern "C" void kernel_launch(void* const* d_in, const int* in_sizes, int n_in,
                              void* d_out, int out_size, void* d_ws, size_t ws_size,
                              hipStream_t stream){
  (void)in_sizes; (void)n_in; (void)out_size; (void)ws_size;
  const float* x       = (const float*)d_in[0];
  const float* tbl     = (const float*)d_in[1];
  const int*   eidx    = (const int*)  d_in[2];
  const int*   etype   = (const int*)  d_in[3];
  const float* w_ih    = (const float*)d_in[4];
  const float* b_ih    = (const float*)d_in[6];
  const float* b_hh    = (const float*)d_in[7];
  const float* conv1_w = (const float*)d_in[8];
  const float* conv1_b = (const float*)d_in[9];
  const float* conv2_w = (const float*)d_in[10];
  const float* conv2_b = (const float*)d_in[11];
  const float* lin1_w  = (const float*)d_in[12];
  const float* lin1_b  = (const float*)d_in[13];
  const float* lin2_w  = (const float*)d_in[14];
  const float* lin2_b  = (const float*)d_in[15];
  const float* bn1_g   = (const float*)d_in[16];
  const float* bn1_b   = (const float*)d_in[17];
  const float* bn2_g   = (const float*)d_in[18];
  const float* bn2_b   = (const float*)d_in[19];
  float* out = (float*)d_out;

  char* base = (char*)d_ws;
  size_t off = 0;
  auto alloc = [&](size_t bytes){ char* p = base + off; off = (off + bytes + 255) & ~(size_t)255; return p; };

  unsigned short* Ap0 = (unsigned short*)alloc((size_t)48 * MP * 16);   // 15.4 MB (hosts h1b,h2b after GEMM0)
  unsigned short* Ap1 = (unsigned short*)alloc((size_t)112 * MP * 16);  // 35.9 MB
  unsigned short* Ap2 = (unsigned short*)alloc((size_t)224 * MP * 16);  // 71.8 MB (hosts gates first)
  float* h2raw = (float*)alloc((size_t)NN * FF2 * 4);                   // 20.5 MB
  unsigned short* Bp0 = (unsigned short*)alloc((size_t)384 * 512 * 2);
  unsigned short* Bp1 = (unsigned short*)alloc((size_t)896 * 256 * 2);
  unsigned short* Bp2 = (unsigned short*)alloc((size_t)1792 * 128 * 2);
  float* bias0 = (float*)alloc(512 * 4);
  float* bias1 = (float*)alloc(256 * 4);
  float* bias2 = (float*)alloc(128 * 4);
  int* counts = (int*)alloc(NSEG * 4);
  int* cursor = (int*)alloc(NSEG * 4);
  int* incl   = (int*)alloc(NSEG * 4);
  int* bsums  = (int*)alloc(512 * 4);
  int* elist  = (int*)alloc((size_t)NE * 4);
  float* bnsum1 = (float*)alloc(512 * 4);
  float* bnsum2 = (float*)alloc(256 * 4);
  float* ss1    = (float*)alloc(512 * 4);
  float* ss2    = (float*)alloc(256 * 4);

  // aliases
  float* gates = (float*)Ap2;                       // 41 MB, dead before Ap2 is written
  unsigned short* h1b = Ap0;                        // 5.12 MB, after GEMM0
  unsigned short* h2b = Ap0 + (size_t)NN * FF;      // 10.24 MB

  const int* src = eidx;
  const int* dst = eidx + NE;

  // zero counters + bn sums
  k_zero<<<(2*NSEG + 255)/256, 256, 0, stream>>>(counts, 2*NSEG);          // counts+cursor contiguous
  k_zero<<<3, 256, 0, stream>>>((int*)bnsum1, 768);                        // bnsum1+bnsum2 contiguous

  // pack weights + biases
  k_packB<<<(384*512 + 255)/256, 256, 0, stream>>>(w_ih,   nullptr, Bp0, 128, 512, 384);
  k_packB<<<(896*256 + 255)/256, 256, 0, stream>>>(lin1_w, conv1_w, Bp1, 128, 256, 896);
  k_packB<<<(1792*128 + 255)/256, 256, 0, stream>>>(lin2_w, conv2_w, Bp2, 256, 128, 1792);
  k_mkbias<<<1, 512, 0, stream>>>(bias0, b_ih,   b_hh,    1.0f, 512);
  k_mkbias<<<1, 256, 0, stream>>>(bias1, lin1_b, conv1_b, 4.0f, 256);
  k_mkbias<<<1, 128, 0, stream>>>(bias2, lin2_b, conv2_b, 4.0f, 128);

  // A0 pack + pads
  k_padz<<<48, 256, 0, stream>>>(Ap0);
  k_padz<<<112, 256, 0, stream>>>(Ap1);
  k_osc_pack<<<(NN*FF + 255)/256, 256, 0, stream>>>(x, tbl, Ap0);

  // CSR
  k_count<<<(NE + 255)/256, 256, 0, stream>>>(dst, etype, counts);
  k_scan_block<<<(NSEG + 255)/256, 256, 0, stream>>>(counts, incl, bsums, NSEG);
  k_scan_bsums<<<1, 512, 0, stream>>>(bsums, (NSEG + 255)/256);
  k_scan_add<<<(NSEG + 255)/256, 256, 0, stream>>>(incl, bsums, NSEG);
  k_scatter<<<(NE + 255)/256, 256, 0, stream>>>(dst, etype, counts, incl, cursor, elist);

  // LSTM: gates = A0 x B0
  k_gemm<512><<<dim3(313, 4), 256, 0, stream>>>(Ap0, Bp0, bias0, gates, 384);
  k_act<<<(NN*FF + 255)/256, 256, 0, stream>>>(gates, Ap1, h1b);
  k_padz<<<224, 256, 0, stream>>>(Ap2);             // after gates is dead

  // layer 1
  k_agg<FF><<<NSEG, FF, 0, stream>>>(h1b, src, elist, incl, counts, Ap1);
  k_gemm<256><<<dim3(313, 2), 256, 0, stream>>>(Ap1, Bp1, bias1, h2raw, 896);
  k_bnstat<<<256, FF2, 0, stream>>>(h2raw, FF2, bnsum1);
  k_bnfin<<<1, FF2, 0, stream>>>(bnsum1, bn1_g, bn1_b, ss1, FF2);
  k_bnrp<<<(NN*FF2 + 255)/256, 256, 0, stream>>>(h2raw, ss1, Ap2, h2b);

  // layer 2
  k_agg<FF2><<<NSEG, FF2, 0, stream>>>(h2b, src, elist, incl, counts, Ap2);
  k_gemm<128><<<dim3(313, 1), 256, 0, stream>>>(Ap2, Bp2, bias2, out, 1792);
  k_bnstat<<<256, FF, 0, stream>>>(out, FF, bnsum2);
  k_bnfin<<<1, FF, 0, stream>>>(bnsum2, bn2_g, bn2_b, ss2, FF);
  k_bnsig<<<(NN*FF + 255)/256, 256, 0, stream>>>(out, ss2, NN*FF);
}

// Round 3
// 372.113 us; speedup vs baseline: 2.5765x; 1.4414x over previous
//
#include <hip/hip_runtime.h>
#include <math.h>

#define NN 20000
#define FF 128
#define FF2 256
#define TT 4
#define NE 640000
#define NSEG (NN*TT)
#define MP 20032          // padded M (multiple of 64)
#define EPSBN 1e-5f

// K-totals for the three GEMMs (A row-major [MP][K])
#define K0 384            // lstm: [hi, hi, lo] of 128
#define K1 896            // layer1: 3*128 + 4*128
#define K2 1792           // layer2: 3*256 + 4*256

typedef short bf16x8 __attribute__((ext_vector_type(8)));
typedef float f32x4  __attribute__((ext_vector_type(4)));
typedef unsigned short u16x2 __attribute__((ext_vector_type(2)));
typedef unsigned short u16x4 __attribute__((ext_vector_type(4)));

__device__ __forceinline__ float sigf(float x){ return 1.0f/(1.0f+expf(-x)); }

__device__ __forceinline__ unsigned short f2bf(float x){
  union { float f; unsigned u; } v; v.f = x;
  unsigned r = v.u + 0x7FFF + ((v.u >> 16) & 1);
  return (unsigned short)(r >> 16);
}
__device__ __forceinline__ float bf2f(unsigned short u){
  union { float f; unsigned u; } v; v.u = ((unsigned)u) << 16; return v.f;
}

// ---------------- utility ----------------
__global__ void k_zero(int* __restrict__ p, int n){
  int i = blockIdx.x*blockDim.x + threadIdx.x;
  if(i < n) p[i] = 0;
}

// ---------------- oscillator -> A0 row-major [n][hi|hi|lo] ----------------
__global__ void k_osc_pack(const float* __restrict__ x, const float* __restrict__ tbl,
                           unsigned short* __restrict__ A0){
  int i = blockIdx.x*256 + threadIdx.x;
  if(i >= NN*FF) return;
  int n = i >> 7, j = i & 127;
  float xv = x[i];
  float xi = (xv < -0.5f || xv > 0.5f) ? 0.5001f : xv;
  int idx = (int)floorf((xi + 0.5f) * 10000.0f);
  float tv = tbl[idx];
  float hv = (tv == 0.0f) ? sigf(xv) : tv;
  unsigned short hu = f2bf(hv);
  unsigned short lu = f2bf(hv - bf2f(hu));
  unsigned short* r = A0 + (size_t)n*K0;
  r[j] = hu; r[128+j] = hu; r[256+j] = lu;
}

// ---------------- B packing: [hiW, loW, hiW, conv_w(bf16)] (frag-packed) ----------------
__global__ void k_packB(const float* __restrict__ lin_w, const float* __restrict__ conv_w,
                        unsigned short* __restrict__ Bp, int C, int COUT, int K){
  int i = blockIdx.x*256 + threadIdx.x;
  if(i >= K*COUT) return;
  int k = i / COUT, o = i - k*COUT;
  size_t dst = ((size_t)(k >> 3)*COUT + o)*8 + (k & 7);
  int reg = k / C;
  if(reg < 3){
    float w = lin_w[(size_t)o*C + (k - reg*C)];
    unsigned short hu = f2bf(w);
    Bp[dst] = (reg == 1) ? f2bf(w - bf2f(hu)) : hu;
  } else {
    int kk = k - 3*C; int t = kk / C; int c = kk - t*C;
    Bp[dst] = f2bf(conv_w[((size_t)t*COUT + o)*C + c]);
  }
}

__global__ void k_mkbias(float* __restrict__ dst, const float* __restrict__ b1,
                         const float* __restrict__ b2, float s, int n){
  int i = threadIdx.x;
  if(i < n) dst[i] = b1[i] + s*b2[i];
}

// ---------------- MFMA GEMM: out[n,o] = A[n,:]·B[:,o] + bias[o] ----------------
// A row-major [MP][K] bf16, B packed [k8][COUT][8] bf16.
// Block: 64 rows x 128 cols; 4 waves each 32x64 (2x4 fragments of 16x16x32).
template<int COUT, int K>
__global__ __launch_bounds__(256)
void k_gemm(const unsigned short* __restrict__ A, const unsigned short* __restrict__ Bp,
            const float* __restrict__ bias, float* __restrict__ out){
  int w  = threadIdx.x >> 6;
  int l  = threadIdx.x & 63;
  int wr = w >> 1, wc = w & 1;
  int lr = l & 15, lg = l >> 4;
  int n0 = blockIdx.x*64 + wr*32;
  int c0 = blockIdx.y*128 + wc*64;
  const unsigned short* a0 = A + (size_t)(n0 + lr)*K + lg*8;
  const unsigned short* a1 = a0 + (size_t)16*K;
  const unsigned short* b0 = Bp + ((size_t)lg*COUT + (c0 + lr))*8;
  f32x4 acc[2][4] = {};
  for(int kk = 0; kk < K; kk += 32){
    bf16x8 a[2], b[4];
    a[0] = *(const bf16x8*)(a0 + kk);
    a[1] = *(const bf16x8*)(a1 + kk);
    #pragma unroll
    for(int j = 0; j < 4; ++j) b[j] = *(const bf16x8*)(b0 + j*16*8);
    b0 += (size_t)4*COUT*8;
    #pragma unroll
    for(int r = 0; r < 2; ++r)
      #pragma unroll
      for(int j = 0; j < 4; ++j)
        acc[r][j] = __builtin_amdgcn_mfma_f32_16x16x32_bf16(a[r], b[j], acc[r][j], 0, 0, 0);
  }
  #pragma unroll
  for(int r = 0; r < 2; ++r){
    int nbase = n0 + r*16 + lg*4;
    #pragma unroll
    for(int j = 0; j < 4; ++j){
      int o = c0 + j*16 + lr;
      float bs = bias[o];
      #pragma unroll
      for(int q = 0; q < 4; ++q){
        int n = nbase + q;
        if(n < NN) out[(size_t)n*COUT + o] = acc[r][j][q] + bs;
      }
    }
  }
}

// ---------------- LSTM activation -> A1 rows [0,384) + bf16 gather table ----------------
__global__ void k_act(const float* __restrict__ gates, unsigned short* __restrict__ A1,
                      unsigned short* __restrict__ h1b){
  int i = blockIdx.x*256 + threadIdx.x;
  if(i >= NN*FF) return;
  int n = i >> 7, j = i & 127;
  const float* g = gates + (size_t)n*512;
  float ig = g[j], gg = g[256+j], og = g[384+j];
  float c  = sigf(ig) * tanhf(gg);
  float hv = sigf(og) * tanhf(c);
  unsigned short hu = f2bf(hv);
  unsigned short lu = f2bf(hv - bf2f(hu));
  h1b[i] = hu;
  unsigned short* r = A1 + (size_t)n*K1;
  r[j] = hu; r[128+j] = hu; r[256+j] = lu;
}

// ---------------- CSR build over seg = dst*T + etype ----------------
__global__ void k_count(const int* __restrict__ dst, const int* __restrict__ et,
                        int* __restrict__ counts){
  int e = blockIdx.x*blockDim.x + threadIdx.x;
  if(e >= NE) return;
  atomicAdd(&counts[dst[e]*TT + et[e]], 1);
}
__global__ void k_scan_block(const int* __restrict__ in, int* __restrict__ out,
                             int* __restrict__ bsums, int n){
  __shared__ int s[256];
  int i = blockIdx.x*256 + threadIdx.x;
  int v = (i < n) ? in[i] : 0;
  s[threadIdx.x] = v; __syncthreads();
  for(int off = 1; off < 256; off <<= 1){
    int add = (threadIdx.x >= off) ? s[threadIdx.x - off] : 0;
    __syncthreads();
    s[threadIdx.x] += add;
    __syncthreads();
  }
  if(i < n) out[i] = s[threadIdx.x];
  if(threadIdx.x == 255) bsums[blockIdx.x] = s[255];
}
__global__ void k_scan_bsums(int* __restrict__ bsums, int nb){
  __shared__ int s[512];
  int v = (threadIdx.x < nb) ? bsums[threadIdx.x] : 0;
  s[threadIdx.x] = v; __syncthreads();
  for(int off = 1; off < 512; off <<= 1){
    int add = (threadIdx.x >= off) ? s[threadIdx.x - off] : 0;
    __syncthreads();
    s[threadIdx.x] += add;
    __syncthreads();
  }
  if(threadIdx.x < nb) bsums[threadIdx.x] = s[threadIdx.x];
}
__global__ void k_scan_add(int* __restrict__ out, const int* __restrict__ bsums, int n){
  int i = blockIdx.x*256 + threadIdx.x;
  if(i >= n || blockIdx.x == 0) return;
  out[i] += bsums[blockIdx.x - 1];
}
// elist stores SOURCE NODE id (not edge id) — kills one dependent load in agg
__global__ void k_scatter(const int* __restrict__ src, const int* __restrict__ dst,
                          const int* __restrict__ et, const int* __restrict__ counts,
                          const int* __restrict__ incl, int* __restrict__ cursor,
                          int* __restrict__ elist){
  int e = blockIdx.x*blockDim.x + threadIdx.x;
  if(e >= NE) return;
  int seg = dst[e]*TT + et[e];
  int base = incl[seg] - counts[seg];
  int pos = atomicAdd(&cursor[seg], 1);
  elist[base + pos] = src[e];
}

// ---------------- per-segment max -> A rows [3C, 7C) row-major ----------------
// one 64-lane wave per segment; VW channels per lane
template<int C, int KTOT>
__global__ __launch_bounds__(256)
void k_agg(const unsigned short* __restrict__ hb, const int* __restrict__ elist,
           const int* __restrict__ incl, const int* __restrict__ counts,
           unsigned short* __restrict__ A){
  constexpr int VW = C/64;
  typedef unsigned short uvec __attribute__((ext_vector_type(VW)));
  int seg  = blockIdx.x*4 + (threadIdx.x >> 6);
  int lane = threadIdx.x & 63;
  int cnt = counts[seg];
  int n = seg >> 2, t = seg & 3;
  int start = incl[seg] - cnt;
  const unsigned short* gp = hb + lane*VW;
  float m[VW];
  #pragma unroll
  for(int v = 0; v < VW; ++v) m[v] = -INFINITY;
  int i = 0;
  for(; i + 4 <= cnt; i += 4){
    int s0 = elist[start+i], s1 = elist[start+i+1];
    int s2 = elist[start+i+2], s3 = elist[start+i+3];
    uvec v0 = *(const uvec*)(gp + (size_t)s0*C);
    uvec v1 = *(const uvec*)(gp + (size_t)s1*C);
    uvec v2 = *(const uvec*)(gp + (size_t)s2*C);
    uvec v3 = *(const uvec*)(gp + (size_t)s3*C);
    #pragma unroll
    for(int v = 0; v < VW; ++v){
      m[v] = fmaxf(m[v], fmaxf(fmaxf(bf2f(v0[v]), bf2f(v1[v])),
                               fmaxf(bf2f(v2[v]), bf2f(v3[v]))));
    }
  }
  for(; i < cnt; ++i){
    int s = elist[start+i];
    uvec vv = *(const uvec*)(gp + (size_t)s*C);
    #pragma unroll
    for(int v = 0; v < VW; ++v) m[v] = fmaxf(m[v], bf2f(vv[v]));
  }
  uvec o;
  #pragma unroll
  for(int v = 0; v < VW; ++v) o[v] = (cnt > 0) ? f2bf(m[v]) : (unsigned short)0;
  *(uvec*)(A + (size_t)n*KTOT + 3*C + t*C + lane*VW) = o;
}

// ---------------- batchnorm ----------------
__global__ void k_bnstat(const float* __restrict__ h, int C, float* __restrict__ sums){
  int t = threadIdx.x;
  float s = 0.0f, s2 = 0.0f;
  for(int n = blockIdx.x; n < NN; n += gridDim.x){
    float v = h[(size_t)n*C + t];
    s += v; s2 += v*v;
  }
  atomicAdd(&sums[t], s);
  atomicAdd(&sums[C + t], s2);
}
__global__ void k_bnfin(const float* __restrict__ sums, const float* __restrict__ g,
                        const float* __restrict__ b, float* __restrict__ ss, int C){
  int c = threadIdx.x;
  if(c >= C) return;
  float mean = sums[c] / (float)NN;
  float var  = sums[C + c] / (float)NN - mean*mean;
  float inv  = 1.0f / sqrtf(var + EPSBN);
  float scale = g[c] * inv;
  ss[c]     = scale;
  ss[C + c] = b[c] - mean*scale;
}
// BN1 + ReLU -> A2 rows [0,768) + bf16 gather table
__global__ void k_bnrp(const float* __restrict__ h2, const float* __restrict__ ss,
                       unsigned short* __restrict__ A2, unsigned short* __restrict__ h2b){
  int i = blockIdx.x*256 + threadIdx.x;
  if(i >= NN*FF2) return;
  int n = i >> 8, c = i & 255;
  float v = h2[i]*ss[c] + ss[FF2 + c];
  v = fmaxf(v, 0.0f);
  unsigned short hu = f2bf(v);
  unsigned short lu = f2bf(v - bf2f(hu));
  h2b[i] = hu;
  unsigned short* r = A2 + (size_t)n*K2;
  r[c] = hu; r[256+c] = hu; r[512+c] = lu;
}
// BN2 + sigmoid(x-10), in place
__global__ void k_bnsig(float* __restrict__ h, const float* __restrict__ ss, int total){
  int i = blockIdx.x*256 + threadIdx.x;
  if(i >= total) return;
  int c = i & (FF - 1);
  float v = h[i]*ss[c] + ss[FF + c] - 10.0f;
  h[i] = 1.0f/(1.0f + expf(-v));
}

// ---------------- launch ----------------
extern "C" void kernel_launch(void* const* d_in, const int* in_sizes, int n_in,
                              void* d_out, int out_size, void* d_ws, size_t ws_size,
                              hipStream_t stream){
  (void)in_sizes; (void)n_in; (void)out_size; (void)ws_size;
  const float* x       = (const float*)d_in[0];
  const float* tbl     = (const float*)d_in[1];
  const int*   eidx    = (const int*)  d_in[2];
  const int*   etype   = (const int*)  d_in[3];
  const float* w_ih    = (const float*)d_in[4];
  const float* b_ih    = (const float*)d_in[6];
  const float* b_hh    = (const float*)d_in[7];
  const float* conv1_w = (const float*)d_in[8];
  const float* conv1_b = (const float*)d_in[9];
  const float* conv2_w = (const float*)d_in[10];
  const float* conv2_b = (const float*)d_in[11];
  const float* lin1_w  = (const float*)d_in[12];
  const float* lin1_b  = (const float*)d_in[13];
  const float* lin2_w  = (const float*)d_in[14];
  const float* lin2_b  = (const float*)d_in[15];
  const float* bn1_g   = (const float*)d_in[16];
  const float* bn1_b   = (const float*)d_in[17];
  const float* bn2_g   = (const float*)d_in[18];
  const float* bn2_b   = (const float*)d_in[19];
  float* out = (float*)d_out;

  char* base = (char*)d_ws;
  size_t off = 0;
  auto alloc = [&](size_t bytes){ char* p = base + off; off = (off + bytes + 255) & ~(size_t)255; return p; };

  unsigned short* A0 = (unsigned short*)alloc((size_t)MP * K0 * 2);   // 15.4 MB (hosts h1b,h2b after GEMM0)
  unsigned short* A1 = (unsigned short*)alloc((size_t)MP * K1 * 2);   // 35.9 MB
  unsigned short* A2 = (unsigned short*)alloc((size_t)MP * K2 * 2);   // 71.8 MB (hosts gates first)
  float* h2raw = (float*)alloc((size_t)NN * FF2 * 4);                 // 20.5 MB
  unsigned short* Bp0 = (unsigned short*)alloc((size_t)K0 * 512 * 2);
  unsigned short* Bp1 = (unsigned short*)alloc((size_t)K1 * 256 * 2);
  unsigned short* Bp2 = (unsigned short*)alloc((size_t)K2 * 128 * 2);
  float* bias0 = (float*)alloc(512 * 4);
  float* bias1 = (float*)alloc(256 * 4);
  float* bias2 = (float*)alloc(128 * 4);
  int* counts = (int*)alloc(NSEG * 4);
  int* cursor = (int*)alloc(NSEG * 4);
  int* incl   = (int*)alloc(NSEG * 4);
  int* bsums  = (int*)alloc(512 * 4);
  int* elist  = (int*)alloc((size_t)NE * 4);
  float* bnsum1 = (float*)alloc(512 * 4);
  float* bnsum2 = (float*)alloc(256 * 4);
  float* ss1    = (float*)alloc(512 * 4);
  float* ss2    = (float*)alloc(256 * 4);

  // aliases (lifetimes disjoint)
  float* gates = (float*)A2;                        // 41 MB, dead before A2 is written
  unsigned short* h1b = A0;                         // 5.12 MB, valid after GEMM0
  unsigned short* h2b = A0 + (size_t)NN * FF;       // 10.24 MB

  const int* src = eidx;
  const int* dst = eidx + NE;

  // zero counters + bn sums
  k_zero<<<(2*NSEG + 255)/256, 256, 0, stream>>>(counts, 2*NSEG);   // counts+cursor contiguous
  k_zero<<<3, 256, 0, stream>>>((int*)bnsum1, 768);                 // bnsum1+bnsum2 contiguous

  // pack weights + biases
  k_packB<<<(K0*512 + 255)/256, 256, 0, stream>>>(w_ih,   nullptr, Bp0, 128, 512, K0);
  k_packB<<<(K1*256 + 255)/256, 256, 0, stream>>>(lin1_w, conv1_w, Bp1, 128, 256, K1);
  k_packB<<<(K2*128 + 255)/256, 256, 0, stream>>>(lin2_w, conv2_w, Bp2, 256, 128, K2);
  k_mkbias<<<1, 512, 0, stream>>>(bias0, b_ih,   b_hh,    1.0f, 512);
  k_mkbias<<<1, 256, 0, stream>>>(bias1, lin1_b, conv1_b, 4.0f, 256);
  k_mkbias<<<1, 128, 0, stream>>>(bias2, lin2_b, conv2_b, 4.0f, 128);

  k_osc_pack<<<(NN*FF + 255)/256, 256, 0, stream>>>(x, tbl, A0);

  // CSR
  k_count<<<(NE + 255)/256, 256, 0, stream>>>(dst, etype, counts);
  k_scan_block<<<(NSEG + 255)/256, 256, 0, stream>>>(counts, incl, bsums, NSEG);
  k_scan_bsums<<<1, 512, 0, stream>>>(bsums, (NSEG + 255)/256);
  k_scan_add<<<(NSEG + 255)/256, 256, 0, stream>>>(incl, bsums, NSEG);
  k_scatter<<<(NE + 255)/256, 256, 0, stream>>>(src, dst, etype, counts, incl, cursor, elist);

  // LSTM: gates = A0 x B0
  k_gemm<512, K0><<<dim3(313, 4), 256, 0, stream>>>(A0, Bp0, bias0, gates);
  k_act<<<(NN*FF + 255)/256, 256, 0, stream>>>(gates, A1, h1b);

  // layer 1
  k_agg<FF, K1><<<NSEG/4, 256, 0, stream>>>(h1b, elist, incl, counts, A1);
  k_gemm<256, K1><<<dim3(313, 2), 256, 0, stream>>>(A1, Bp1, bias1, h2raw);
  k_bnstat<<<256, FF2, 0, stream>>>(h2raw, FF2, bnsum1);
  k_bnfin<<<1, FF2, 0, stream>>>(bnsum1, bn1_g, bn1_b, ss1, FF2);
  k_bnrp<<<(NN*FF2 + 255)/256, 256, 0, stream>>>(h2raw, ss1, A2, h2b);

  // layer 2
  k_agg<FF2, K2><<<NSEG/4, 256, 0, stream>>>(h2b, elist, incl, counts, A2);
  k_gemm<128, K2><<<dim3(313, 1), 256, 0, stream>>>(A2, Bp2, bias2, out);
  k_bnstat<<<256, FF, 0, stream>>>(out, FF, bnsum2);
  k_bnfin<<<1, FF, 0, stream>>>(bnsum2, bn2_g, bn2_b, ss2, FF);
  k_bnsig<<<(NN*FF + 255)/256, 256, 0, stream>>>(out, ss2, NN*FF);
}

// Round 4
// 352.918 us; speedup vs baseline: 2.7167x; 1.0544x over previous
//
#include <hip/hip_runtime.h>
#include <math.h>

#define NN 20000
#define FF 128
#define FF2 256
#define TT 4
#define NE 640000
#define NSEG (NN*TT)
#define MP 20032          // padded M (multiple of 64)
#define EPSBN 1e-5f

typedef short bf16x8 __attribute__((ext_vector_type(8)));
typedef float f32x4  __attribute__((ext_vector_type(4)));

__device__ __forceinline__ float sigf(float x){ return 1.0f/(1.0f+expf(-x)); }

__device__ __forceinline__ unsigned short f2bf(float x){
  union { float f; unsigned u; } v; v.f = x;
  unsigned r = v.u + 0x7FFF + ((v.u >> 16) & 1);
  return (unsigned short)(r >> 16);
}
__device__ __forceinline__ float bf2f(unsigned short u){
  union { float f; unsigned u; } v; v.u = ((unsigned)u) << 16; return v.f;
}
// monotone u16 key for bf16 bits (unsigned order == float order)
__device__ __forceinline__ unsigned short bfkey(unsigned short b){
  return (unsigned short)(b ^ ((b & 0x8000) ? 0xFFFF : 0x8000));
}

// ---------------- utility ----------------
__global__ void k_zero(int* __restrict__ p, int n){
  int i = blockIdx.x*blockDim.x + threadIdx.x;
  if(i < n) p[i] = 0;
}

// ---------------- oscillator -> A0 row-major [hi(128)|lo(128)] ----------------
__global__ void k_osc_pack(const float* __restrict__ x, const float* __restrict__ tbl,
                           unsigned short* __restrict__ A0){
  int i = blockIdx.x*256 + threadIdx.x;
  if(i >= NN*FF) return;
  int n = i >> 7, j = i & 127;
  float xv = x[i];
  float xi = (xv < -0.5f || xv > 0.5f) ? 0.5001f : xv;
  int idx = (int)floorf((xi + 0.5f) * 10000.0f);
  float tv = tbl[idx];
  float hv = (tv == 0.0f) ? sigf(xv) : tv;
  unsigned short hu = f2bf(hv);
  unsigned short lu = f2bf(hv - bf2f(hu));
  unsigned short* r = A0 + (size_t)n*256;
  r[j] = hu; r[128+j] = lu;
}

// ---------------- B packing ----------------
// generic: B = [hiW(C) | loW(C) | hiW(C) | conv(4C)] frag-packed [k8][COUT][8]
__global__ void k_packB(const float* __restrict__ lin_w, const float* __restrict__ conv_w,
                        unsigned short* __restrict__ Bp, int C, int COUT, int K){
  int i = blockIdx.x*256 + threadIdx.x;
  if(i >= K*COUT) return;
  int k = i / COUT, o = i - k*COUT;
  size_t dst = ((size_t)(k >> 3)*COUT + o)*8 + (k & 7);
  int reg = k / C;
  if(reg < 3){
    float w = lin_w[(size_t)o*C + (k - reg*C)];
    unsigned short hu = f2bf(w);
    Bp[dst] = (reg == 1) ? f2bf(w - bf2f(hu)) : hu;
  } else {
    int kk = k - 3*C; int t = kk / C; int c = kk - t*C;
    Bp[dst] = f2bf(conv_w[((size_t)t*COUT + o)*C + c]);
  }
}
// LSTM B0: gates i,g,o only (f skipped), COUT=384, K=384
__global__ void k_packB0(const float* __restrict__ w_ih, unsigned short* __restrict__ Bp){
  int i = blockIdx.x*256 + threadIdx.x;
  if(i >= 384*384) return;
  int k = i / 384, o = i - k*384;
  int grow = (o < 128) ? o : o + 128;      // i:[0,128) g:[256,384) o:[384,512)
  int reg = k >> 7, c = k & 127;
  float w = w_ih[(size_t)grow*128 + c];
  unsigned short hu = f2bf(w);
  unsigned short val = (reg == 1) ? f2bf(w - bf2f(hu)) : hu;
  Bp[((size_t)(k >> 3)*384 + o)*8 + (k & 7)] = val;
}

__global__ void k_mkbias(float* __restrict__ dst, const float* __restrict__ b1,
                         const float* __restrict__ b2, float s, int n){
  int i = threadIdx.x;
  if(i < n) dst[i] = b1[i] + s*b2[i];
}
__global__ void k_mkbias0(const float* __restrict__ bih, const float* __restrict__ bhh,
                          float* __restrict__ bias0){
  int o = threadIdx.x;
  if(o >= 384) return;
  int grow = (o < 128) ? o : o + 128;
  bias0[o] = bih[grow] + bhh[grow];
}

// ---------------- MFMA GEMM with hi/lo A reuse + split-K ----------------
// A row-major [MP][AK] bf16 = [hi(C) | lo(C) | agg(AK-2C)]
// B frag-packed [k8][COUT][8]  = [hiW(C) | loW(C) | hiW(C) | conv]
// A col ak<C pairs with B rows ak (hiW) AND C+ak (loW); ak>=C pairs with B row ak+C.
// Block: 64 rows x 128 cols; 4 waves each 32x64. Partial z -> out + z*NN*COUT (no bias).
template<int C, int COUT, int SPLITS, int AK>
__global__ __launch_bounds__(256)
void k_gemm(const unsigned short* __restrict__ A, const unsigned short* __restrict__ Bp,
            float* __restrict__ out){
  int w  = threadIdx.x >> 6;
  int l  = threadIdx.x & 63;
  int wr = w >> 1, wc = w & 1;
  int lr = l & 15, lg = l >> 4;
  int n0 = blockIdx.x*64 + wr*32;
  int c0 = blockIdx.y*128 + wc*64;
  int kb = blockIdx.z * (AK/SPLITS), ke = kb + AK/SPLITS;
  const unsigned short* arow0 = A + (size_t)(n0 + lr)*AK + lg*8;
  const unsigned short* arow1 = arow0 + (size_t)16*AK;
  f32x4 acc[2][4] = {};
  for(int ak = kb; ak < ke; ak += 32){
    bf16x8 a0 = *(const bf16x8*)(arow0 + ak);
    bf16x8 a1 = *(const bf16x8*)(arow1 + ak);
    if(ak < C){
      const unsigned short* b1p = Bp + (((size_t)(ak >> 3) + lg)*COUT + c0 + lr)*8;
      const unsigned short* b2p = Bp + (((size_t)((C + ak) >> 3) + lg)*COUT + c0 + lr)*8;
      #pragma unroll
      for(int j = 0; j < 4; ++j){
        bf16x8 b1 = *(const bf16x8*)(b1p + j*16*8);
        bf16x8 b2 = *(const bf16x8*)(b2p + j*16*8);
        acc[0][j] = __builtin_amdgcn_mfma_f32_16x16x32_bf16(a0, b1, acc[0][j], 0, 0, 0);
        acc[1][j] = __builtin_amdgcn_mfma_f32_16x16x32_bf16(a1, b1, acc[1][j], 0, 0, 0);
        acc[0][j] = __builtin_amdgcn_mfma_f32_16x16x32_bf16(a0, b2, acc[0][j], 0, 0, 0);
        acc[1][j] = __builtin_amdgcn_mfma_f32_16x16x32_bf16(a1, b2, acc[1][j], 0, 0, 0);
      }
    } else {
      const unsigned short* bp = Bp + (((size_t)((ak + C) >> 3) + lg)*COUT + c0 + lr)*8;
      #pragma unroll
      for(int j = 0; j < 4; ++j){
        bf16x8 b = *(const bf16x8*)(bp + j*16*8);
        acc[0][j] = __builtin_amdgcn_mfma_f32_16x16x32_bf16(a0, b, acc[0][j], 0, 0, 0);
        acc[1][j] = __builtin_amdgcn_mfma_f32_16x16x32_bf16(a1, b, acc[1][j], 0, 0, 0);
      }
    }
  }
  float* o = out + (size_t)blockIdx.z*NN*COUT;
  #pragma unroll
  for(int r = 0; r < 2; ++r){
    int nb = n0 + r*16 + lg*4;
    #pragma unroll
    for(int j = 0; j < 4; ++j){
      int oc = c0 + j*16 + lr;
      #pragma unroll
      for(int q = 0; q < 4; ++q){
        int n = nb + q;
        if(n < NN) o[(size_t)n*COUT + oc] = acc[r][j][q];
      }
    }
  }
}

// ---------------- split-K reduce + bias + BN stats ----------------
template<int COUT, int SPLITS>
__global__ __launch_bounds__(COUT)
void k_reduce(const float* __restrict__ P, const float* __restrict__ bias,
              float* __restrict__ h, float* __restrict__ sums){
  int c = threadIdx.x;
  float bs = bias[c];
  float s = 0.0f, s2 = 0.0f;
  for(int n = blockIdx.x; n < NN; n += gridDim.x){
    float v = bs;
    #pragma unroll
    for(int z = 0; z < SPLITS; ++z) v += P[(size_t)z*NN*COUT + (size_t)n*COUT + c];
    h[(size_t)n*COUT + c] = v;
    s += v; s2 += v*v;
  }
  atomicAdd(&sums[c], s);
  atomicAdd(&sums[COUT + c], s2);
}

// ---------------- LSTM activation (+bias) -> A1 [hi|lo] + key table ----------------
__global__ void k_act(const float* __restrict__ gates, const float* __restrict__ bias0,
                      unsigned short* __restrict__ A1, unsigned short* __restrict__ h1k){
  int i = blockIdx.x*256 + threadIdx.x;
  if(i >= NN*FF) return;
  int n = i >> 7, j = i & 127;
  const float* g = gates + (size_t)n*384;
  float ig = g[j]       + bias0[j];
  float gg = g[128 + j] + bias0[128 + j];
  float og = g[256 + j] + bias0[256 + j];
  float c  = sigf(ig) * tanhf(gg);
  float hv = sigf(og) * tanhf(c);
  unsigned short hu = f2bf(hv);
  unsigned short lu = f2bf(hv - bf2f(hu));
  unsigned short* r = A1 + (size_t)n*768;
  r[j] = hu; r[128 + j] = lu;
  h1k[i] = bfkey(hu);
}

// ---------------- CSR build over seg = dst*T + etype ----------------
__global__ void k_count(const int* __restrict__ dst, const int* __restrict__ et,
                        int* __restrict__ counts){
  int e = blockIdx.x*blockDim.x + threadIdx.x;
  if(e >= NE) return;
  atomicAdd(&counts[dst[e]*TT + et[e]], 1);
}
__global__ void k_scan_block(const int* __restrict__ in, int* __restrict__ out,
                             int* __restrict__ bsums, int n){
  __shared__ int s[256];
  int i = blockIdx.x*256 + threadIdx.x;
  int v = (i < n) ? in[i] : 0;
  s[threadIdx.x] = v; __syncthreads();
  for(int off = 1; off < 256; off <<= 1){
    int add = (threadIdx.x >= off) ? s[threadIdx.x - off] : 0;
    __syncthreads();
    s[threadIdx.x] += add;
    __syncthreads();
  }
  if(i < n) out[i] = s[threadIdx.x];
  if(threadIdx.x == 255) bsums[blockIdx.x] = s[255];
}
__global__ void k_scan_bsums(int* __restrict__ bsums, int nb){
  __shared__ int s[512];
  int v = (threadIdx.x < nb) ? bsums[threadIdx.x] : 0;
  s[threadIdx.x] = v; __syncthreads();
  for(int off = 1; off < 512; off <<= 1){
    int add = (threadIdx.x >= off) ? s[threadIdx.x - off] : 0;
    __syncthreads();
    s[threadIdx.x] += add;
    __syncthreads();
  }
  if(threadIdx.x < nb) bsums[threadIdx.x] = s[threadIdx.x];
}
__global__ void k_scan_add(int* __restrict__ out, const int* __restrict__ bsums, int n){
  int i = blockIdx.x*256 + threadIdx.x;
  if(i >= n || blockIdx.x == 0) return;
  out[i] += bsums[blockIdx.x - 1];
}
__global__ void k_scatter(const int* __restrict__ src, const int* __restrict__ dst,
                          const int* __restrict__ et, const int* __restrict__ counts,
                          const int* __restrict__ incl, int* __restrict__ cursor,
                          int* __restrict__ elist){
  int e = blockIdx.x*blockDim.x + threadIdx.x;
  if(e >= NE) return;
  int seg = dst[e]*TT + et[e];
  int base = incl[seg] - counts[seg];
  int pos = atomicAdd(&cursor[seg], 1);
  elist[base + pos] = src[e];
}

// ---------------- per-segment max over u16 keys -> A agg block ----------------
// one wave per segment; 2 rows per load (32 lanes x VW chans each), pk_max_u16
template<int C, int AK>
__global__ __launch_bounds__(256)
void k_agg(const unsigned short* __restrict__ keys, const int* __restrict__ elist,
           const int* __restrict__ incl, const int* __restrict__ counts,
           unsigned short* __restrict__ A){
  constexpr int VW = C/32;
  typedef unsigned short kvec __attribute__((ext_vector_type(VW)));
  int seg  = blockIdx.x*4 + (threadIdx.x >> 6);
  int l    = threadIdx.x & 63;
  int half = l >> 5;
  int cl   = l & 31;
  int cnt = counts[seg];
  int start = incl[seg] - cnt;
  const unsigned short* kp = keys + cl*VW;
  kvec m = {};
  int i = 0;
  for(; i + 8 <= cnt; i += 8){
    int e0 = elist[start+i+half],   e1 = elist[start+i+2+half];
    int e2 = elist[start+i+4+half], e3 = elist[start+i+6+half];
    kvec v0 = *(const kvec*)(kp + (size_t)e0*C);
    kvec v1 = *(const kvec*)(kp + (size_t)e1*C);
    kvec v2 = *(const kvec*)(kp + (size_t)e2*C);
    kvec v3 = *(const kvec*)(kp + (size_t)e3*C);
    kvec t0 = __builtin_elementwise_max(v0, v1);
    kvec t1 = __builtin_elementwise_max(v2, v3);
    m = __builtin_elementwise_max(m, __builtin_elementwise_max(t0, t1));
  }
  for(; i + 2 <= cnt; i += 2){
    int e = elist[start+i+half];
    kvec v = *(const kvec*)(kp + (size_t)e*C);
    m = __builtin_elementwise_max(m, v);
  }
  if(i < cnt && half == 0){
    int e = elist[start+i];
    kvec v = *(const kvec*)(kp + (size_t)e*C);
    m = __builtin_elementwise_max(m, v);
  }
  // merge the two halves (lanes l and l^32 hold the same channels)
  union Ux { kvec v; int w[VW/2]; };
  Ux a, b; a.v = m;
  #pragma unroll
  for(int q = 0; q < VW/2; ++q) b.w[q] = __shfl_xor(a.w[q], 32);
  m = __builtin_elementwise_max(a.v, b.v);
  if(half == 0){
    int n = seg >> 2, t = seg & 3;
    kvec o;
    #pragma unroll
    for(int q = 0; q < VW; ++q){
      unsigned short k = m[q];
      unsigned short bb = (k & 0x8000) ? (unsigned short)(k ^ 0x8000) : (unsigned short)(~k);
      o[q] = (cnt == 0) ? (unsigned short)0 : bb;
    }
    *(kvec*)(A + (size_t)n*AK + 2*C + t*C + cl*VW) = o;
  }
}

// ---------------- BN1(inline finalize) + ReLU -> A2 [hi|lo] + key table ----------------
__global__ void k_bnrp(const float* __restrict__ h2, const float* __restrict__ sums,
                       const float* __restrict__ g, const float* __restrict__ bb,
                       unsigned short* __restrict__ A2, unsigned short* __restrict__ h2k){
  int i = blockIdx.x*256 + threadIdx.x;
  if(i >= NN*FF2) return;
  int n = i >> 8, c = i & 255;
  float mean = sums[c] * (1.0f/NN);
  float var  = sums[256 + c] * (1.0f/NN) - mean*mean;
  float scale = g[c] / sqrtf(var + EPSBN);
  float shift = bb[c] - mean*scale;
  float v = fmaxf(h2[i]*scale + shift, 0.0f);
  unsigned short hu = f2bf(v);
  unsigned short lu = f2bf(v - bf2f(hu));
  unsigned short* r = A2 + (size_t)n*1536;
  r[c] = hu; r[256 + c] = lu;
  h2k[i] = (unsigned short)(hu | 0x8000);
}

// ---------------- BN2(inline finalize) + sigmoid(x-10), in place ----------------
__global__ void k_bnsig(float* __restrict__ h, const float* __restrict__ sums,
                        const float* __restrict__ g, const float* __restrict__ bb){
  int i = blockIdx.x*256 + threadIdx.x;
  if(i >= NN*FF) return;
  int c = i & 127;
  float mean = sums[c] * (1.0f/NN);
  float var  = sums[128 + c] * (1.0f/NN) - mean*mean;
  float scale = g[c] / sqrtf(var + EPSBN);
  float shift = bb[c] - mean*scale;
  float v = h[i]*scale + shift - 10.0f;
  h[i] = 1.0f/(1.0f + expf(-v));
}

// ---------------- launch ----------------
extern "C" void kernel_launch(void* const* d_in, const int* in_sizes, int n_in,
                              void* d_out, int out_size, void* d_ws, size_t ws_size,
                              hipStream_t stream){
  (void)in_sizes; (void)n_in; (void)out_size; (void)ws_size;
  const float* x       = (const float*)d_in[0];
  const float* tbl     = (const float*)d_in[1];
  const int*   eidx    = (const int*)  d_in[2];
  const int*   etype   = (const int*)  d_in[3];
  const float* w_ih    = (const float*)d_in[4];
  const float* b_ih    = (const float*)d_in[6];
  const float* b_hh    = (const float*)d_in[7];
  const float* conv1_w = (const float*)d_in[8];
  const float* conv1_b = (const float*)d_in[9];
  const float* conv2_w = (const float*)d_in[10];
  const float* conv2_b = (const float*)d_in[11];
  const float* lin1_w  = (const float*)d_in[12];
  const float* lin1_b  = (const float*)d_in[13];
  const float* lin2_w  = (const float*)d_in[14];
  const float* lin2_b  = (const float*)d_in[15];
  const float* bn1_g   = (const float*)d_in[16];
  const float* bn1_b   = (const float*)d_in[17];
  const float* bn2_g   = (const float*)d_in[18];
  const float* bn2_b   = (const float*)d_in[19];
  float* out = (float*)d_out;

  char* base = (char*)d_ws;
  size_t off = 0;
  auto alloc = [&](size_t bytes){ char* p = base + off; off = (off + bytes + 255) & ~(size_t)255; return p; };

  unsigned short* A0 = (unsigned short*)alloc((size_t)MP * 256 * 2);   // 10.26 MB
  unsigned short* A1 = (unsigned short*)alloc((size_t)MP * 768 * 2);   // 30.77 MB
  unsigned short* A2 = (unsigned short*)alloc((size_t)MP * 1536 * 2);  // 61.54 MB
  float* h2raw = (float*)alloc((size_t)NN * 256 * 4);                  // 20.48 MB
  unsigned short* h1k = (unsigned short*)alloc((size_t)NN * 128 * 2);  // 5.12 MB
  unsigned short* h2k = (unsigned short*)alloc((size_t)NN * 256 * 2);  // 10.24 MB
  unsigned short* Bp0 = (unsigned short*)alloc((size_t)384 * 384 * 2);
  unsigned short* Bp1 = (unsigned short*)alloc((size_t)896 * 256 * 2);
  unsigned short* Bp2 = (unsigned short*)alloc((size_t)1792 * 128 * 2);
  float* bias0 = (float*)alloc(384 * 4);
  float* bias1 = (float*)alloc(256 * 4);
  float* bias2 = (float*)alloc(128 * 4);
  int* counts  = (int*)alloc(NSEG * 4);
  int* cursor  = (int*)alloc(NSEG * 4);
  float* bnsum1 = (float*)alloc(512 * 4);
  float* bnsum2 = (float*)alloc(256 * 4);
  int* incl    = (int*)alloc(NSEG * 4);
  int* bsums   = (int*)alloc(512 * 4);
  int* elist   = (int*)alloc((size_t)NE * 4);

  // aliases (lifetimes disjoint; all sizes 256B-aligned so regions are contiguous)
  float* gates = (float*)A2;     // NN*384*4 = 30.7 MB, dead after k_act
  float* P1    = (float*)A2;     // 2*NN*256*4 = 41 MB, dead before k_bnrp writes A2
  float* P2    = (float*)A0;     // 4*NN*128*4 = 41 MB, spans A0+A1 (both dead by gemm2)

  const int* src = eidx;
  const int* dst = eidx + NE;

  // zero counts+cursor+bnsum1+bnsum2 (contiguous)
  k_zero<<<(2*NSEG + 768 + 255)/256, 256, 0, stream>>>(counts, 2*NSEG + 768);

  // pack weights + biases
  k_packB0<<<(384*384 + 255)/256, 256, 0, stream>>>(w_ih, Bp0);
  k_packB<<<(896*256 + 255)/256, 256, 0, stream>>>(lin1_w, conv1_w, Bp1, 128, 256, 896);
  k_packB<<<(1792*128 + 255)/256, 256, 0, stream>>>(lin2_w, conv2_w, Bp2, 256, 128, 1792);
  k_mkbias0<<<1, 384, 0, stream>>>(b_ih, b_hh, bias0);
  k_mkbias<<<1, 256, 0, stream>>>(bias1, lin1_b, conv1_b, 4.0f, 256);
  k_mkbias<<<1, 128, 0, stream>>>(bias2, lin2_b, conv2_b, 4.0f, 128);

  k_osc_pack<<<(NN*FF + 255)/256, 256, 0, stream>>>(x, tbl, A0);

  // CSR
  k_count<<<(NE + 255)/256, 256, 0, stream>>>(dst, etype, counts);
  k_scan_block<<<(NSEG + 255)/256, 256, 0, stream>>>(counts, incl, bsums, NSEG);
  k_scan_bsums<<<1, 512, 0, stream>>>(bsums, (NSEG + 255)/256);
  k_scan_add<<<(NSEG + 255)/256, 256, 0, stream>>>(incl, bsums, NSEG);
  k_scatter<<<(NE + 255)/256, 256, 0, stream>>>(src, dst, etype, counts, incl, cursor, elist);

  // LSTM: gates (i,g,o) = A0 x B0; bias+activation fused in k_act
  k_gemm<128, 384, 1, 256><<<dim3(313, 3, 1), 256, 0, stream>>>(A0, Bp0, gates);
  k_act<<<(NN*FF + 255)/256, 256, 0, stream>>>(gates, bias0, A1, h1k);

  // layer 1
  k_agg<128, 768><<<NSEG/4, 256, 0, stream>>>(h1k, elist, incl, counts, A1);
  k_gemm<128, 256, 2, 768><<<dim3(313, 2, 2), 256, 0, stream>>>(A1, Bp1, P1);
  k_reduce<256, 2><<<256, 256, 0, stream>>>(P1, bias1, h2raw, bnsum1);
  k_bnrp<<<(NN*FF2 + 255)/256, 256, 0, stream>>>(h2raw, bnsum1, bn1_g, bn1_b, A2, h2k);

  // layer 2
  k_agg<256, 1536><<<NSEG/4, 256, 0, stream>>>(h2k, elist, incl, counts, A2);
  k_gemm<256, 128, 4, 1536><<<dim3(313, 1, 4), 256, 0, stream>>>(A2, Bp2, P2);
  k_reduce<128, 4><<<256, 128, 0, stream>>>(P2, bias2, out, bnsum2);
  k_bnsig<<<(NN*FF + 255)/256, 256, 0, stream>>>(out, bnsum2, bn2_g, bn2_b);
}

// Round 5
// 346.894 us; speedup vs baseline: 2.7639x; 1.0174x over previous
//
#include <hip/hip_runtime.h>
#include <math.h>

#define NN 20000
#define FF 128
#define FF2 256
#define TT 4
#define NE 640000
#define NSEG (NN*TT)
#define MP 20096          // padded M (multiple of 128)
#define EPSBN 1e-5f

typedef short bf16x8 __attribute__((ext_vector_type(8)));
typedef float f32x4  __attribute__((ext_vector_type(4)));

__device__ __forceinline__ float sigf(float x){ return 1.0f/(1.0f+expf(-x)); }

__device__ __forceinline__ unsigned short f2bf(float x){
  union { float f; unsigned u; } v; v.f = x;
  unsigned r = v.u + 0x7FFF + ((v.u >> 16) & 1);
  return (unsigned short)(r >> 16);
}
__device__ __forceinline__ float bf2f(unsigned short u){
  union { float f; unsigned u; } v; v.u = ((unsigned)u) << 16; return v.f;
}
// monotone u16 key for bf16 bits (unsigned order == float order)
__device__ __forceinline__ unsigned short bfkey(unsigned short b){
  return (unsigned short)(b ^ ((b & 0x8000) ? 0xFFFF : 0x8000));
}

// ---------------- utility ----------------
__global__ void k_zero(int* __restrict__ p, int n){
  int i = blockIdx.x*blockDim.x + threadIdx.x;
  if(i < n) p[i] = 0;
}

// ---------------- oscillator -> A0 row-major [hi(128)|lo(128)] ----------------
__global__ void k_osc_pack(const float* __restrict__ x, const float* __restrict__ tbl,
                           unsigned short* __restrict__ A0){
  int i = blockIdx.x*256 + threadIdx.x;
  if(i >= NN*FF) return;
  int n = i >> 7, j = i & 127;
  float xv = x[i];
  float xi = (xv < -0.5f || xv > 0.5f) ? 0.5001f : xv;
  int idx = (int)floorf((xi + 0.5f) * 10000.0f);
  float tv = tbl[idx];
  float hv = (tv == 0.0f) ? sigf(xv) : tv;
  unsigned short hu = f2bf(hv);
  unsigned short lu = f2bf(hv - bf2f(hu));
  unsigned short* r = A0 + (size_t)n*256;
  r[j] = hu; r[128+j] = lu;
}

// ---------------- B packing ----------------
// generic: B = [hiW(C) | loW(C) | hiW(C) | conv(4C)] frag-packed [k8][COUT][8]
__global__ void k_packB(const float* __restrict__ lin_w, const float* __restrict__ conv_w,
                        unsigned short* __restrict__ Bp, int C, int COUT, int K){
  int i = blockIdx.x*256 + threadIdx.x;
  if(i >= K*COUT) return;
  int k = i / COUT, o = i - k*COUT;
  size_t dst = ((size_t)(k >> 3)*COUT + o)*8 + (k & 7);
  int reg = k / C;
  if(reg < 3){
    float w = lin_w[(size_t)o*C + (k - reg*C)];
    unsigned short hu = f2bf(w);
    Bp[dst] = (reg == 1) ? f2bf(w - bf2f(hu)) : hu;
  } else {
    int kk = k - 3*C; int t = kk / C; int c = kk - t*C;
    Bp[dst] = f2bf(conv_w[((size_t)t*COUT + o)*C + c]);
  }
}
// LSTM B0: gates i,g,o only (f skipped), COUT=384, K=384
__global__ void k_packB0(const float* __restrict__ w_ih, unsigned short* __restrict__ Bp){
  int i = blockIdx.x*256 + threadIdx.x;
  if(i >= 384*384) return;
  int k = i / 384, o = i - k*384;
  int grow = (o < 128) ? o : o + 128;      // i:[0,128) g:[256,384) o:[384,512)
  int reg = k >> 7, c = k & 127;
  float w = w_ih[(size_t)grow*128 + c];
  unsigned short hu = f2bf(w);
  unsigned short val = (reg == 1) ? f2bf(w - bf2f(hu)) : hu;
  Bp[((size_t)(k >> 3)*384 + o)*8 + (k & 7)] = val;
}

__global__ void k_mkbias(float* __restrict__ dst, const float* __restrict__ b1,
                         const float* __restrict__ b2, float s, int n){
  int i = threadIdx.x;
  if(i < n) dst[i] = b1[i] + s*b2[i];
}
__global__ void k_mkbias0(const float* __restrict__ bih, const float* __restrict__ bhh,
                          float* __restrict__ bias0){
  int o = threadIdx.x;
  if(o >= 384) return;
  int grow = (o < 128) ? o : o + 128;
  bias0[o] = bih[grow] + bhh[grow];
}

// ---------------- MFMA GEMM, 64x64 per wave, hi/lo A reuse + balanced split-K ----
// A row-major [MP][AK] bf16 = [hi(C) | lo(C) | agg(AK-2C)]
// B frag-packed [k8][COUT][8] = [hiW(C) | loW(C) | hiW(C) | conv]
// A col ak<C pairs with B rows ak (hiW) AND C+ak (loW); ak>=C pairs with B row ak+C.
// Block: 128 rows x 128 cols = 4 waves (2x2), each wave 64x64 (4x4 frags 16x16x32).
// Split z covers A-cols [kb,ke) chosen so MFMA-K (dual counts 2x) is equal per z.
template<int C, int COUT, int SPLITS, int AK>
__global__ __launch_bounds__(256)
void k_gemm(const unsigned short* __restrict__ A, const unsigned short* __restrict__ Bp,
            float* __restrict__ out){
  int w  = threadIdx.x >> 6;
  int l  = threadIdx.x & 63;
  int wr = w >> 1, wc = w & 1;
  int lr = l & 15, lg = l >> 4;
  int n0 = blockIdx.x*128 + wr*64;
  int c0 = blockIdx.y*128 + wc*64;
  constexpr int Q = (AK + C)/SPLITS;   // MFMA-K per split
  int zq0 = blockIdx.z*Q, zq1 = zq0 + Q;
  int kb = (zq0 <= 2*C) ? (zq0 >> 1) : (zq0 - C);
  int ke = (zq1 <= 2*C) ? (zq1 >> 1) : (zq1 - C);
  const size_t abase = (size_t)(n0 + lr)*AK + lg*8;
  const size_t bstep = (size_t)COUT*8;
  const unsigned short* bcolp = Bp + (size_t)(c0 + lr)*8 + lg*bstep;
  f32x4 acc[4][4] = {};
  int kde = ke < C ? ke : C;
  for(int ak = kb; ak < kde; ak += 32){
    bf16x8 a[4];
    #pragma unroll
    for(int r = 0; r < 4; ++r) a[r] = *(const bf16x8*)(A + abase + (size_t)r*16*AK + ak);
    const unsigned short* p1 = bcolp + (size_t)(ak >> 3)*bstep;
    const unsigned short* p2 = bcolp + (size_t)((C + ak) >> 3)*bstep;
    #pragma unroll
    for(int j = 0; j < 4; ++j){
      bf16x8 b1 = *(const bf16x8*)(p1 + j*128);
      bf16x8 b2 = *(const bf16x8*)(p2 + j*128);
      #pragma unroll
      for(int r = 0; r < 4; ++r){
        acc[r][j] = __builtin_amdgcn_mfma_f32_16x16x32_bf16(a[r], b1, acc[r][j], 0, 0, 0);
        acc[r][j] = __builtin_amdgcn_mfma_f32_16x16x32_bf16(a[r], b2, acc[r][j], 0, 0, 0);
      }
    }
  }
  int ks = kb > C ? kb : C;
  for(int ak = ks; ak < ke; ak += 32){
    bf16x8 a[4];
    #pragma unroll
    for(int r = 0; r < 4; ++r) a[r] = *(const bf16x8*)(A + abase + (size_t)r*16*AK + ak);
    const unsigned short* p = bcolp + (size_t)((C + ak) >> 3)*bstep;
    #pragma unroll
    for(int j = 0; j < 4; ++j){
      bf16x8 b = *(const bf16x8*)(p + j*128);
      #pragma unroll
      for(int r = 0; r < 4; ++r)
        acc[r][j] = __builtin_amdgcn_mfma_f32_16x16x32_bf16(a[r], b, acc[r][j], 0, 0, 0);
    }
  }
  float* o = out + (size_t)blockIdx.z*NN*COUT;
  #pragma unroll
  for(int r = 0; r < 4; ++r){
    int nb = n0 + r*16 + lg*4;
    #pragma unroll
    for(int j = 0; j < 4; ++j){
      int oc = c0 + j*16 + lr;
      #pragma unroll
      for(int q = 0; q < 4; ++q){
        int n = nb + q;
        if(n < NN) o[(size_t)n*COUT + oc] = acc[r][j][q];
      }
    }
  }
}

// ---------------- split-K reduce + bias + BN stats ----------------
template<int COUT, int SPLITS>
__global__ __launch_bounds__(COUT)
void k_reduce(const float* __restrict__ P, const float* __restrict__ bias,
              float* __restrict__ h, float* __restrict__ sums){
  int c = threadIdx.x;
  float bs = bias[c];
  float s = 0.0f, s2 = 0.0f;
  for(int n = blockIdx.x; n < NN; n += gridDim.x){
    float v = bs;
    #pragma unroll
    for(int z = 0; z < SPLITS; ++z) v += P[(size_t)z*NN*COUT + (size_t)n*COUT + c];
    h[(size_t)n*COUT + c] = v;
    s += v; s2 += v*v;
  }
  atomicAdd(&sums[c], s);
  atomicAdd(&sums[COUT + c], s2);
}

// ---------------- LSTM activation (+bias) -> A1 [hi|lo] + key table ----------------
__global__ void k_act(const float* __restrict__ gates, const float* __restrict__ bias0,
                      unsigned short* __restrict__ A1, unsigned short* __restrict__ h1k){
  int i = blockIdx.x*256 + threadIdx.x;
  if(i >= NN*FF) return;
  int n = i >> 7, j = i & 127;
  const float* g = gates + (size_t)n*384;
  float ig = g[j]       + bias0[j];
  float gg = g[128 + j] + bias0[128 + j];
  float og = g[256 + j] + bias0[256 + j];
  float c  = sigf(ig) * tanhf(gg);
  float hv = sigf(og) * tanhf(c);
  unsigned short hu = f2bf(hv);
  unsigned short lu = f2bf(hv - bf2f(hu));
  unsigned short* r = A1 + (size_t)n*768;
  r[j] = hu; r[128 + j] = lu;
  h1k[i] = bfkey(hu);
}

// ---------------- CSR build over seg = dst*T + etype ----------------
__global__ void k_count(const int* __restrict__ dst, const int* __restrict__ et,
                        int* __restrict__ counts){
  int e = blockIdx.x*blockDim.x + threadIdx.x;
  if(e >= NE) return;
  atomicAdd(&counts[dst[e]*TT + et[e]], 1);
}
// block-level inclusive scan, emits EXCLUSIVE prefix + block sums
__global__ void k_scan_block(const int* __restrict__ in, int* __restrict__ excl,
                             int* __restrict__ bsums, int n){
  __shared__ int s[256];
  int i = blockIdx.x*256 + threadIdx.x;
  int v = (i < n) ? in[i] : 0;
  s[threadIdx.x] = v; __syncthreads();
  for(int off = 1; off < 256; off <<= 1){
    int add = (threadIdx.x >= off) ? s[threadIdx.x - off] : 0;
    __syncthreads();
    s[threadIdx.x] += add;
    __syncthreads();
  }
  if(i < n) excl[i] = s[threadIdx.x] - v;
  if(threadIdx.x == 255) bsums[blockIdx.x] = s[255];
}
__global__ void k_scan_bsums(int* __restrict__ bsums, int nb){
  __shared__ int s[512];
  int v = (threadIdx.x < nb) ? bsums[threadIdx.x] : 0;
  s[threadIdx.x] = v; __syncthreads();
  for(int off = 1; off < 512; off <<= 1){
    int add = (threadIdx.x >= off) ? s[threadIdx.x - off] : 0;
    __syncthreads();
    s[threadIdx.x] += add;
    __syncthreads();
  }
  if(threadIdx.x < nb) bsums[threadIdx.x] = s[threadIdx.x];
}
__global__ void k_scan_add(int* __restrict__ excl, const int* __restrict__ bsums, int n){
  int i = blockIdx.x*256 + threadIdx.x;
  if(i >= n || blockIdx.x == 0) return;
  excl[i] += bsums[blockIdx.x - 1];
}
// 2 edges per thread: two independent random-access chains
__global__ void k_scatter(const int* __restrict__ src, const int* __restrict__ dst,
                          const int* __restrict__ et, const int* __restrict__ excl,
                          int* __restrict__ cursor, int* __restrict__ elist){
  int i = blockIdx.x*blockDim.x + threadIdx.x;
  int e0 = i*2;
  if(e0 >= NE) return;
  int e1 = e0 + 1;
  int s0 = src[e0], s1 = src[e1];
  int g0 = dst[e0]*TT + et[e0];
  int g1 = dst[e1]*TT + et[e1];
  int b0 = excl[g0];
  int b1 = excl[g1];
  int p0 = atomicAdd(&cursor[g0], 1);
  int p1 = atomicAdd(&cursor[g1], 1);
  __builtin_nontemporal_store(s0, &elist[b0 + p0]);
  __builtin_nontemporal_store(s1, &elist[b1 + p1]);
}

// ---------------- per-segment max over u16 keys -> A agg block ----------------
// one wave per segment; 2 rows per load (32 lanes x VW chans each), pk_max_u16
template<int C, int AK>
__global__ __launch_bounds__(256)
void k_agg(const unsigned short* __restrict__ keys, const int* __restrict__ elist,
           const int* __restrict__ excl, const int* __restrict__ counts,
           unsigned short* __restrict__ A){
  constexpr int VW = C/32;
  typedef unsigned short kvec __attribute__((ext_vector_type(VW)));
  int seg  = blockIdx.x*4 + (threadIdx.x >> 6);
  int l    = threadIdx.x & 63;
  int half = l >> 5;
  int cl   = l & 31;
  int cnt = counts[seg];
  int start = excl[seg];
  const unsigned short* kp = keys + cl*VW;
  kvec m = {};
  int i = 0;
  for(; i + 8 <= cnt; i += 8){
    int e0 = elist[start+i+half],   e1 = elist[start+i+2+half];
    int e2 = elist[start+i+4+half], e3 = elist[start+i+6+half];
    kvec v0 = *(const kvec*)(kp + (size_t)e0*C);
    kvec v1 = *(const kvec*)(kp + (size_t)e1*C);
    kvec v2 = *(const kvec*)(kp + (size_t)e2*C);
    kvec v3 = *(const kvec*)(kp + (size_t)e3*C);
    kvec t0 = __builtin_elementwise_max(v0, v1);
    kvec t1 = __builtin_elementwise_max(v2, v3);
    m = __builtin_elementwise_max(m, __builtin_elementwise_max(t0, t1));
  }
  for(; i + 2 <= cnt; i += 2){
    int e = elist[start+i+half];
    kvec v = *(const kvec*)(kp + (size_t)e*C);
    m = __builtin_elementwise_max(m, v);
  }
  if(i < cnt && half == 0){
    int e = elist[start+i];
    kvec v = *(const kvec*)(kp + (size_t)e*C);
    m = __builtin_elementwise_max(m, v);
  }
  // merge the two halves (lanes l and l^32 hold the same channels)
  union Ux { kvec v; int w[VW/2]; };
  Ux a, b; a.v = m;
  #pragma unroll
  for(int q = 0; q < VW/2; ++q) b.w[q] = __shfl_xor(a.w[q], 32);
  m = __builtin_elementwise_max(a.v, b.v);
  if(half == 0){
    int n = seg >> 2, t = seg & 3;
    kvec o;
    #pragma unroll
    for(int q = 0; q < VW; ++q){
      unsigned short k = m[q];
      unsigned short bb = (k & 0x8000) ? (unsigned short)(k ^ 0x8000) : (unsigned short)(~k);
      o[q] = (cnt == 0) ? (unsigned short)0 : bb;
    }
    *(kvec*)(A + (size_t)n*AK + 2*C + t*C + cl*VW) = o;
  }
}

// ---------------- BN1(inline finalize) + ReLU -> A2 [hi|lo] + key table ----------------
__global__ void k_bnrp(const float* __restrict__ h2, const float* __restrict__ sums,
                       const float* __restrict__ g, const float* __restrict__ bb,
                       unsigned short* __restrict__ A2, unsigned short* __restrict__ h2k){
  int i = blockIdx.x*256 + threadIdx.x;
  if(i >= NN*FF2) return;
  int n = i >> 8, c = i & 255;
  float mean = sums[c] * (1.0f/NN);
  float var  = sums[256 + c] * (1.0f/NN) - mean*mean;
  float scale = g[c] / sqrtf(var + EPSBN);
  float shift = bb[c] - mean*scale;
  float v = fmaxf(h2[i]*scale + shift, 0.0f);
  unsigned short hu = f2bf(v);
  unsigned short lu = f2bf(v - bf2f(hu));
  unsigned short* r = A2 + (size_t)n*1536;
  r[c] = hu; r[256 + c] = lu;
  h2k[i] = (unsigned short)(hu | 0x8000);
}

// ---------------- BN2(inline finalize) + sigmoid(x-10), in place ----------------
__global__ void k_bnsig(float* __restrict__ h, const float* __restrict__ sums,
                        const float* __restrict__ g, const float* __restrict__ bb){
  int i = blockIdx.x*256 + threadIdx.x;
  if(i >= NN*FF) return;
  int c = i & 127;
  float mean = sums[c] * (1.0f/NN);
  float var  = sums[128 + c] * (1.0f/NN) - mean*mean;
  float scale = g[c] / sqrtf(var + EPSBN);
  float shift = bb[c] - mean*scale;
  float v = h[i]*scale + shift - 10.0f;
  h[i] = 1.0f/(1.0f + expf(-v));
}

// ---------------- launch ----------------
extern "C" void kernel_launch(void* const* d_in, const int* in_sizes, int n_in,
                              void* d_out, int out_size, void* d_ws, size_t ws_size,
                              hipStream_t stream){
  (void)in_sizes; (void)n_in; (void)out_size; (void)ws_size;
  const float* x       = (const float*)d_in[0];
  const float* tbl     = (const float*)d_in[1];
  const int*   eidx    = (const int*)  d_in[2];
  const int*   etype   = (const int*)  d_in[3];
  const float* w_ih    = (const float*)d_in[4];
  const float* b_ih    = (const float*)d_in[6];
  const float* b_hh    = (const float*)d_in[7];
  const float* conv1_w = (const float*)d_in[8];
  const float* conv1_b = (const float*)d_in[9];
  const float* conv2_w = (const float*)d_in[10];
  const float* conv2_b = (const float*)d_in[11];
  const float* lin1_w  = (const float*)d_in[12];
  const float* lin1_b  = (const float*)d_in[13];
  const float* lin2_w  = (const float*)d_in[14];
  const float* lin2_b  = (const float*)d_in[15];
  const float* bn1_g   = (const float*)d_in[16];
  const float* bn1_b   = (const float*)d_in[17];
  const float* bn2_g   = (const float*)d_in[18];
  const float* bn2_b   = (const float*)d_in[19];
  float* out = (float*)d_out;

  char* base = (char*)d_ws;
  size_t off = 0;
  auto alloc = [&](size_t bytes){ char* p = base + off; off = (off + bytes + 255) & ~(size_t)255; return p; };

  unsigned short* A0 = (unsigned short*)alloc((size_t)MP * 256 * 2);   // 10.29 MB
  unsigned short* A1 = (unsigned short*)alloc((size_t)MP * 768 * 2);   // 30.87 MB
  unsigned short* A2 = (unsigned short*)alloc((size_t)MP * 1536 * 2);  // 61.73 MB
  float* h2raw = (float*)alloc((size_t)NN * 256 * 4);                  // 20.48 MB
  unsigned short* h1k = (unsigned short*)alloc((size_t)NN * 128 * 2);  // 5.12 MB
  unsigned short* h2k = (unsigned short*)alloc((size_t)NN * 256 * 2);  // 10.24 MB
  unsigned short* Bp0 = (unsigned short*)alloc((size_t)384 * 384 * 2);
  unsigned short* Bp1 = (unsigned short*)alloc((size_t)896 * 256 * 2);
  unsigned short* Bp2 = (unsigned short*)alloc((size_t)1792 * 128 * 2);
  float* bias0 = (float*)alloc(384 * 4);
  float* bias1 = (float*)alloc(256 * 4);
  float* bias2 = (float*)alloc(128 * 4);
  int* counts  = (int*)alloc(NSEG * 4);
  int* cursor  = (int*)alloc(NSEG * 4);
  float* bnsum1 = (float*)alloc(512 * 4);
  float* bnsum2 = (float*)alloc(256 * 4);
  int* excl    = (int*)alloc(NSEG * 4);
  int* bsums   = (int*)alloc(512 * 4);
  int* elist   = (int*)alloc((size_t)NE * 4);

  // aliases (lifetimes disjoint; all region sizes are 256B-aligned)
  float* gates = (float*)A2;     // MP*384*4 = 30.9 MB, dead after k_act
  float* P1    = (float*)A2;     // 2*NN*256*4 = 41 MB, dead before k_bnrp writes A2
  float* P2    = (float*)A0;     // 4*NN*128*4 = 41 MB, spans A0+A1 (both dead by gemm2)

  const int* src = eidx;
  const int* dst = eidx + NE;

  // zero counts+cursor+bnsum1+bnsum2 (contiguous)
  k_zero<<<(2*NSEG + 768 + 255)/256, 256, 0, stream>>>(counts, 2*NSEG + 768);

  // pack weights + biases
  k_packB0<<<(384*384 + 255)/256, 256, 0, stream>>>(w_ih, Bp0);
  k_packB<<<(896*256 + 255)/256, 256, 0, stream>>>(lin1_w, conv1_w, Bp1, 128, 256, 896);
  k_packB<<<(1792*128 + 255)/256, 256, 0, stream>>>(lin2_w, conv2_w, Bp2, 256, 128, 1792);
  k_mkbias0<<<1, 384, 0, stream>>>(b_ih, b_hh, bias0);
  k_mkbias<<<1, 256, 0, stream>>>(bias1, lin1_b, conv1_b, 4.0f, 256);
  k_mkbias<<<1, 128, 0, stream>>>(bias2, lin2_b, conv2_b, 4.0f, 128);

  k_osc_pack<<<(NN*FF + 255)/256, 256, 0, stream>>>(x, tbl, A0);

  // CSR (exclusive offsets)
  k_count<<<(NE + 255)/256, 256, 0, stream>>>(dst, etype, counts);
  k_scan_block<<<(NSEG + 255)/256, 256, 0, stream>>>(counts, excl, bsums, NSEG);
  k_scan_bsums<<<1, 512, 0, stream>>>(bsums, (NSEG + 255)/256);
  k_scan_add<<<(NSEG + 255)/256, 256, 0, stream>>>(excl, bsums, NSEG);
  k_scatter<<<(NE/2 + 255)/256, 256, 0, stream>>>(src, dst, etype, excl, cursor, elist);

  // LSTM: gates (i,g,o) = A0 x B0; bias+activation fused in k_act
  k_gemm<128, 384, 1, 256><<<dim3(157, 3, 1), 256, 0, stream>>>(A0, Bp0, gates);
  k_act<<<(NN*FF + 255)/256, 256, 0, stream>>>(gates, bias0, A1, h1k);

  // layer 1
  k_agg<128, 768><<<NSEG/4, 256, 0, stream>>>(h1k, elist, excl, counts, A1);
  k_gemm<128, 256, 2, 768><<<dim3(157, 2, 2), 256, 0, stream>>>(A1, Bp1, P1);
  k_reduce<256, 2><<<256, 256, 0, stream>>>(P1, bias1, h2raw, bnsum1);
  k_bnrp<<<(NN*FF2 + 255)/256, 256, 0, stream>>>(h2raw, bnsum1, bn1_g, bn1_b, A2, h2k);

  // layer 2
  k_agg<256, 1536><<<NSEG/4, 256, 0, stream>>>(h2k, elist, excl, counts, A2);
  k_gemm<256, 128, 4, 1536><<<dim3(157, 1, 4), 256, 0, stream>>>(A2, Bp2, P2);
  k_reduce<128, 4><<<256, 128, 0, stream>>>(P2, bias2, out, bnsum2);
  k_bnsig<<<(NN*FF + 255)/256, 256, 0, stream>>>(out, bnsum2, bn2_g, bn2_b);
}

// Round 6
// 298.681 us; speedup vs baseline: 3.2100x; 1.1614x over previous
//
#include <hip/hip_runtime.h>
#include <math.h>

#define NN 20000
#define FF 128
#define FF2 256
#define TT 4
#define NE 640000
#define NSEG (NN*TT)
#define MP 20096          // padded M (multiple of 128)
#define NBUCK 157         // ceil(20000/128) buckets of 128 nodes (512 segs each)
#define EPSBN 1e-5f

typedef short bf16x8 __attribute__((ext_vector_type(8)));
typedef float f32x4  __attribute__((ext_vector_type(4)));

__device__ __forceinline__ float sigf(float x){ return 1.0f/(1.0f+expf(-x)); }

__device__ __forceinline__ unsigned short f2bf(float x){
  union { float f; unsigned u; } v; v.f = x;
  unsigned r = v.u + 0x7FFF + ((v.u >> 16) & 1);
  return (unsigned short)(r >> 16);
}
__device__ __forceinline__ float bf2f(unsigned short u){
  union { float f; unsigned u; } v; v.u = ((unsigned)u) << 16; return v.f;
}
// monotone u16 key for bf16 bits (unsigned order == float order)
__device__ __forceinline__ unsigned short bfkey(unsigned short b){
  return (unsigned short)(b ^ ((b & 0x8000) ? 0xFFFF : 0x8000));
}

// ---------------- init: biases + zero small counters ----------------
__global__ void k_init(const float* __restrict__ bih, const float* __restrict__ bhh,
                       const float* __restrict__ l1b, const float* __restrict__ c1b,
                       const float* __restrict__ l2b, const float* __restrict__ c2b,
                       float* __restrict__ bias0, float* __restrict__ bias1,
                       float* __restrict__ bias2, int* __restrict__ gbcnt,
                       int* __restrict__ gcursor, float* __restrict__ bnsum1,
                       float* __restrict__ bnsum2){
  int t = threadIdx.x;   // 768
  if(t < 384){ int grow = (t < 128) ? t : t + 128; bias0[t] = bih[grow] + bhh[grow]; }
  else if(t < 640){ int c = t - 384; bias1[c] = l1b[c] + 4.0f*c1b[c]; }
  else { int c = t - 640; bias2[c] = l2b[c] + 4.0f*c2b[c]; }
  for(int i = t; i < NBUCK; i += 768){ gbcnt[i] = 0; gcursor[i] = 0; }
  for(int i = t; i < 512; i += 768) bnsum1[i] = 0.0f;
  for(int i = t; i < 256; i += 768) bnsum2[i] = 0.0f;
}

// ---------------- oscillator -> A0 row-major [hi(128)|lo(128)] ----------------
__global__ void k_osc_pack(const float* __restrict__ x, const float* __restrict__ tbl,
                           unsigned short* __restrict__ A0){
  int i = blockIdx.x*256 + threadIdx.x;
  if(i >= NN*FF) return;
  int n = i >> 7, j = i & 127;
  float xv = x[i];
  float xi = (xv < -0.5f || xv > 0.5f) ? 0.5001f : xv;
  int idx = (int)floorf((xi + 0.5f) * 10000.0f);
  float tv = tbl[idx];
  float hv = (tv == 0.0f) ? sigf(xv) : tv;
  unsigned short hu = f2bf(hv);
  unsigned short lu = f2bf(hv - bf2f(hu));
  unsigned short* r = A0 + (size_t)n*256;
  r[j] = hu; r[128+j] = lu;
}

// ---------------- B packing ----------------
// generic: B = [hiW(C) | loW(C) | hiW(C) | conv(4C)] frag-packed [k8][COUT][8]
__global__ void k_packB(const float* __restrict__ lin_w, const float* __restrict__ conv_w,
                        unsigned short* __restrict__ Bp, int C, int COUT, int K){
  int i = blockIdx.x*256 + threadIdx.x;
  if(i >= K*COUT) return;
  int k = i / COUT, o = i - k*COUT;
  size_t dst = ((size_t)(k >> 3)*COUT + o)*8 + (k & 7);
  int reg = k / C;
  if(reg < 3){
    float w = lin_w[(size_t)o*C + (k - reg*C)];
    unsigned short hu = f2bf(w);
    Bp[dst] = (reg == 1) ? f2bf(w - bf2f(hu)) : hu;
  } else {
    int kk = k - 3*C; int t = kk / C; int c = kk - t*C;
    Bp[dst] = f2bf(conv_w[((size_t)t*COUT + o)*C + c]);
  }
}
// LSTM B0: gates i,g,o only (f skipped), COUT=384, K=384
__global__ void k_packB0(const float* __restrict__ w_ih, unsigned short* __restrict__ Bp){
  int i = blockIdx.x*256 + threadIdx.x;
  if(i >= 384*384) return;
  int k = i / 384, o = i - k*384;
  int grow = (o < 128) ? o : o + 128;      // i:[0,128) g:[256,384) o:[384,512)
  int reg = k >> 7, c = k & 127;
  float w = w_ih[(size_t)grow*128 + c];
  unsigned short hu = f2bf(w);
  unsigned short val = (reg == 1) ? f2bf(w - bf2f(hu)) : hu;
  Bp[((size_t)(k >> 3)*384 + o)*8 + (k & 7)] = val;
}

// ---------------- MFMA GEMM, 64x64 per wave, hi/lo A reuse + balanced split-K ----
template<int C, int COUT, int SPLITS, int AK>
__global__ __launch_bounds__(256)
void k_gemm(const unsigned short* __restrict__ A, const unsigned short* __restrict__ Bp,
            float* __restrict__ out){
  int w  = threadIdx.x >> 6;
  int l  = threadIdx.x & 63;
  int wr = w >> 1, wc = w & 1;
  int lr = l & 15, lg = l >> 4;
  int n0 = blockIdx.x*128 + wr*64;
  int c0 = blockIdx.y*128 + wc*64;
  constexpr int Q = (AK + C)/SPLITS;   // MFMA-K per split
  int zq0 = blockIdx.z*Q, zq1 = zq0 + Q;
  int kb = (zq0 <= 2*C) ? (zq0 >> 1) : (zq0 - C);
  int ke = (zq1 <= 2*C) ? (zq1 >> 1) : (zq1 - C);
  const size_t abase = (size_t)(n0 + lr)*AK + lg*8;
  const size_t bstep = (size_t)COUT*8;
  const unsigned short* bcolp = Bp + (size_t)(c0 + lr)*8 + lg*bstep;
  f32x4 acc[4][4] = {};
  int kde = ke < C ? ke : C;
  for(int ak = kb; ak < kde; ak += 32){
    bf16x8 a[4];
    #pragma unroll
    for(int r = 0; r < 4; ++r) a[r] = *(const bf16x8*)(A + abase + (size_t)r*16*AK + ak);
    const unsigned short* p1 = bcolp + (size_t)(ak >> 3)*bstep;
    const unsigned short* p2 = bcolp + (size_t)((C + ak) >> 3)*bstep;
    #pragma unroll
    for(int j = 0; j < 4; ++j){
      bf16x8 b1 = *(const bf16x8*)(p1 + j*128);
      bf16x8 b2 = *(const bf16x8*)(p2 + j*128);
      #pragma unroll
      for(int r = 0; r < 4; ++r){
        acc[r][j] = __builtin_amdgcn_mfma_f32_16x16x32_bf16(a[r], b1, acc[r][j], 0, 0, 0);
        acc[r][j] = __builtin_amdgcn_mfma_f32_16x16x32_bf16(a[r], b2, acc[r][j], 0, 0, 0);
      }
    }
  }
  int ks = kb > C ? kb : C;
  for(int ak = ks; ak < ke; ak += 32){
    bf16x8 a[4];
    #pragma unroll
    for(int r = 0; r < 4; ++r) a[r] = *(const bf16x8*)(A + abase + (size_t)r*16*AK + ak);
    const unsigned short* p = bcolp + (size_t)((C + ak) >> 3)*bstep;
    #pragma unroll
    for(int j = 0; j < 4; ++j){
      bf16x8 b = *(const bf16x8*)(p + j*128);
      #pragma unroll
      for(int r = 0; r < 4; ++r)
        acc[r][j] = __builtin_amdgcn_mfma_f32_16x16x32_bf16(a[r], b, acc[r][j], 0, 0, 0);
    }
  }
  float* o = out + (size_t)blockIdx.z*NN*COUT;
  #pragma unroll
  for(int r = 0; r < 4; ++r){
    int nb = n0 + r*16 + lg*4;
    #pragma unroll
    for(int j = 0; j < 4; ++j){
      int oc = c0 + j*16 + lr;
      #pragma unroll
      for(int q = 0; q < 4; ++q){
        int n = nb + q;
        if(n < NN) o[(size_t)n*COUT + oc] = acc[r][j][q];
      }
    }
  }
}

// ---------------- split-K reduce + bias + BN stats ----------------
template<int COUT, int SPLITS>
__global__ __launch_bounds__(COUT)
void k_reduce(const float* __restrict__ P, const float* __restrict__ bias,
              float* __restrict__ h, float* __restrict__ sums){
  int c = threadIdx.x;
  float bs = bias[c];
  float s = 0.0f, s2 = 0.0f;
  for(int n = blockIdx.x; n < NN; n += gridDim.x){
    float v = bs;
    #pragma unroll
    for(int z = 0; z < SPLITS; ++z) v += P[(size_t)z*NN*COUT + (size_t)n*COUT + c];
    h[(size_t)n*COUT + c] = v;
    s += v; s2 += v*v;
  }
  atomicAdd(&sums[c], s);
  atomicAdd(&sums[COUT + c], s2);
}

// ---------------- LSTM activation (+bias) -> A1 [hi|lo] + key table ----------------
__global__ void k_act(const float* __restrict__ gates, const float* __restrict__ bias0,
                      unsigned short* __restrict__ A1, unsigned short* __restrict__ h1k){
  int i = blockIdx.x*256 + threadIdx.x;
  if(i >= NN*FF) return;
  int n = i >> 7, j = i & 127;
  const float* g = gates + (size_t)n*384;
  float ig = g[j]       + bias0[j];
  float gg = g[128 + j] + bias0[128 + j];
  float og = g[256 + j] + bias0[256 + j];
  float c  = sigf(ig) * tanhf(gg);
  float hv = sigf(og) * tanhf(c);
  unsigned short hu = f2bf(hv);
  unsigned short lu = f2bf(hv - bf2f(hu));
  unsigned short* r = A1 + (size_t)n*768;
  r[j] = hu; r[128 + j] = lu;
  h1k[i] = bfkey(hu);
}

// ---------------- binned CSR build ----------------
// bucket = dst>>7 (128 nodes, 512 segs per bucket); seg_local = (dst&127)*4 + et
__global__ void k_bcount(const int* __restrict__ dst, int* __restrict__ gbcnt){
  __shared__ int h[NBUCK];
  for(int i = threadIdx.x; i < NBUCK; i += 256) h[i] = 0;
  __syncthreads();
  int e0 = blockIdx.x*2048;
  #pragma unroll
  for(int k = 0; k < 8; ++k){
    int e = e0 + threadIdx.x + k*256;
    if(e < NE) atomicAdd(&h[dst[e] >> 7], 1);
  }
  __syncthreads();
  for(int i = threadIdx.x; i < NBUCK; i += 256) if(h[i]) atomicAdd(&gbcnt[i], h[i]);
}
__global__ void k_bscan(const int* __restrict__ gbcnt, int* __restrict__ gbase){
  if(threadIdx.x == 0){
    int s = 0;
    for(int i = 0; i < NBUCK; ++i){ gbase[i] = s; s += gbcnt[i]; }
  }
}
// stage 4096 edges in LDS, bin by bucket, dump contiguous per-bucket runs
__global__ __launch_bounds__(512)
void k_binscat(const int* __restrict__ src, const int* __restrict__ dst,
               const int* __restrict__ et, const int* __restrict__ gbase,
               int* __restrict__ gcursor, unsigned* __restrict__ gstage){
  __shared__ unsigned stage[4096];
  __shared__ unsigned char stgb[4096];
  __shared__ int lcnt[NBUCK], lexc[NBUCK], lcur[NBUCK], gofs[NBUCK];
  int tid = threadIdx.x;
  for(int i = tid; i < NBUCK; i += 512) lcnt[i] = 0;
  __syncthreads();
  int e0 = blockIdx.x*4096;
  int b_[8]; unsigned v_[8];
  #pragma unroll
  for(int k = 0; k < 8; ++k){
    int e = e0 + tid + k*512;
    if(e < NE){
      int d = dst[e]; int b = d >> 7;
      b_[k] = b;
      v_[k] = ((unsigned)((((d & 127) << 2) | et[e])) << 16) | (unsigned)src[e];
      atomicAdd(&lcnt[b], 1);
    } else b_[k] = -1;
  }
  __syncthreads();
  if(tid == 0){
    int s = 0;
    for(int i = 0; i < NBUCK; ++i){ lexc[i] = s; s += lcnt[i]; }
  }
  __syncthreads();
  if(tid < NBUCK){
    lcur[tid] = lexc[tid];
    if(lcnt[tid]) gofs[tid] = atomicAdd(&gcursor[tid], lcnt[tid]);
  }
  __syncthreads();
  #pragma unroll
  for(int k = 0; k < 8; ++k){
    if(b_[k] >= 0){
      int p = atomicAdd(&lcur[b_[k]], 1);
      stage[p] = v_[k]; stgb[p] = (unsigned char)b_[k];
    }
  }
  __syncthreads();
  int ne = NE - e0; if(ne > 4096) ne = 4096;
  for(int i = tid; i < ne; i += 512){
    int b = stgb[i];
    gstage[gbase[b] + gofs[b] + (i - lexc[b])] = stage[i];
  }
}
// one block per bucket: per-seg counts + scan + place, all in LDS / private L2 region
__global__ __launch_bounds__(512)
void k_fine(const unsigned* __restrict__ gstage, const int* __restrict__ gbcnt,
            const int* __restrict__ gbase, int* __restrict__ counts,
            int* __restrict__ excl, unsigned short* __restrict__ elist){
  __shared__ int cnt[512], scn[512], cur[512];
  int t = threadIdx.x, bk = blockIdx.x;
  cnt[t] = 0;
  __syncthreads();
  int gB = gbase[bk], cE = gbcnt[bk];
  for(int i = t; i < cE; i += 512) atomicAdd(&cnt[gstage[gB + i] >> 16], 1);
  __syncthreads();
  scn[t] = cnt[t]; __syncthreads();
  for(int off = 1; off < 512; off <<= 1){
    int add = (t >= off) ? scn[t - off] : 0;
    __syncthreads();
    scn[t] += add;
    __syncthreads();
  }
  int ex = scn[t] - cnt[t];
  cur[t] = ex;
  int s = bk*512 + t;
  if(s < NSEG){ counts[s] = cnt[t]; excl[s] = gB + ex; }
  __syncthreads();
  for(int i = t; i < cE; i += 512){
    unsigned v = gstage[gB + i];
    int p = atomicAdd(&cur[v >> 16], 1);
    elist[gB + p] = (unsigned short)(v & 0xFFFFu);
  }
}

// ---------------- per-segment max over u16 keys -> A agg block ----------------
template<int C, int AK>
__global__ __launch_bounds__(256)
void k_agg(const unsigned short* __restrict__ keys, const unsigned short* __restrict__ elist,
           const int* __restrict__ excl, const int* __restrict__ counts,
           unsigned short* __restrict__ A){
  constexpr int VW = C/32;
  typedef unsigned short kvec __attribute__((ext_vector_type(VW)));
  int seg  = blockIdx.x*4 + (threadIdx.x >> 6);
  int l    = threadIdx.x & 63;
  int half = l >> 5;
  int cl   = l & 31;
  int cnt = counts[seg];
  int start = excl[seg];
  const unsigned short* kp = keys + cl*VW;
  kvec m = {};
  int i = 0;
  for(; i + 8 <= cnt; i += 8){
    int e0 = elist[start+i+half],   e1 = elist[start+i+2+half];
    int e2 = elist[start+i+4+half], e3 = elist[start+i+6+half];
    kvec v0 = *(const kvec*)(kp + (size_t)e0*C);
    kvec v1 = *(const kvec*)(kp + (size_t)e1*C);
    kvec v2 = *(const kvec*)(kp + (size_t)e2*C);
    kvec v3 = *(const kvec*)(kp + (size_t)e3*C);
    kvec t0 = __builtin_elementwise_max(v0, v1);
    kvec t1 = __builtin_elementwise_max(v2, v3);
    m = __builtin_elementwise_max(m, __builtin_elementwise_max(t0, t1));
  }
  for(; i + 2 <= cnt; i += 2){
    int e = elist[start+i+half];
    kvec v = *(const kvec*)(kp + (size_t)e*C);
    m = __builtin_elementwise_max(m, v);
  }
  if(i < cnt && half == 0){
    int e = elist[start+i];
    kvec v = *(const kvec*)(kp + (size_t)e*C);
    m = __builtin_elementwise_max(m, v);
  }
  union Ux { kvec v; int w[VW/2]; };
  Ux a, b; a.v = m;
  #pragma unroll
  for(int q = 0; q < VW/2; ++q) b.w[q] = __shfl_xor(a.w[q], 32);
  m = __builtin_elementwise_max(a.v, b.v);
  if(half == 0){
    int n = seg >> 2, t = seg & 3;
    kvec o;
    #pragma unroll
    for(int q = 0; q < VW; ++q){
      unsigned short k = m[q];
      unsigned short bb = (k & 0x8000) ? (unsigned short)(k ^ 0x8000) : (unsigned short)(~k);
      o[q] = (cnt == 0) ? (unsigned short)0 : bb;
    }
    *(kvec*)(A + (size_t)n*AK + 2*C + t*C + cl*VW) = o;
  }
}

// ---------------- BN1(inline finalize) + ReLU -> A2 [hi|lo] + key table ----------------
__global__ void k_bnrp(const float* __restrict__ h2, const float* __restrict__ sums,
                       const float* __restrict__ g, const float* __restrict__ bb,
                       unsigned short* __restrict__ A2, unsigned short* __restrict__ h2k){
  int i = blockIdx.x*256 + threadIdx.x;
  if(i >= NN*FF2) return;
  int n = i >> 8, c = i & 255;
  float mean = sums[c] * (1.0f/NN);
  float var  = sums[256 + c] * (1.0f/NN) - mean*mean;
  float scale = g[c] / sqrtf(var + EPSBN);
  float shift = bb[c] - mean*scale;
  float v = fmaxf(h2[i]*scale + shift, 0.0f);
  unsigned short hu = f2bf(v);
  unsigned short lu = f2bf(v - bf2f(hu));
  unsigned short* r = A2 + (size_t)n*1536;
  r[c] = hu; r[256 + c] = lu;
  h2k[i] = (unsigned short)(hu | 0x8000);
}

// ---------------- BN2(inline finalize) + sigmoid(x-10), in place ----------------
__global__ void k_bnsig(float* __restrict__ h, const float* __restrict__ sums,
                        const float* __restrict__ g, const float* __restrict__ bb){
  int i = blockIdx.x*256 + threadIdx.x;
  if(i >= NN*FF) return;
  int c = i & 127;
  float mean = sums[c] * (1.0f/NN);
  float var  = sums[128 + c] * (1.0f/NN) - mean*mean;
  float scale = g[c] / sqrtf(var + EPSBN);
  float shift = bb[c] - mean*scale;
  float v = h[i]*scale + shift - 10.0f;
  h[i] = 1.0f/(1.0f + expf(-v));
}

// ---------------- launch ----------------
extern "C" void kernel_launch(void* const* d_in, const int* in_sizes, int n_in,
                              void* d_out, int out_size, void* d_ws, size_t ws_size,
                              hipStream_t stream){
  (void)in_sizes; (void)n_in; (void)out_size; (void)ws_size;
  const float* x       = (const float*)d_in[0];
  const float* tbl     = (const float*)d_in[1];
  const int*   eidx    = (const int*)  d_in[2];
  const int*   etype   = (const int*)  d_in[3];
  const float* w_ih    = (const float*)d_in[4];
  const float* b_ih    = (const float*)d_in[6];
  const float* b_hh    = (const float*)d_in[7];
  const float* conv1_w = (const float*)d_in[8];
  const float* conv1_b = (const float*)d_in[9];
  const float* conv2_w = (const float*)d_in[10];
  const float* conv2_b = (const float*)d_in[11];
  const float* lin1_w  = (const float*)d_in[12];
  const float* lin1_b  = (const float*)d_in[13];
  const float* lin2_w  = (const float*)d_in[14];
  const float* lin2_b  = (const float*)d_in[15];
  const float* bn1_g   = (const float*)d_in[16];
  const float* bn1_b   = (const float*)d_in[17];
  const float* bn2_g   = (const float*)d_in[18];
  const float* bn2_b   = (const float*)d_in[19];
  float* out = (float*)d_out;

  char* base = (char*)d_ws;
  size_t off = 0;
  auto alloc = [&](size_t bytes){ char* p = base + off; off = (off + bytes + 255) & ~(size_t)255; return p; };

  unsigned short* A0 = (unsigned short*)alloc((size_t)MP * 256 * 2);   // 10.29 MB
  unsigned short* A1 = (unsigned short*)alloc((size_t)MP * 768 * 2);   // 30.87 MB
  unsigned short* A2 = (unsigned short*)alloc((size_t)MP * 1536 * 2);  // 61.73 MB
  float* h2raw = (float*)alloc((size_t)NN * 256 * 4);                  // 20.48 MB
  unsigned short* h1k = (unsigned short*)alloc((size_t)NN * 128 * 2);  // 5.12 MB
  unsigned short* h2k = (unsigned short*)alloc((size_t)NN * 256 * 2);  // 10.24 MB
  unsigned short* Bp0 = (unsigned short*)alloc((size_t)384 * 384 * 2);
  unsigned short* Bp1 = (unsigned short*)alloc((size_t)896 * 256 * 2);
  unsigned short* Bp2 = (unsigned short*)alloc((size_t)1792 * 128 * 2);
  float* bias0 = (float*)alloc(384 * 4);
  float* bias1 = (float*)alloc(256 * 4);
  float* bias2 = (float*)alloc(128 * 4);
  int* counts  = (int*)alloc(NSEG * 4);
  int* excl    = (int*)alloc(NSEG * 4);
  float* bnsum1 = (float*)alloc(512 * 4);
  float* bnsum2 = (float*)alloc(256 * 4);
  int* gbcnt   = (int*)alloc(NBUCK * 4);
  int* gbase   = (int*)alloc(NBUCK * 4);
  int* gcursor = (int*)alloc(NBUCK * 4);
  unsigned* gstage = (unsigned*)alloc((size_t)NE * 4);
  unsigned short* elist = (unsigned short*)alloc((size_t)NE * 2);

  // aliases (lifetimes disjoint; all region sizes are 256B-aligned)
  float* gates = (float*)A2;     // MP*384*4 = 30.9 MB, dead after k_act
  float* P1    = (float*)A2;     // 2*NN*256*4 = 41 MB, dead before k_bnrp writes A2
  float* P2    = (float*)A0;     // 4*NN*128*4 = 41 MB, spans A0+A1 (both dead by gemm2)

  const int* src = eidx;
  const int* dst = eidx + NE;

  // init: biases + zero gbcnt/gcursor/bnsums
  k_init<<<1, 768, 0, stream>>>(b_ih, b_hh, lin1_b, conv1_b, lin2_b, conv2_b,
                                bias0, bias1, bias2, gbcnt, gcursor, bnsum1, bnsum2);

  // pack weights
  k_packB0<<<(384*384 + 255)/256, 256, 0, stream>>>(w_ih, Bp0);
  k_packB<<<(896*256 + 255)/256, 256, 0, stream>>>(lin1_w, conv1_w, Bp1, 128, 256, 896);
  k_packB<<<(1792*128 + 255)/256, 256, 0, stream>>>(lin2_w, conv2_w, Bp2, 256, 128, 1792);

  k_osc_pack<<<(NN*FF + 255)/256, 256, 0, stream>>>(x, tbl, A0);

  // binned CSR build
  k_bcount<<<(NE + 2047)/2048, 256, 0, stream>>>(dst, gbcnt);
  k_bscan<<<1, 64, 0, stream>>>(gbcnt, gbase);
  k_binscat<<<(NE + 4095)/4096, 512, 0, stream>>>(src, dst, etype, gbase, gcursor, gstage);
  k_fine<<<NBUCK, 512, 0, stream>>>(gstage, gbcnt, gbase, counts, excl, elist);

  // LSTM: gates (i,g,o) = A0 x B0; bias+activation fused in k_act
  k_gemm<128, 384, 1, 256><<<dim3(157, 3, 1), 256, 0, stream>>>(A0, Bp0, gates);
  k_act<<<(NN*FF + 255)/256, 256, 0, stream>>>(gates, bias0, A1, h1k);

  // layer 1
  k_agg<128, 768><<<NSEG/4, 256, 0, stream>>>(h1k, elist, excl, counts, A1);
  k_gemm<128, 256, 2, 768><<<dim3(157, 2, 2), 256, 0, stream>>>(A1, Bp1, P1);
  k_reduce<256, 2><<<256, 256, 0, stream>>>(P1, bias1, h2raw, bnsum1);
  k_bnrp<<<(NN*FF2 + 255)/256, 256, 0, stream>>>(h2raw, bnsum1, bn1_g, bn1_b, A2, h2k);

  // layer 2
  k_agg<256, 1536><<<NSEG/4, 256, 0, stream>>>(h2k, elist, excl, counts, A2);
  k_gemm<256, 128, 4, 1536><<<dim3(157, 1, 4), 256, 0, stream>>>(A2, Bp2, P2);
  k_reduce<128, 4><<<256, 128, 0, stream>>>(P2, bias2, out, bnsum2);
  k_bnsig<<<(NN*FF + 255)/256, 256, 0, stream>>>(out, bnsum2, bn2_g, bn2_b);
}

// Round 7
// 291.161 us; speedup vs baseline: 3.2929x; 1.0258x over previous
//
#include <hip/hip_runtime.h>
#include <math.h>

#define NN 20000
#define NE 640000
#define TT 4
#define FF 128
#define FF2 256
#define NSEG (NN*TT)
#define MP 20096          // padded M (multiple of 128)
#define NBUCK 157         // ceil(20000/128) buckets of 128 nodes (512 segs each)
#define EPSBN 1e-5f

typedef short bf16x8 __attribute__((ext_vector_type(8)));
typedef float f32x4  __attribute__((ext_vector_type(4)));

__device__ __forceinline__ float sigf(float x){ return 1.0f/(1.0f+expf(-x)); }

__device__ __forceinline__ unsigned short f2bf(float x){
  union { float f; unsigned u; } v; v.f = x;
  unsigned r = v.u + 0x7FFF + ((v.u >> 16) & 1);
  return (unsigned short)(r >> 16);
}
__device__ __forceinline__ float bf2f(unsigned short u){
  union { float f; unsigned u; } v; v.u = ((unsigned)u) << 16; return v.f;
}

// ---- fp8 e4m3fn helpers (monotone RTN-even encode; used for gather tables) ----
__device__ __forceinline__ unsigned char f2f8(float x){
  union{float f; unsigned u;} v; v.f = x;
  unsigned s = (v.u >> 24) & 0x80u;
  unsigned a = v.u & 0x7FFFFFFFu;
  if(a > 0x43E00000u) a = 0x43E00000u;          // clamp |x| to 448
  union{unsigned u; float f;} w; w.u = a;
  float ax = w.f;
  if(ax < 0.015625f){                           // denormal: ulp = 2^-9
    int q = (int)rintf(ax * 512.0f);            // 0..8 (8 -> min normal)
    return (unsigned char)(s | (unsigned)q);
  }
  unsigned rb = a & 0xFFFFFu;
  unsigned base = a >> 20;                      // exp(8) | mant(3)
  unsigned r = base + (((rb > 0x80000u) || (rb == 0x80000u && (base & 1u))) ? 1u : 0u);
  unsigned e = r >> 3, m3 = r & 7u;
  int fe = (int)e - 120;                        // e4m3 bias 7
  if(fe >= 16) return (unsigned char)(s | 0x7Eu);  // 448
  return (unsigned char)(s | ((unsigned)fe << 3) | m3);
}
// monotone u8 key (unsigned order == float order)
__device__ __forceinline__ unsigned char fold8(unsigned char b){
  return (unsigned char)(b ^ ((b & 0x80u) ? 0xFFu : 0x80u));
}
// key -> original fp8 -> bf16 bits (exact: 3-bit mantissa fits bf16)
__device__ __forceinline__ unsigned short key8tobf(unsigned char k){
  unsigned char b = (unsigned char)(k ^ ((k & 0x80u) ? 0x80u : 0xFFu));
  unsigned s = ((unsigned)b & 0x80u) << 24;
  unsigned e = ((unsigned)b >> 3) & 0xFu;
  unsigned m = (unsigned)b & 7u;
  union{unsigned u; float f;} v;
  if(e == 0){ v.f = (float)m * 0.001953125f; v.u |= s; }
  else v.u = s | ((e + 120u) << 23) | (m << 20);
  return (unsigned short)(v.u >> 16);
}
// packed per-byte unsigned max (even/odd byte lanes via pk_max_u16)
__device__ __forceinline__ unsigned maxu8x4(unsigned a, unsigned b){
  typedef unsigned short us2 __attribute__((ext_vector_type(2)));
  union U{unsigned u; us2 v;};
  U ae, be, ao, bo, me, mo;
  ae.u = a & 0x00FF00FFu;        be.u = b & 0x00FF00FFu;
  ao.u = (a >> 8) & 0x00FF00FFu; bo.u = (b >> 8) & 0x00FF00FFu;
  me.v = __builtin_elementwise_max(ae.v, be.v);
  mo.v = __builtin_elementwise_max(ao.v, bo.v);
  return me.u | (mo.u << 8);
}

// ---------------- fused prep: pack B0/B1/B2 + biases + zero counters ----------------
#define PB0 147456                  // 384x384
#define PB1 (PB0 + 229376)          // + 896x256
#define PB2 (PB1 + 229376)          // + 1792x128
__global__ __launch_bounds__(256)
void k_prep(const float* __restrict__ w_ih, const float* __restrict__ lin1_w,
            const float* __restrict__ conv1_w, const float* __restrict__ lin2_w,
            const float* __restrict__ conv2_w,
            const float* __restrict__ bih, const float* __restrict__ bhh,
            const float* __restrict__ l1b, const float* __restrict__ c1b,
            const float* __restrict__ l2b, const float* __restrict__ c2b,
            unsigned short* __restrict__ Bp0, unsigned short* __restrict__ Bp1,
            unsigned short* __restrict__ Bp2,
            float* __restrict__ bias0, float* __restrict__ bias1, float* __restrict__ bias2,
            int* __restrict__ gbcnt, int* __restrict__ gcursor,
            float* __restrict__ bnsum1, float* __restrict__ bnsum2){
  int gi = blockIdx.x*256 + threadIdx.x;
  if(gi < PB0){                                  // B0: [hi|lo|hi] of w_ih (i,g,o rows)
    int k = gi/384, o = gi - k*384;
    int grow = (o < 128) ? o : o + 128;
    int reg = k >> 7, c = k & 127;
    float w = w_ih[(size_t)grow*128 + c];
    unsigned short hu = f2bf(w);
    Bp0[((size_t)(k >> 3)*384 + o)*8 + (k & 7)] = (reg == 1) ? f2bf(w - bf2f(hu)) : hu;
  } else if(gi < PB1){                           // B1: [hi|lo|hi|conv] C=128 COUT=256
    int i = gi - PB0; int k = i >> 8, o = i & 255;
    int reg = k >> 7;
    unsigned short val;
    if(reg < 3){
      float w = lin1_w[(size_t)o*128 + (k & 127)];
      unsigned short hu = f2bf(w);
      val = (reg == 1) ? f2bf(w - bf2f(hu)) : hu;
    } else {
      int kk = k - 384; int t = kk >> 7; int c = kk & 127;
      val = f2bf(conv1_w[((size_t)t*256 + o)*128 + c]);
    }
    Bp1[((size_t)(k >> 3)*256 + o)*8 + (k & 7)] = val;
  } else if(gi < PB2){                           // B2: C=256 COUT=128
    int i = gi - PB1; int k = i >> 7, o = i & 127;
    int reg = k >> 8;
    unsigned short val;
    if(reg < 3){
      float w = lin2_w[(size_t)o*256 + (k & 255)];
      unsigned short hu = f2bf(w);
      val = (reg == 1) ? f2bf(w - bf2f(hu)) : hu;
    } else {
      int kk = k - 768; int t = kk >> 8; int c = kk & 255;
      val = f2bf(conv2_w[((size_t)t*128 + o)*256 + c]);
    }
    Bp2[((size_t)(k >> 3)*128 + o)*8 + (k & 7)] = val;
  } else {                                       // tail: biases + zero fills
    int t = gi - PB2;
    if(t < 384){ int grow = (t < 128) ? t : t + 128; bias0[t] = bih[grow] + bhh[grow]; }
    else if(t < 640){ int c = t - 384; bias1[c] = l1b[c] + 4.0f*c1b[c]; }
    else if(t < 768){ int c = t - 640; bias2[c] = l2b[c] + 4.0f*c2b[c]; }
    else if(t < 1280){ bnsum1[t - 768] = 0.0f; }
    else if(t < 1536){ bnsum2[t - 1280] = 0.0f; }
    else if(t < 1536 + NBUCK){ gbcnt[t - 1536] = 0; }
    else if(t < 1536 + 2*NBUCK){ gcursor[t - 1536 - NBUCK] = 0; }
  }
}

// ---------------- oscillator -> A0 row-major [hi(128)|lo(128)] ----------------
__global__ void k_osc_pack(const float* __restrict__ x, const float* __restrict__ tbl,
                           unsigned short* __restrict__ A0){
  int i = blockIdx.x*256 + threadIdx.x;
  if(i >= NN*FF) return;
  int n = i >> 7, j = i & 127;
  float xv = x[i];
  float xi = (xv < -0.5f || xv > 0.5f) ? 0.5001f : xv;
  int idx = (int)floorf((xi + 0.5f) * 10000.0f);
  float tv = tbl[idx];
  float hv = (tv == 0.0f) ? sigf(xv) : tv;
  unsigned short hu = f2bf(hv);
  unsigned short lu = f2bf(hv - bf2f(hu));
  unsigned short* r = A0 + (size_t)n*256;
  r[j] = hu; r[128+j] = lu;
}

// ---------------- MFMA GEMM, 64x64 per wave, hi/lo A reuse + balanced split-K ----
template<int C, int COUT, int SPLITS, int AK>
__global__ __launch_bounds__(256)
void k_gemm(const unsigned short* __restrict__ A, const unsigned short* __restrict__ Bp,
            float* __restrict__ out){
  int w  = threadIdx.x >> 6;
  int l  = threadIdx.x & 63;
  int wr = w >> 1, wc = w & 1;
  int lr = l & 15, lg = l >> 4;
  int n0 = blockIdx.x*128 + wr*64;
  int c0 = blockIdx.y*128 + wc*64;
  constexpr int Q = (AK + C)/SPLITS;   // MFMA-K per split
  int zq0 = blockIdx.z*Q, zq1 = zq0 + Q;
  int kb = (zq0 <= 2*C) ? (zq0 >> 1) : (zq0 - C);
  int ke = (zq1 <= 2*C) ? (zq1 >> 1) : (zq1 - C);
  const size_t abase = (size_t)(n0 + lr)*AK + lg*8;
  const size_t bstep = (size_t)COUT*8;
  const unsigned short* bcolp = Bp + (size_t)(c0 + lr)*8 + lg*bstep;
  f32x4 acc[4][4] = {};
  int kde = ke < C ? ke : C;
  for(int ak = kb; ak < kde; ak += 32){
    bf16x8 a[4];
    #pragma unroll
    for(int r = 0; r < 4; ++r) a[r] = *(const bf16x8*)(A + abase + (size_t)r*16*AK + ak);
    const unsigned short* p1 = bcolp + (size_t)(ak >> 3)*bstep;
    const unsigned short* p2 = bcolp + (size_t)((C + ak) >> 3)*bstep;
    #pragma unroll
    for(int j = 0; j < 4; ++j){
      bf16x8 b1 = *(const bf16x8*)(p1 + j*128);
      bf16x8 b2 = *(const bf16x8*)(p2 + j*128);
      #pragma unroll
      for(int r = 0; r < 4; ++r){
        acc[r][j] = __builtin_amdgcn_mfma_f32_16x16x32_bf16(a[r], b1, acc[r][j], 0, 0, 0);
        acc[r][j] = __builtin_amdgcn_mfma_f32_16x16x32_bf16(a[r], b2, acc[r][j], 0, 0, 0);
      }
    }
  }
  int ks = kb > C ? kb : C;
  for(int ak = ks; ak < ke; ak += 32){
    bf16x8 a[4];
    #pragma unroll
    for(int r = 0; r < 4; ++r) a[r] = *(const bf16x8*)(A + abase + (size_t)r*16*AK + ak);
    const unsigned short* p = bcolp + (size_t)((C + ak) >> 3)*bstep;
    #pragma unroll
    for(int j = 0; j < 4; ++j){
      bf16x8 b = *(const bf16x8*)(p + j*128);
      #pragma unroll
      for(int r = 0; r < 4; ++r)
        acc[r][j] = __builtin_amdgcn_mfma_f32_16x16x32_bf16(a[r], b, acc[r][j], 0, 0, 0);
    }
  }
  float* o = out + (size_t)blockIdx.z*NN*COUT;
  #pragma unroll
  for(int r = 0; r < 4; ++r){
    int nb = n0 + r*16 + lg*4;
    #pragma unroll
    for(int j = 0; j < 4; ++j){
      int oc = c0 + j*16 + lr;
      #pragma unroll
      for(int q = 0; q < 4; ++q){
        int n = nb + q;
        if(n < NN) o[(size_t)n*COUT + oc] = acc[r][j][q];
      }
    }
  }
}

// ---------------- split-K reduce + bias + BN stats ----------------
template<int COUT, int SPLITS>
__global__ __launch_bounds__(COUT)
void k_reduce(const float* __restrict__ P, const float* __restrict__ bias,
              float* __restrict__ h, float* __restrict__ sums){
  int c = threadIdx.x;
  float bs = bias[c];
  float s = 0.0f, s2 = 0.0f;
  for(int n = blockIdx.x; n < NN; n += gridDim.x){
    float v = bs;
    #pragma unroll
    for(int z = 0; z < SPLITS; ++z) v += P[(size_t)z*NN*COUT + (size_t)n*COUT + c];
    h[(size_t)n*COUT + c] = v;
    s += v; s2 += v*v;
  }
  atomicAdd(&sums[c], s);
  atomicAdd(&sums[COUT + c], s2);
}

// ---------------- LSTM activation (+bias) -> A1 [hi|lo] + fp8 key table ----------------
__global__ void k_act(const float* __restrict__ gates, const float* __restrict__ bias0,
                      unsigned short* __restrict__ A1, unsigned char* __restrict__ h1k8){
  int i = blockIdx.x*256 + threadIdx.x;
  if(i >= NN*FF) return;
  int n = i >> 7, j = i & 127;
  const float* g = gates + (size_t)n*384;
  float ig = g[j]       + bias0[j];
  float gg = g[128 + j] + bias0[128 + j];
  float og = g[256 + j] + bias0[256 + j];
  float c  = sigf(ig) * tanhf(gg);
  float hv = sigf(og) * tanhf(c);
  unsigned short hu = f2bf(hv);
  unsigned short lu = f2bf(hv - bf2f(hu));
  unsigned short* r = A1 + (size_t)n*768;
  r[j] = hu; r[128 + j] = lu;
  h1k8[i] = fold8(f2f8(hv));
}

// ---------------- binned CSR build ----------------
__global__ void k_bcount(const int* __restrict__ dst, int* __restrict__ gbcnt){
  __shared__ int h[NBUCK];
  for(int i = threadIdx.x; i < NBUCK; i += 256) h[i] = 0;
  __syncthreads();
  int e0 = blockIdx.x*2048;
  #pragma unroll
  for(int k = 0; k < 8; ++k){
    int e = e0 + threadIdx.x + k*256;
    if(e < NE) atomicAdd(&h[dst[e] >> 7], 1);
  }
  __syncthreads();
  for(int i = threadIdx.x; i < NBUCK; i += 256) if(h[i]) atomicAdd(&gbcnt[i], h[i]);
}
__global__ void k_bscan(const int* __restrict__ gbcnt, int* __restrict__ gbase){
  if(threadIdx.x == 0){
    int s = 0;
    for(int i = 0; i < NBUCK; ++i){ gbase[i] = s; s += gbcnt[i]; }
  }
}
__global__ __launch_bounds__(512)
void k_binscat(const int* __restrict__ src, const int* __restrict__ dst,
               const int* __restrict__ et, const int* __restrict__ gbase,
               int* __restrict__ gcursor, unsigned* __restrict__ gstage){
  __shared__ unsigned stage[4096];
  __shared__ unsigned char stgb[4096];
  __shared__ int lcnt[NBUCK], lexc[NBUCK], lcur[NBUCK], gofs[NBUCK];
  int tid = threadIdx.x;
  for(int i = tid; i < NBUCK; i += 512) lcnt[i] = 0;
  __syncthreads();
  int e0 = blockIdx.x*4096;
  int b_[8]; unsigned v_[8];
  #pragma unroll
  for(int k = 0; k < 8; ++k){
    int e = e0 + tid + k*512;
    if(e < NE){
      int d = dst[e]; int b = d >> 7;
      b_[k] = b;
      v_[k] = ((unsigned)((((d & 127) << 2) | et[e])) << 16) | (unsigned)src[e];
      atomicAdd(&lcnt[b], 1);
    } else b_[k] = -1;
  }
  __syncthreads();
  if(tid == 0){
    int s = 0;
    for(int i = 0; i < NBUCK; ++i){ lexc[i] = s; s += lcnt[i]; }
  }
  __syncthreads();
  if(tid < NBUCK){
    lcur[tid] = lexc[tid];
    if(lcnt[tid]) gofs[tid] = atomicAdd(&gcursor[tid], lcnt[tid]);
  }
  __syncthreads();
  #pragma unroll
  for(int k = 0; k < 8; ++k){
    if(b_[k] >= 0){
      int p = atomicAdd(&lcur[b_[k]], 1);
      stage[p] = v_[k]; stgb[p] = (unsigned char)b_[k];
    }
  }
  __syncthreads();
  int ne = NE - e0; if(ne > 4096) ne = 4096;
  for(int i = tid; i < ne; i += 512){
    int b = stgb[i];
    gstage[gbase[b] + gofs[b] + (i - lexc[b])] = stage[i];
  }
}
__global__ __launch_bounds__(512)
void k_fine(const unsigned* __restrict__ gstage, const int* __restrict__ gbcnt,
            const int* __restrict__ gbase, int* __restrict__ counts,
            int* __restrict__ excl, unsigned short* __restrict__ elist){
  __shared__ int cnt[512], scn[512], cur[512];
  int t = threadIdx.x, bk = blockIdx.x;
  cnt[t] = 0;
  __syncthreads();
  int gB = gbase[bk], cE = gbcnt[bk];
  for(int i = t; i < cE; i += 512) atomicAdd(&cnt[gstage[gB + i] >> 16], 1);
  __syncthreads();
  scn[t] = cnt[t]; __syncthreads();
  for(int off = 1; off < 512; off <<= 1){
    int add = (t >= off) ? scn[t - off] : 0;
    __syncthreads();
    scn[t] += add;
    __syncthreads();
  }
  int ex = scn[t] - cnt[t];
  cur[t] = ex;
  int s = bk*512 + t;
  if(s < NSEG){ counts[s] = cnt[t]; excl[s] = gB + ex; }
  __syncthreads();
  for(int i = t; i < cE; i += 512){
    unsigned v = gstage[gB + i];
    int p = atomicAdd(&cur[v >> 16], 1);
    elist[gB + p] = (unsigned short)(v & 0xFFFFu);
  }
}

// ---------------- per-segment max over fp8 keys -> bf16 A agg block ----------------
template<int C, int AK>
__global__ __launch_bounds__(256)
void k_agg8(const unsigned char* __restrict__ keys, const unsigned short* __restrict__ elist,
            const int* __restrict__ excl, const int* __restrict__ counts,
            unsigned short* __restrict__ A){
  constexpr int NW = C/128;           // uints per lane (1 or 2)
  int seg  = blockIdx.x*4 + (threadIdx.x >> 6);
  int l = threadIdx.x & 63, half = l >> 5, cl = l & 31;
  int cnt = counts[seg], start = excl[seg];
  const unsigned char* kp = keys + cl*(C/32);
  unsigned m0 = 0, m1 = 0;
  int i = 0;
  for(; i + 8 <= cnt; i += 8){
    int e0 = elist[start+i+half],   e1 = elist[start+i+2+half];
    int e2 = elist[start+i+4+half], e3 = elist[start+i+6+half];
    if constexpr(NW == 1){
      unsigned v0 = *(const unsigned*)(kp + (size_t)e0*C);
      unsigned v1 = *(const unsigned*)(kp + (size_t)e1*C);
      unsigned v2 = *(const unsigned*)(kp + (size_t)e2*C);
      unsigned v3 = *(const unsigned*)(kp + (size_t)e3*C);
      m0 = maxu8x4(m0, maxu8x4(maxu8x4(v0, v1), maxu8x4(v2, v3)));
    } else {
      uint2 v0 = *(const uint2*)(kp + (size_t)e0*C);
      uint2 v1 = *(const uint2*)(kp + (size_t)e1*C);
      uint2 v2 = *(const uint2*)(kp + (size_t)e2*C);
      uint2 v3 = *(const uint2*)(kp + (size_t)e3*C);
      m0 = maxu8x4(m0, maxu8x4(maxu8x4(v0.x, v1.x), maxu8x4(v2.x, v3.x)));
      m1 = maxu8x4(m1, maxu8x4(maxu8x4(v0.y, v1.y), maxu8x4(v2.y, v3.y)));
    }
  }
  for(; i + 2 <= cnt; i += 2){
    int e = elist[start+i+half];
    if constexpr(NW == 1){
      m0 = maxu8x4(m0, *(const unsigned*)(kp + (size_t)e*C));
    } else {
      uint2 v = *(const uint2*)(kp + (size_t)e*C);
      m0 = maxu8x4(m0, v.x); m1 = maxu8x4(m1, v.y);
    }
  }
  if(i < cnt && half == 0){
    int e = elist[start+i];
    if constexpr(NW == 1){
      m0 = maxu8x4(m0, *(const unsigned*)(kp + (size_t)e*C));
    } else {
      uint2 v = *(const uint2*)(kp + (size_t)e*C);
      m0 = maxu8x4(m0, v.x); m1 = maxu8x4(m1, v.y);
    }
  }
  m0 = maxu8x4(m0, (unsigned)__shfl_xor((int)m0, 32));
  if constexpr(NW == 2) m1 = maxu8x4(m1, (unsigned)__shfl_xor((int)m1, 32));
  if(half == 0){
    int n = seg >> 2, t = seg & 3;
    unsigned short* op = A + (size_t)n*AK + 2*C + t*C + cl*(C/32);
    if constexpr(NW == 1){
      typedef unsigned short u4 __attribute__((ext_vector_type(4)));
      u4 o;
      #pragma unroll
      for(int q = 0; q < 4; ++q)
        o[q] = (cnt == 0) ? (unsigned short)0 : key8tobf((unsigned char)(m0 >> (8*q)));
      *(u4*)op = o;
    } else {
      typedef unsigned short u8v __attribute__((ext_vector_type(8)));
      u8v o;
      #pragma unroll
      for(int q = 0; q < 4; ++q){
        o[q]   = (cnt == 0) ? (unsigned short)0 : key8tobf((unsigned char)(m0 >> (8*q)));
        o[4+q] = (cnt == 0) ? (unsigned short)0 : key8tobf((unsigned char)(m1 >> (8*q)));
      }
      *(u8v*)op = o;
    }
  }
}

// ---------------- BN1(inline finalize) + ReLU -> A2 [hi|lo] + fp8 key table ----------------
__global__ void k_bnrp(const float* __restrict__ h2, const float* __restrict__ sums,
                       const float* __restrict__ g, const float* __restrict__ bb,
                       unsigned short* __restrict__ A2, unsigned char* __restrict__ h2k8){
  int i = blockIdx.x*256 + threadIdx.x;
  if(i >= NN*FF2) return;
  int n = i >> 8, c = i & 255;
  float mean = sums[c] * (1.0f/NN);
  float var  = sums[256 + c] * (1.0f/NN) - mean*mean;
  float scale = g[c] / sqrtf(var + EPSBN);
  float shift = bb[c] - mean*scale;
  float v = fmaxf(h2[i]*scale + shift, 0.0f);
  unsigned short hu = f2bf(v);
  unsigned short lu = f2bf(v - bf2f(hu));
  unsigned short* r = A2 + (size_t)n*1536;
  r[c] = hu; r[256 + c] = lu;
  h2k8[i] = fold8(f2f8(v));
}

// ---------------- BN2(inline finalize) + sigmoid(x-10), in place ----------------
__global__ void k_bnsig(float* __restrict__ h, const float* __restrict__ sums,
                        const float* __restrict__ g, const float* __restrict__ bb){
  int i = blockIdx.x*256 + threadIdx.x;
  if(i >= NN*FF) return;
  int c = i & 127;
  float mean = sums[c] * (1.0f/NN);
  float var  = sums[128 + c] * (1.0f/NN) - mean*mean;
  float scale = g[c] / sqrtf(var + EPSBN);
  float shift = bb[c] - mean*scale;
  float v = h[i]*scale + shift - 10.0f;
  h[i] = 1.0f/(1.0f + expf(-v));
}

// ---------------- launch ----------------
extern "C" void kernel_launch(void* const* d_in, const int* in_sizes, int n_in,
                              void* d_out, int out_size, void* d_ws, size_t ws_size,
                              hipStream_t stream){
  (void)in_sizes; (void)n_in; (void)out_size; (void)ws_size;
  const float* x       = (const float*)d_in[0];
  const float* tbl     = (const float*)d_in[1];
  const int*   eidx    = (const int*)  d_in[2];
  const int*   etype   = (const int*)  d_in[3];
  const float* w_ih    = (const float*)d_in[4];
  const float* b_ih    = (const float*)d_in[6];
  const float* b_hh    = (const float*)d_in[7];
  const float* conv1_w = (const float*)d_in[8];
  const float* conv1_b = (const float*)d_in[9];
  const float* conv2_w = (const float*)d_in[10];
  const float* conv2_b = (const float*)d_in[11];
  const float* lin1_w  = (const float*)d_in[12];
  const float* lin1_b  = (const float*)d_in[13];
  const float* lin2_w  = (const float*)d_in[14];
  const float* lin2_b  = (const float*)d_in[15];
  const float* bn1_g   = (const float*)d_in[16];
  const float* bn1_b   = (const float*)d_in[17];
  const float* bn2_g   = (const float*)d_in[18];
  const float* bn2_b   = (const float*)d_in[19];
  float* out = (float*)d_out;

  char* base = (char*)d_ws;
  size_t off = 0;
  auto alloc = [&](size_t bytes){ char* p = base + off; off = (off + bytes + 255) & ~(size_t)255; return p; };

  unsigned short* A0 = (unsigned short*)alloc((size_t)MP * 256 * 2);   // 10.29 MB
  unsigned short* A1 = (unsigned short*)alloc((size_t)MP * 768 * 2);   // 30.87 MB
  unsigned short* A2 = (unsigned short*)alloc((size_t)MP * 1536 * 2);  // 61.73 MB
  float* h2raw = (float*)alloc((size_t)NN * 256 * 4);                  // 20.48 MB
  unsigned char* h1k8 = (unsigned char*)alloc((size_t)NN * 128);       // 2.56 MB
  unsigned char* h2k8 = (unsigned char*)alloc((size_t)NN * 256);       // 5.12 MB
  unsigned short* Bp0 = (unsigned short*)alloc((size_t)384 * 384 * 2);
  unsigned short* Bp1 = (unsigned short*)alloc((size_t)896 * 256 * 2);
  unsigned short* Bp2 = (unsigned short*)alloc((size_t)1792 * 128 * 2);
  float* bias0 = (float*)alloc(384 * 4);
  float* bias1 = (float*)alloc(256 * 4);
  float* bias2 = (float*)alloc(128 * 4);
  int* counts  = (int*)alloc(NSEG * 4);
  int* excl    = (int*)alloc(NSEG * 4);
  float* bnsum1 = (float*)alloc(512 * 4);
  float* bnsum2 = (float*)alloc(256 * 4);
  int* gbcnt   = (int*)alloc(NBUCK * 4);
  int* gbase   = (int*)alloc(NBUCK * 4);
  int* gcursor = (int*)alloc(NBUCK * 4);
  unsigned* gstage = (unsigned*)alloc((size_t)NE * 4);
  unsigned short* elist = (unsigned short*)alloc((size_t)NE * 2);

  // aliases (lifetimes disjoint)
  float* gates = (float*)A2;     // MP*384*4 = 30.9 MB, dead after k_act
  float* P1    = (float*)A2;     // 2*NN*256*4 = 41 MB, dead before k_bnrp writes A2
  float* P2    = (float*)A0;     // 4*NN*128*4 = 41 MB, spans A0+A1 (both dead by gemm2)

  const int* src = eidx;
  const int* dst = eidx + NE;

  // fused prep: pack B0/B1/B2, biases, zero counters/bn sums
  k_prep<<<(PB2 + 1850 + 255)/256, 256, 0, stream>>>(
      w_ih, lin1_w, conv1_w, lin2_w, conv2_w,
      b_ih, b_hh, lin1_b, conv1_b, lin2_b, conv2_b,
      Bp0, Bp1, Bp2, bias0, bias1, bias2, gbcnt, gcursor, bnsum1, bnsum2);

  k_osc_pack<<<(NN*FF + 255)/256, 256, 0, stream>>>(x, tbl, A0);

  // binned CSR build
  k_bcount<<<(NE + 2047)/2048, 256, 0, stream>>>(dst, gbcnt);
  k_bscan<<<1, 64, 0, stream>>>(gbcnt, gbase);
  k_binscat<<<(NE + 4095)/4096, 512, 0, stream>>>(src, dst, etype, gbase, gcursor, gstage);
  k_fine<<<NBUCK, 512, 0, stream>>>(gstage, gbcnt, gbase, counts, excl, elist);

  // LSTM: gates (i,g,o) = A0 x B0; bias+activation fused in k_act
  k_gemm<128, 384, 1, 256><<<dim3(157, 3, 1), 256, 0, stream>>>(A0, Bp0, gates);
  k_act<<<(NN*FF + 255)/256, 256, 0, stream>>>(gates, bias0, A1, h1k8);

  // layer 1
  k_agg8<128, 768><<<NSEG/4, 256, 0, stream>>>(h1k8, elist, excl, counts, A1);
  k_gemm<128, 256, 2, 768><<<dim3(157, 2, 2), 256, 0, stream>>>(A1, Bp1, P1);
  k_reduce<256, 2><<<256, 256, 0, stream>>>(P1, bias1, h2raw, bnsum1);
  k_bnrp<<<(NN*FF2 + 255)/256, 256, 0, stream>>>(h2raw, bnsum1, bn1_g, bn1_b, A2, h2k8);

  // layer 2
  k_agg8<256, 1536><<<NSEG/4, 256, 0, stream>>>(h2k8, elist, excl, counts, A2);
  k_gemm<256, 128, 4, 1536><<<dim3(157, 1, 4), 256, 0, stream>>>(A2, Bp2, P2);
  k_reduce<128, 4><<<256, 128, 0, stream>>>(P2, bias2, out, bnsum2);
  k_bnsig<<<(NN*FF + 255)/256, 256, 0, stream>>>(out, bnsum2, bn2_g, bn2_b);
}

// Round 8
// 288.539 us; speedup vs baseline: 3.3228x; 1.0091x over previous
//
#include <hip/hip_runtime.h>
#include <math.h>

#define NN 20000
#define NE 640000
#define TT 4
#define FF 128
#define FF2 256
#define NSEG (NN*TT)
#define MP 20096          // padded M (multiple of 128)
#define NBUCK 157         // ceil(20000/128) buckets of 128 nodes (512 segs each)
#define EPSBN 1e-5f

typedef short bf16x8 __attribute__((ext_vector_type(8)));
typedef float f32x4  __attribute__((ext_vector_type(4)));
typedef unsigned short us2 __attribute__((ext_vector_type(2)));

__device__ __forceinline__ float sigf(float x){ return 1.0f/(1.0f+expf(-x)); }

__device__ __forceinline__ unsigned short f2bf(float x){
  union { float f; unsigned u; } v; v.f = x;
  unsigned r = v.u + 0x7FFF + ((v.u >> 16) & 1);
  return (unsigned short)(r >> 16);
}
__device__ __forceinline__ float bf2f(unsigned short u){
  union { float f; unsigned u; } v; v.u = ((unsigned)u) << 16; return v.f;
}

// ---- fp8 e4m3fn helpers (monotone RTN-even encode; used for gather tables) ----
__device__ __forceinline__ unsigned char f2f8(float x){
  union{float f; unsigned u;} v; v.f = x;
  unsigned s = (v.u >> 24) & 0x80u;
  unsigned a = v.u & 0x7FFFFFFFu;
  if(a > 0x43E00000u) a = 0x43E00000u;          // clamp |x| to 448
  union{unsigned u; float f;} w; w.u = a;
  float ax = w.f;
  if(ax < 0.015625f){                           // denormal: ulp = 2^-9
    int q = (int)rintf(ax * 512.0f);            // 0..8 (8 -> min normal)
    return (unsigned char)(s | (unsigned)q);
  }
  unsigned rb = a & 0xFFFFFu;
  unsigned base = a >> 20;                      // exp(8) | mant(3)
  unsigned r = base + (((rb > 0x80000u) || (rb == 0x80000u && (base & 1u))) ? 1u : 0u);
  unsigned e = r >> 3, m3 = r & 7u;
  int fe = (int)e - 120;                        // e4m3 bias 7
  if(fe >= 16) return (unsigned char)(s | 0x7Eu);  // 448
  return (unsigned char)(s | ((unsigned)fe << 3) | m3);
}
// monotone u8 key (unsigned order == float order)
__device__ __forceinline__ unsigned char fold8(unsigned char b){
  return (unsigned char)(b ^ ((b & 0x80u) ? 0xFFu : 0x80u));
}
// key -> original fp8 -> bf16 bits (exact: 3-bit mantissa fits bf16)
__device__ __forceinline__ unsigned short key8tobf(unsigned char k){
  unsigned char b = (unsigned char)(k ^ ((k & 0x80u) ? 0x80u : 0xFFu));
  unsigned s = ((unsigned)b & 0x80u) << 24;
  unsigned e = ((unsigned)b >> 3) & 0xFu;
  unsigned m = (unsigned)b & 7u;
  union{unsigned u; float f;} v;
  if(e == 0){ v.f = (float)m * 0.001953125f; v.u |= s; }
  else v.u = s | ((e + 120u) << 23) | (m << 20);
  return (unsigned short)(v.u >> 16);
}
// accumulate per-byte max in deinterleaved (even,odd) u16-lane form:
// 2 v_perm + 2 v_pk_max_u16 per uint
__device__ __forceinline__ void acc8(unsigned v, unsigned &me, unsigned &mo){
  union U{unsigned u; us2 v;};
  U a, b, r;
  a.u = __builtin_amdgcn_perm(v, 0u, 0x0C060C04u);   // [b0, 0, b2, 0]
  b.u = me; r.v = __builtin_elementwise_max(a.v, b.v); me = r.u;
  a.u = __builtin_amdgcn_perm(v, 0u, 0x0C070C05u);   // [b1, 0, b3, 0]
  b.u = mo; r.v = __builtin_elementwise_max(a.v, b.v); mo = r.u;
}
__device__ __forceinline__ unsigned maxsplit(unsigned a, unsigned b){
  union U{unsigned u; us2 v;};
  U x, y, r; x.u = a; y.u = b;
  r.v = __builtin_elementwise_max(x.v, y.v);
  return r.u;
}

// ---------------- fused prep: pack B0/B1/B2 + biases + zero counters ----------------
#define PB0 147456                  // 384x384
#define PB1 (PB0 + 229376)          // + 896x256
#define PB2 (PB1 + 229376)          // + 1792x128
__global__ __launch_bounds__(256)
void k_prep(const float* __restrict__ w_ih, const float* __restrict__ lin1_w,
            const float* __restrict__ conv1_w, const float* __restrict__ lin2_w,
            const float* __restrict__ conv2_w,
            const float* __restrict__ bih, const float* __restrict__ bhh,
            const float* __restrict__ l1b, const float* __restrict__ c1b,
            const float* __restrict__ l2b, const float* __restrict__ c2b,
            unsigned short* __restrict__ Bp0, unsigned short* __restrict__ Bp1,
            unsigned short* __restrict__ Bp2,
            float* __restrict__ bias0, float* __restrict__ bias1, float* __restrict__ bias2,
            int* __restrict__ gbcnt, int* __restrict__ gcursor,
            float* __restrict__ bnsum1, float* __restrict__ bnsum2){
  int gi = blockIdx.x*256 + threadIdx.x;
  if(gi < PB0){                                  // B0: [hi|lo|hi] of w_ih (i,g,o rows)
    int k = gi/384, o = gi - k*384;
    int grow = (o < 128) ? o : o + 128;
    int reg = k >> 7, c = k & 127;
    float w = w_ih[(size_t)grow*128 + c];
    unsigned short hu = f2bf(w);
    Bp0[((size_t)(k >> 3)*384 + o)*8 + (k & 7)] = (reg == 1) ? f2bf(w - bf2f(hu)) : hu;
  } else if(gi < PB1){                           // B1: [hi|lo|hi|conv] C=128 COUT=256
    int i = gi - PB0; int k = i >> 8, o = i & 255;
    int reg = k >> 7;
    unsigned short val;
    if(reg < 3){
      float w = lin1_w[(size_t)o*128 + (k & 127)];
      unsigned short hu = f2bf(w);
      val = (reg == 1) ? f2bf(w - bf2f(hu)) : hu;
    } else {
      int kk = k - 384; int t = kk >> 7; int c = kk & 127;
      val = f2bf(conv1_w[((size_t)t*256 + o)*128 + c]);
    }
    Bp1[((size_t)(k >> 3)*256 + o)*8 + (k & 7)] = val;
  } else if(gi < PB2){                           // B2: C=256 COUT=128
    int i = gi - PB1; int k = i >> 7, o = i & 127;
    int reg = k >> 8;
    unsigned short val;
    if(reg < 3){
      float w = lin2_w[(size_t)o*256 + (k & 255)];
      unsigned short hu = f2bf(w);
      val = (reg == 1) ? f2bf(w - bf2f(hu)) : hu;
    } else {
      int kk = k - 768; int t = kk >> 8; int c = kk & 255;
      val = f2bf(conv2_w[((size_t)t*128 + o)*256 + c]);
    }
    Bp2[((size_t)(k >> 3)*128 + o)*8 + (k & 7)] = val;
  } else {                                       // tail: biases + zero fills
    int t = gi - PB2;
    if(t < 384){ int grow = (t < 128) ? t : t + 128; bias0[t] = bih[grow] + bhh[grow]; }
    else if(t < 640){ int c = t - 384; bias1[c] = l1b[c] + 4.0f*c1b[c]; }
    else if(t < 768){ int c = t - 640; bias2[c] = l2b[c] + 4.0f*c2b[c]; }
    else if(t < 1280){ bnsum1[t - 768] = 0.0f; }
    else if(t < 1536){ bnsum2[t - 1280] = 0.0f; }
    else if(t < 1536 + NBUCK){ gbcnt[t - 1536] = 0; }
    else if(t < 1536 + 2*NBUCK){ gcursor[t - 1536 - NBUCK] = 0; }
  }
}

// ---------------- oscillator -> A0 row-major [hi(128)|lo(128)] ----------------
__global__ void k_osc_pack(const float* __restrict__ x, const float* __restrict__ tbl,
                           unsigned short* __restrict__ A0){
  int i = blockIdx.x*256 + threadIdx.x;
  if(i >= NN*FF) return;
  int n = i >> 7, j = i & 127;
  float xv = x[i];
  float xi = (xv < -0.5f || xv > 0.5f) ? 0.5001f : xv;
  int idx = (int)floorf((xi + 0.5f) * 10000.0f);
  float tv = tbl[idx];
  float hv = (tv == 0.0f) ? sigf(xv) : tv;
  unsigned short hu = f2bf(hv);
  unsigned short lu = f2bf(hv - bf2f(hu));
  unsigned short* r = A0 + (size_t)n*256;
  r[j] = hu; r[128+j] = lu;
}

// ---------------- MFMA GEMM, 64x64 per wave, hi/lo A reuse + balanced split-K ----
template<int C, int COUT, int SPLITS, int AK>
__global__ __launch_bounds__(256)
void k_gemm(const unsigned short* __restrict__ A, const unsigned short* __restrict__ Bp,
            float* __restrict__ out){
  int w  = threadIdx.x >> 6;
  int l  = threadIdx.x & 63;
  int wr = w >> 1, wc = w & 1;
  int lr = l & 15, lg = l >> 4;
  int n0 = blockIdx.x*128 + wr*64;
  int c0 = blockIdx.y*128 + wc*64;
  constexpr int Q = (AK + C)/SPLITS;   // MFMA-K per split
  int zq0 = blockIdx.z*Q, zq1 = zq0 + Q;
  int kb = (zq0 <= 2*C) ? (zq0 >> 1) : (zq0 - C);
  int ke = (zq1 <= 2*C) ? (zq1 >> 1) : (zq1 - C);
  const size_t abase = (size_t)(n0 + lr)*AK + lg*8;
  const size_t bstep = (size_t)COUT*8;
  const unsigned short* bcolp = Bp + (size_t)(c0 + lr)*8 + lg*bstep;
  f32x4 acc[4][4] = {};
  int kde = ke < C ? ke : C;
  for(int ak = kb; ak < kde; ak += 32){
    bf16x8 a[4];
    #pragma unroll
    for(int r = 0; r < 4; ++r) a[r] = *(const bf16x8*)(A + abase + (size_t)r*16*AK + ak);
    const unsigned short* p1 = bcolp + (size_t)(ak >> 3)*bstep;
    const unsigned short* p2 = bcolp + (size_t)((C + ak) >> 3)*bstep;
    #pragma unroll
    for(int j = 0; j < 4; ++j){
      bf16x8 b1 = *(const bf16x8*)(p1 + j*128);
      bf16x8 b2 = *(const bf16x8*)(p2 + j*128);
      #pragma unroll
      for(int r = 0; r < 4; ++r){
        acc[r][j] = __builtin_amdgcn_mfma_f32_16x16x32_bf16(a[r], b1, acc[r][j], 0, 0, 0);
        acc[r][j] = __builtin_amdgcn_mfma_f32_16x16x32_bf16(a[r], b2, acc[r][j], 0, 0, 0);
      }
    }
  }
  int ks = kb > C ? kb : C;
  for(int ak = ks; ak < ke; ak += 32){
    bf16x8 a[4];
    #pragma unroll
    for(int r = 0; r < 4; ++r) a[r] = *(const bf16x8*)(A + abase + (size_t)r*16*AK + ak);
    const unsigned short* p = bcolp + (size_t)((C + ak) >> 3)*bstep;
    #pragma unroll
    for(int j = 0; j < 4; ++j){
      bf16x8 b = *(const bf16x8*)(p + j*128);
      #pragma unroll
      for(int r = 0; r < 4; ++r)
        acc[r][j] = __builtin_amdgcn_mfma_f32_16x16x32_bf16(a[r], b, acc[r][j], 0, 0, 0);
    }
  }
  float* o = out + (size_t)blockIdx.z*NN*COUT;
  #pragma unroll
  for(int r = 0; r < 4; ++r){
    int nb = n0 + r*16 + lg*4;
    #pragma unroll
    for(int j = 0; j < 4; ++j){
      int oc = c0 + j*16 + lr;
      #pragma unroll
      for(int q = 0; q < 4; ++q){
        int n = nb + q;
        if(n < NN) o[(size_t)n*COUT + oc] = acc[r][j][q];
      }
    }
  }
}

// ---------------- split-K reduce + bias + BN stats ----------------
template<int COUT, int SPLITS>
__global__ __launch_bounds__(COUT)
void k_reduce(const float* __restrict__ P, const float* __restrict__ bias,
              float* __restrict__ h, float* __restrict__ sums){
  int c = threadIdx.x;
  float bs = bias[c];
  float s = 0.0f, s2 = 0.0f;
  for(int n = blockIdx.x; n < NN; n += gridDim.x){
    float v = bs;
    #pragma unroll
    for(int z = 0; z < SPLITS; ++z) v += P[(size_t)z*NN*COUT + (size_t)n*COUT + c];
    h[(size_t)n*COUT + c] = v;
    s += v; s2 += v*v;
  }
  atomicAdd(&sums[c], s);
  atomicAdd(&sums[COUT + c], s2);
}

// ---------------- LSTM activation (+bias) -> A1 [hi|lo] + fp8 key table ----------------
__global__ void k_act(const float* __restrict__ gates, const float* __restrict__ bias0,
                      unsigned short* __restrict__ A1, unsigned char* __restrict__ h1k8){
  int i = blockIdx.x*256 + threadIdx.x;
  if(i >= NN*FF) return;
  int n = i >> 7, j = i & 127;
  const float* g = gates + (size_t)n*384;
  float ig = g[j]       + bias0[j];
  float gg = g[128 + j] + bias0[128 + j];
  float og = g[256 + j] + bias0[256 + j];
  float c  = sigf(ig) * tanhf(gg);
  float hv = sigf(og) * tanhf(c);
  unsigned short hu = f2bf(hv);
  unsigned short lu = f2bf(hv - bf2f(hu));
  unsigned short* r = A1 + (size_t)n*768;
  r[j] = hu; r[128 + j] = lu;
  h1k8[i] = fold8(f2f8(hv));
}

// ---------------- binned CSR build ----------------
__global__ void k_bcount(const int* __restrict__ dst, int* __restrict__ gbcnt){
  __shared__ int h[NBUCK];
  for(int i = threadIdx.x; i < NBUCK; i += 256) h[i] = 0;
  __syncthreads();
  int e0 = blockIdx.x*2048;
  #pragma unroll
  for(int k = 0; k < 8; ++k){
    int e = e0 + threadIdx.x + k*256;
    if(e < NE) atomicAdd(&h[dst[e] >> 7], 1);
  }
  __syncthreads();
  for(int i = threadIdx.x; i < NBUCK; i += 256) if(h[i]) atomicAdd(&gbcnt[i], h[i]);
}
__global__ void k_bscan(const int* __restrict__ gbcnt, int* __restrict__ gbase){
  if(threadIdx.x == 0){
    int s = 0;
    for(int i = 0; i < NBUCK; ++i){ gbase[i] = s; s += gbcnt[i]; }
  }
}
__global__ __launch_bounds__(512)
void k_binscat(const int* __restrict__ src, const int* __restrict__ dst,
               const int* __restrict__ et, const int* __restrict__ gbase,
               int* __restrict__ gcursor, unsigned* __restrict__ gstage){
  __shared__ unsigned stage[4096];
  __shared__ unsigned char stgb[4096];
  __shared__ int lcnt[NBUCK], lexc[NBUCK], lcur[NBUCK], gofs[NBUCK];
  int tid = threadIdx.x;
  for(int i = tid; i < NBUCK; i += 512) lcnt[i] = 0;
  __syncthreads();
  int e0 = blockIdx.x*4096;
  int b_[8]; unsigned v_[8];
  #pragma unroll
  for(int k = 0; k < 8; ++k){
    int e = e0 + tid + k*512;
    if(e < NE){
      int d = dst[e]; int b = d >> 7;
      b_[k] = b;
      v_[k] = ((unsigned)((((d & 127) << 2) | et[e])) << 16) | (unsigned)src[e];
      atomicAdd(&lcnt[b], 1);
    } else b_[k] = -1;
  }
  __syncthreads();
  if(tid == 0){
    int s = 0;
    for(int i = 0; i < NBUCK; ++i){ lexc[i] = s; s += lcnt[i]; }
  }
  __syncthreads();
  if(tid < NBUCK){
    lcur[tid] = lexc[tid];
    if(lcnt[tid]) gofs[tid] = atomicAdd(&gcursor[tid], lcnt[tid]);
  }
  __syncthreads();
  #pragma unroll
  for(int k = 0; k < 8; ++k){
    if(b_[k] >= 0){
      int p = atomicAdd(&lcur[b_[k]], 1);
      stage[p] = v_[k]; stgb[p] = (unsigned char)b_[k];
    }
  }
  __syncthreads();
  int ne = NE - e0; if(ne > 4096) ne = 4096;
  for(int i = tid; i < ne; i += 512){
    int b = stgb[i];
    gstage[gbase[b] + gofs[b] + (i - lexc[b])] = stage[i];
  }
}
__global__ __launch_bounds__(512)
void k_fine(const unsigned* __restrict__ gstage, const int* __restrict__ gbcnt,
            const int* __restrict__ gbase, int* __restrict__ counts,
            int* __restrict__ excl, unsigned short* __restrict__ elist){
  __shared__ int cnt[512], scn[512], cur[512];
  int t = threadIdx.x, bk = blockIdx.x;
  cnt[t] = 0;
  __syncthreads();
  int gB = gbase[bk], cE = gbcnt[bk];
  for(int i = t; i < cE; i += 512) atomicAdd(&cnt[gstage[gB + i] >> 16], 1);
  __syncthreads();
  scn[t] = cnt[t]; __syncthreads();
  for(int off = 1; off < 512; off <<= 1){
    int add = (t >= off) ? scn[t - off] : 0;
    __syncthreads();
    scn[t] += add;
    __syncthreads();
  }
  int ex = scn[t] - cnt[t];
  cur[t] = ex;
  int s = bk*512 + t;
  if(s < NSEG){ counts[s] = cnt[t]; excl[s] = gB + ex; }
  __syncthreads();
  for(int i = t; i < cE; i += 512){
    unsigned v = gstage[gB + i];
    int p = atomicAdd(&cur[v >> 16], 1);
    elist[gB + p] = (unsigned short)(v & 0xFFFFu);
  }
}

// ---------------- per-segment max over fp8 keys (perm-deinterleaved) ----------------
template<int C, int AK>
__global__ __launch_bounds__(256)
void k_agg8(const unsigned char* __restrict__ keys, const unsigned short* __restrict__ elist,
            const int* __restrict__ excl, const int* __restrict__ counts,
            unsigned short* __restrict__ A){
  constexpr int NW = C/128;           // uints per lane (1 or 2)
  int seg  = blockIdx.x*4 + (threadIdx.x >> 6);
  int l = threadIdx.x & 63, half = l >> 5, cl = l & 31;
  int cnt = counts[seg], start = excl[seg];
  const unsigned char* kp = keys + cl*(C/32);
  unsigned me0 = 0, mo0 = 0, me1 = 0, mo1 = 0;
  int i = 0;
  for(; i + 8 <= cnt; i += 8){
    int e0 = elist[start+i+half],   e1 = elist[start+i+2+half];
    int e2 = elist[start+i+4+half], e3 = elist[start+i+6+half];
    if constexpr(NW == 1){
      unsigned v0 = *(const unsigned*)(kp + (size_t)e0*C);
      unsigned v1 = *(const unsigned*)(kp + (size_t)e1*C);
      unsigned v2 = *(const unsigned*)(kp + (size_t)e2*C);
      unsigned v3 = *(const unsigned*)(kp + (size_t)e3*C);
      acc8(v0, me0, mo0); acc8(v1, me0, mo0);
      acc8(v2, me0, mo0); acc8(v3, me0, mo0);
    } else {
      uint2 v0 = *(const uint2*)(kp + (size_t)e0*C);
      uint2 v1 = *(const uint2*)(kp + (size_t)e1*C);
      uint2 v2 = *(const uint2*)(kp + (size_t)e2*C);
      uint2 v3 = *(const uint2*)(kp + (size_t)e3*C);
      acc8(v0.x, me0, mo0); acc8(v0.y, me1, mo1);
      acc8(v1.x, me0, mo0); acc8(v1.y, me1, mo1);
      acc8(v2.x, me0, mo0); acc8(v2.y, me1, mo1);
      acc8(v3.x, me0, mo0); acc8(v3.y, me1, mo1);
    }
  }
  for(; i + 2 <= cnt; i += 2){
    int e = elist[start+i+half];
    if constexpr(NW == 1){
      acc8(*(const unsigned*)(kp + (size_t)e*C), me0, mo0);
    } else {
      uint2 v = *(const uint2*)(kp + (size_t)e*C);
      acc8(v.x, me0, mo0); acc8(v.y, me1, mo1);
    }
  }
  if(i < cnt && half == 0){
    int e = elist[start+i];
    if constexpr(NW == 1){
      acc8(*(const unsigned*)(kp + (size_t)e*C), me0, mo0);
    } else {
      uint2 v = *(const uint2*)(kp + (size_t)e*C);
      acc8(v.x, me0, mo0); acc8(v.y, me1, mo1);
    }
  }
  // merge halves (lanes l and l^32 hold the same channels)
  me0 = maxsplit(me0, (unsigned)__shfl_xor((int)me0, 32));
  mo0 = maxsplit(mo0, (unsigned)__shfl_xor((int)mo0, 32));
  if constexpr(NW == 2){
    me1 = maxsplit(me1, (unsigned)__shfl_xor((int)me1, 32));
    mo1 = maxsplit(mo1, (unsigned)__shfl_xor((int)mo1, 32));
  }
  if(half == 0){
    int n = seg >> 2, t = seg & 3;
    unsigned short* op = A + (size_t)n*AK + 2*C + t*C + cl*(C/32);
    // channels per uint j: [j*4+0]=me.lo, [j*4+1]=mo.lo, [j*4+2]=me.hi, [j*4+3]=mo.hi
    if constexpr(NW == 1){
      typedef unsigned short u4 __attribute__((ext_vector_type(4)));
      u4 o;
      o[0] = (cnt == 0) ? (unsigned short)0 : key8tobf((unsigned char)(me0 & 0xFF));
      o[1] = (cnt == 0) ? (unsigned short)0 : key8tobf((unsigned char)(mo0 & 0xFF));
      o[2] = (cnt == 0) ? (unsigned short)0 : key8tobf((unsigned char)(me0 >> 16));
      o[3] = (cnt == 0) ? (unsigned short)0 : key8tobf((unsigned char)(mo0 >> 16));
      *(u4*)op = o;
    } else {
      typedef unsigned short u8v __attribute__((ext_vector_type(8)));
      u8v o;
      o[0] = (cnt == 0) ? (unsigned short)0 : key8tobf((unsigned char)(me0 & 0xFF));
      o[1] = (cnt == 0) ? (unsigned short)0 : key8tobf((unsigned char)(mo0 & 0xFF));
      o[2] = (cnt == 0) ? (unsigned short)0 : key8tobf((unsigned char)(me0 >> 16));
      o[3] = (cnt == 0) ? (unsigned short)0 : key8tobf((unsigned char)(mo0 >> 16));
      o[4] = (cnt == 0) ? (unsigned short)0 : key8tobf((unsigned char)(me1 & 0xFF));
      o[5] = (cnt == 0) ? (unsigned short)0 : key8tobf((unsigned char)(mo1 & 0xFF));
      o[6] = (cnt == 0) ? (unsigned short)0 : key8tobf((unsigned char)(me1 >> 16));
      o[7] = (cnt == 0) ? (unsigned short)0 : key8tobf((unsigned char)(mo1 >> 16));
      *(u8v*)op = o;
    }
  }
}

// ---------------- BN1(inline finalize) + ReLU -> A2 [hi|lo] + fp8 key table ----------------
__global__ void k_bnrp(const float* __restrict__ h2, const float* __restrict__ sums,
                       const float* __restrict__ g, const float* __restrict__ bb,
                       unsigned short* __restrict__ A2, unsigned char* __restrict__ h2k8){
  int i = blockIdx.x*256 + threadIdx.x;
  if(i >= NN*FF2) return;
  int n = i >> 8, c = i & 255;
  float mean = sums[c] * (1.0f/NN);
  float var  = sums[256 + c] * (1.0f/NN) - mean*mean;
  float scale = g[c] / sqrtf(var + EPSBN);
  float shift = bb[c] - mean*scale;
  float v = fmaxf(h2[i]*scale + shift, 0.0f);
  unsigned short hu = f2bf(v);
  unsigned short lu = f2bf(v - bf2f(hu));
  unsigned short* r = A2 + (size_t)n*1536;
  r[c] = hu; r[256 + c] = lu;
  h2k8[i] = fold8(f2f8(v));
}

// ---------------- BN2(inline finalize) + sigmoid(x-10), in place ----------------
__global__ void k_bnsig(float* __restrict__ h, const float* __restrict__ sums,
                        const float* __restrict__ g, const float* __restrict__ bb){
  int i = blockIdx.x*256 + threadIdx.x;
  if(i >= NN*FF) return;
  int c = i & 127;
  float mean = sums[c] * (1.0f/NN);
  float var  = sums[128 + c] * (1.0f/NN) - mean*mean;
  float scale = g[c] / sqrtf(var + EPSBN);
  float shift = bb[c] - mean*scale;
  float v = h[i]*scale + shift - 10.0f;
  h[i] = 1.0f/(1.0f + expf(-v));
}

// ---------------- launch ----------------
extern "C" void kernel_launch(void* const* d_in, const int* in_sizes, int n_in,
                              void* d_out, int out_size, void* d_ws, size_t ws_size,
                              hipStream_t stream){
  (void)in_sizes; (void)n_in; (void)out_size; (void)ws_size;
  const float* x       = (const float*)d_in[0];
  const float* tbl     = (const float*)d_in[1];
  const int*   eidx    = (const int*)  d_in[2];
  const int*   etype   = (const int*)  d_in[3];
  const float* w_ih    = (const float*)d_in[4];
  const float* b_ih    = (const float*)d_in[6];
  const float* b_hh    = (const float*)d_in[7];
  const float* conv1_w = (const float*)d_in[8];
  const float* conv1_b = (const float*)d_in[9];
  const float* conv2_w = (const float*)d_in[10];
  const float* conv2_b = (const float*)d_in[11];
  const float* lin1_w  = (const float*)d_in[12];
  const float* lin1_b  = (const float*)d_in[13];
  const float* lin2_w  = (const float*)d_in[14];
  const float* lin2_b  = (const float*)d_in[15];
  const float* bn1_g   = (const float*)d_in[16];
  const float* bn1_b   = (const float*)d_in[17];
  const float* bn2_g   = (const float*)d_in[18];
  const float* bn2_b   = (const float*)d_in[19];
  float* out = (float*)d_out;

  char* base = (char*)d_ws;
  size_t off = 0;
  auto alloc = [&](size_t bytes){ char* p = base + off; off = (off + bytes + 255) & ~(size_t)255; return p; };

  unsigned short* A0 = (unsigned short*)alloc((size_t)MP * 256 * 2);   // 10.29 MB
  unsigned short* A1 = (unsigned short*)alloc((size_t)MP * 768 * 2);   // 30.87 MB
  unsigned short* A2 = (unsigned short*)alloc((size_t)MP * 1536 * 2);  // 61.73 MB
  float* h2raw = (float*)alloc((size_t)NN * 256 * 4);                  // 20.48 MB
  unsigned char* h1k8 = (unsigned char*)alloc((size_t)NN * 128);       // 2.56 MB
  unsigned char* h2k8 = (unsigned char*)alloc((size_t)NN * 256);       // 5.12 MB
  unsigned short* Bp0 = (unsigned short*)alloc((size_t)384 * 384 * 2);
  unsigned short* Bp1 = (unsigned short*)alloc((size_t)896 * 256 * 2);
  unsigned short* Bp2 = (unsigned short*)alloc((size_t)1792 * 128 * 2);
  float* bias0 = (float*)alloc(384 * 4);
  float* bias1 = (float*)alloc(256 * 4);
  float* bias2 = (float*)alloc(128 * 4);
  int* counts  = (int*)alloc(NSEG * 4);
  int* excl    = (int*)alloc(NSEG * 4);
  float* bnsum1 = (float*)alloc(512 * 4);
  float* bnsum2 = (float*)alloc(256 * 4);
  int* gbcnt   = (int*)alloc(NBUCK * 4);
  int* gbase   = (int*)alloc(NBUCK * 4);
  int* gcursor = (int*)alloc(NBUCK * 4);
  unsigned* gstage = (unsigned*)alloc((size_t)NE * 4);
  unsigned short* elist = (unsigned short*)alloc((size_t)NE * 2);

  // aliases (lifetimes disjoint)
  float* gates = (float*)A2;     // MP*384*4 = 30.9 MB, dead after k_act
  float* P1    = (float*)A2;     // 2*NN*256*4 = 41 MB, dead before k_bnrp writes A2
  float* P2    = (float*)A0;     // 4*NN*128*4 = 41 MB, spans A0+A1 (both dead by gemm2)

  const int* src = eidx;
  const int* dst = eidx + NE;

  // fused prep: pack B0/B1/B2, biases, zero counters/bn sums
  k_prep<<<(PB2 + 1850 + 255)/256, 256, 0, stream>>>(
      w_ih, lin1_w, conv1_w, lin2_w, conv2_w,
      b_ih, b_hh, lin1_b, conv1_b, lin2_b, conv2_b,
      Bp0, Bp1, Bp2, bias0, bias1, bias2, gbcnt, gcursor, bnsum1, bnsum2);

  k_osc_pack<<<(NN*FF + 255)/256, 256, 0, stream>>>(x, tbl, A0);

  // binned CSR build
  k_bcount<<<(NE + 2047)/2048, 256, 0, stream>>>(dst, gbcnt);
  k_bscan<<<1, 64, 0, stream>>>(gbcnt, gbase);
  k_binscat<<<(NE + 4095)/4096, 512, 0, stream>>>(src, dst, etype, gbase, gcursor, gstage);
  k_fine<<<NBUCK, 512, 0, stream>>>(gstage, gbcnt, gbase, counts, excl, elist);

  // LSTM: gates (i,g,o) = A0 x B0; bias+activation fused in k_act
  k_gemm<128, 384, 1, 256><<<dim3(157, 3, 1), 256, 0, stream>>>(A0, Bp0, gates);
  k_act<<<(NN*FF + 255)/256, 256, 0, stream>>>(gates, bias0, A1, h1k8);

  // layer 1
  k_agg8<128, 768><<<NSEG/4, 256, 0, stream>>>(h1k8, elist, excl, counts, A1);
  k_gemm<128, 256, 2, 768><<<dim3(157, 2, 2), 256, 0, stream>>>(A1, Bp1, P1);
  k_reduce<256, 2><<<256, 256, 0, stream>>>(P1, bias1, h2raw, bnsum1);
  k_bnrp<<<(NN*FF2 + 255)/256, 256, 0, stream>>>(h2raw, bnsum1, bn1_g, bn1_b, A2, h2k8);

  // layer 2
  k_agg8<256, 1536><<<NSEG/4, 256, 0, stream>>>(h2k8, elist, excl, counts, A2);
  k_gemm<256, 128, 4, 1536><<<dim3(157, 1, 4), 256, 0, stream>>>(A2, Bp2, P2);
  k_reduce<128, 4><<<256, 128, 0, stream>>>(P2, bias2, out, bnsum2);
  k_bnsig<<<(NN*FF + 255)/256, 256, 0, stream>>>(out, bnsum2, bn2_g, bn2_b);
}

// Round 9
// 277.486 us; speedup vs baseline: 3.4552x; 1.0398x over previous
//
#include <hip/hip_runtime.h>
#include <math.h>

#define NN 20000
#define NE 640000
#define TT 4
#define FF 128
#define FF2 256
#define NSEG (NN*TT)
#define MP 20096          // padded M (multiple of 128)
#define NBUCK 157         // ceil(20000/128) buckets of 128 nodes (512 segs each)
#define EPSBN 1e-5f

typedef short bf16x8 __attribute__((ext_vector_type(8)));
typedef float f32x4  __attribute__((ext_vector_type(4)));
typedef unsigned short us2 __attribute__((ext_vector_type(2)));

__device__ __forceinline__ float sigf(float x){ return 1.0f/(1.0f+expf(-x)); }

__device__ __forceinline__ unsigned short f2bf(float x){
  union { float f; unsigned u; } v; v.f = x;
  unsigned r = v.u + 0x7FFF + ((v.u >> 16) & 1);
  return (unsigned short)(r >> 16);
}
__device__ __forceinline__ float bf2f(unsigned short u){
  union { float f; unsigned u; } v; v.u = ((unsigned)u) << 16; return v.f;
}

// ---- fp8 e4m3fn helpers (monotone RTN-even encode; used for gather tables) ----
__device__ __forceinline__ unsigned char f2f8(float x){
  union{float f; unsigned u;} v; v.f = x;
  unsigned s = (v.u >> 24) & 0x80u;
  unsigned a = v.u & 0x7FFFFFFFu;
  if(a > 0x43E00000u) a = 0x43E00000u;          // clamp |x| to 448
  union{unsigned u; float f;} w; w.u = a;
  float ax = w.f;
  if(ax < 0.015625f){                           // denormal: ulp = 2^-9
    int q = (int)rintf(ax * 512.0f);            // 0..8 (8 -> min normal)
    return (unsigned char)(s | (unsigned)q);
  }
  unsigned rb = a & 0xFFFFFu;
  unsigned base = a >> 20;                      // exp(8) | mant(3)
  unsigned r = base + (((rb > 0x80000u) || (rb == 0x80000u && (base & 1u))) ? 1u : 0u);
  unsigned e = r >> 3, m3 = r & 7u;
  int fe = (int)e - 120;                        // e4m3 bias 7
  if(fe >= 16) return (unsigned char)(s | 0x7Eu);  // 448
  return (unsigned char)(s | ((unsigned)fe << 3) | m3);
}
// monotone u8 key (unsigned order == float order)
__device__ __forceinline__ unsigned char fold8(unsigned char b){
  return (unsigned char)(b ^ ((b & 0x80u) ? 0xFFu : 0x80u));
}
// key -> original fp8 -> bf16 bits (exact: 3-bit mantissa fits bf16)
__device__ __forceinline__ unsigned short key8tobf(unsigned char k){
  unsigned char b = (unsigned char)(k ^ ((k & 0x80u) ? 0x80u : 0xFFu));
  unsigned s = ((unsigned)b & 0x80u) << 24;
  unsigned e = ((unsigned)b >> 3) & 0xFu;
  unsigned m = (unsigned)b & 7u;
  union{unsigned u; float f;} v;
  if(e == 0){ v.f = (float)m * 0.001953125f; v.u |= s; }
  else v.u = s | ((e + 120u) << 23) | (m << 20);
  return (unsigned short)(v.u >> 16);
}
// accumulate per-byte max in deinterleaved (even,odd) u16-lane form:
// 2 v_perm + 2 v_pk_max_u16 per uint
__device__ __forceinline__ void acc8(unsigned v, unsigned &me, unsigned &mo){
  union U{unsigned u; us2 v;};
  U a, b, r;
  a.u = __builtin_amdgcn_perm(v, 0u, 0x0C060C04u);   // [b0, 0, b2, 0]
  b.u = me; r.v = __builtin_elementwise_max(a.v, b.v); me = r.u;
  a.u = __builtin_amdgcn_perm(v, 0u, 0x0C070C05u);   // [b1, 0, b3, 0]
  b.u = mo; r.v = __builtin_elementwise_max(a.v, b.v); mo = r.u;
}
__device__ __forceinline__ unsigned maxsplit(unsigned a, unsigned b){
  union U{unsigned u; us2 v;};
  U x, y, r; x.u = a; y.u = b;
  r.v = __builtin_elementwise_max(x.v, y.v);
  return r.u;
}

// ---------------- fused prep: pack B0/B1/B2 + biases + zero counters ----------------
#define PB0 147456                  // 384x384
#define PB1 (PB0 + 229376)          // + 896x256
#define PB2 (PB1 + 229376)          // + 1792x128
__global__ __launch_bounds__(256)
void k_prep(const float* __restrict__ w_ih, const float* __restrict__ lin1_w,
            const float* __restrict__ conv1_w, const float* __restrict__ lin2_w,
            const float* __restrict__ conv2_w,
            const float* __restrict__ bih, const float* __restrict__ bhh,
            const float* __restrict__ l1b, const float* __restrict__ c1b,
            const float* __restrict__ l2b, const float* __restrict__ c2b,
            unsigned short* __restrict__ Bp0, unsigned short* __restrict__ Bp1,
            unsigned short* __restrict__ Bp2,
            float* __restrict__ bias0, float* __restrict__ bias1, float* __restrict__ bias2,
            int* __restrict__ gbcnt, int* __restrict__ gcursor,
            float* __restrict__ bnsum1, float* __restrict__ bnsum2){
  int gi = blockIdx.x*256 + threadIdx.x;
  if(gi < PB0){                                  // B0: [hi|lo|hi] of w_ih (i,g,o rows)
    int k = gi/384, o = gi - k*384;
    int grow = (o < 128) ? o : o + 128;
    int reg = k >> 7, c = k & 127;
    float w = w_ih[(size_t)grow*128 + c];
    unsigned short hu = f2bf(w);
    Bp0[((size_t)(k >> 3)*384 + o)*8 + (k & 7)] = (reg == 1) ? f2bf(w - bf2f(hu)) : hu;
  } else if(gi < PB1){                           // B1: [hi|lo|hi|conv] C=128 COUT=256
    int i = gi - PB0; int k = i >> 8, o = i & 255;
    int reg = k >> 7;
    unsigned short val;
    if(reg < 3){
      float w = lin1_w[(size_t)o*128 + (k & 127)];
      unsigned short hu = f2bf(w);
      val = (reg == 1) ? f2bf(w - bf2f(hu)) : hu;
    } else {
      int kk = k - 384; int t = kk >> 7; int c = kk & 127;
      val = f2bf(conv1_w[((size_t)t*256 + o)*128 + c]);
    }
    Bp1[((size_t)(k >> 3)*256 + o)*8 + (k & 7)] = val;
  } else if(gi < PB2){                           // B2: C=256 COUT=128
    int i = gi - PB1; int k = i >> 7, o = i & 127;
    int reg = k >> 8;
    unsigned short val;
    if(reg < 3){
      float w = lin2_w[(size_t)o*256 + (k & 255)];
      unsigned short hu = f2bf(w);
      val = (reg == 1) ? f2bf(w - bf2f(hu)) : hu;
    } else {
      int kk = k - 768; int t = kk >> 8; int c = kk & 255;
      val = f2bf(conv2_w[((size_t)t*128 + o)*256 + c]);
    }
    Bp2[((size_t)(k >> 3)*128 + o)*8 + (k & 7)] = val;
  } else {                                       // tail: biases + zero fills
    int t = gi - PB2;
    if(t < 384){ int grow = (t < 128) ? t : t + 128; bias0[t] = bih[grow] + bhh[grow]; }
    else if(t < 640){ int c = t - 384; bias1[c] = l1b[c] + 4.0f*c1b[c]; }
    else if(t < 768){ int c = t - 640; bias2[c] = l2b[c] + 4.0f*c2b[c]; }
    else if(t < 1280){ bnsum1[t - 768] = 0.0f; }
    else if(t < 1536){ bnsum2[t - 1280] = 0.0f; }
    else if(t < 1536 + NBUCK){ gbcnt[t - 1536] = 0; }
    else if(t < 1536 + 2*NBUCK){ gcursor[t - 1536 - NBUCK] = 0; }
  }
}

// ---------------- oscillator -> A0 row-major [hi(128)|lo(128)] ----------------
__global__ void k_osc_pack(const float* __restrict__ x, const float* __restrict__ tbl,
                           unsigned short* __restrict__ A0){
  int i = blockIdx.x*256 + threadIdx.x;
  if(i >= NN*FF) return;
  int n = i >> 7, j = i & 127;
  float xv = x[i];
  float xi = (xv < -0.5f || xv > 0.5f) ? 0.5001f : xv;
  int idx = (int)floorf((xi + 0.5f) * 10000.0f);
  float tv = tbl[idx];
  float hv = (tv == 0.0f) ? sigf(xv) : tv;
  unsigned short hu = f2bf(hv);
  unsigned short lu = f2bf(hv - bf2f(hu));
  unsigned short* r = A0 + (size_t)n*256;
  r[j] = hu; r[128+j] = lu;
}

// ---------------- MFMA GEMM, 64x64 per wave, hi/lo A reuse + balanced split-K ----
template<int C, int COUT, int SPLITS, int AK>
__global__ __launch_bounds__(256)
void k_gemm(const unsigned short* __restrict__ A, const unsigned short* __restrict__ Bp,
            float* __restrict__ out){
  int w  = threadIdx.x >> 6;
  int l  = threadIdx.x & 63;
  int wr = w >> 1, wc = w & 1;
  int lr = l & 15, lg = l >> 4;
  int n0 = blockIdx.x*128 + wr*64;
  int c0 = blockIdx.y*128 + wc*64;
  constexpr int Q = (AK + C)/SPLITS;   // MFMA-K per split
  int zq0 = blockIdx.z*Q, zq1 = zq0 + Q;
  int kb = (zq0 <= 2*C) ? (zq0 >> 1) : (zq0 - C);
  int ke = (zq1 <= 2*C) ? (zq1 >> 1) : (zq1 - C);
  const size_t abase = (size_t)(n0 + lr)*AK + lg*8;
  const size_t bstep = (size_t)COUT*8;
  const unsigned short* bcolp = Bp + (size_t)(c0 + lr)*8 + lg*bstep;
  f32x4 acc[4][4] = {};
  int kde = ke < C ? ke : C;
  for(int ak = kb; ak < kde; ak += 32){
    bf16x8 a[4];
    #pragma unroll
    for(int r = 0; r < 4; ++r) a[r] = *(const bf16x8*)(A + abase + (size_t)r*16*AK + ak);
    const unsigned short* p1 = bcolp + (size_t)(ak >> 3)*bstep;
    const unsigned short* p2 = bcolp + (size_t)((C + ak) >> 3)*bstep;
    #pragma unroll
    for(int j = 0; j < 4; ++j){
      bf16x8 b1 = *(const bf16x8*)(p1 + j*128);
      bf16x8 b2 = *(const bf16x8*)(p2 + j*128);
      #pragma unroll
      for(int r = 0; r < 4; ++r){
        acc[r][j] = __builtin_amdgcn_mfma_f32_16x16x32_bf16(a[r], b1, acc[r][j], 0, 0, 0);
        acc[r][j] = __builtin_amdgcn_mfma_f32_16x16x32_bf16(a[r], b2, acc[r][j], 0, 0, 0);
      }
    }
  }
  int ks = kb > C ? kb : C;
  for(int ak = ks; ak < ke; ak += 32){
    bf16x8 a[4];
    #pragma unroll
    for(int r = 0; r < 4; ++r) a[r] = *(const bf16x8*)(A + abase + (size_t)r*16*AK + ak);
    const unsigned short* p = bcolp + (size_t)((C + ak) >> 3)*bstep;
    #pragma unroll
    for(int j = 0; j < 4; ++j){
      bf16x8 b = *(const bf16x8*)(p + j*128);
      #pragma unroll
      for(int r = 0; r < 4; ++r)
        acc[r][j] = __builtin_amdgcn_mfma_f32_16x16x32_bf16(a[r], b, acc[r][j], 0, 0, 0);
    }
  }
  float* o = out + (size_t)blockIdx.z*NN*COUT;
  #pragma unroll
  for(int r = 0; r < 4; ++r){
    int nb = n0 + r*16 + lg*4;
    #pragma unroll
    for(int j = 0; j < 4; ++j){
      int oc = c0 + j*16 + lr;
      #pragma unroll
      for(int q = 0; q < 4; ++q){
        int n = nb + q;
        if(n < NN) o[(size_t)n*COUT + oc] = acc[r][j][q];
      }
    }
  }
}

// ---------------- split-K reduce + bias + BN stats ----------------
template<int COUT, int SPLITS>
__global__ __launch_bounds__(COUT)
void k_reduce(const float* __restrict__ P, const float* __restrict__ bias,
              float* __restrict__ h, float* __restrict__ sums){
  int c = threadIdx.x;
  float bs = bias[c];
  float s = 0.0f, s2 = 0.0f;
  for(int n = blockIdx.x; n < NN; n += gridDim.x){
    float v = bs;
    #pragma unroll
    for(int z = 0; z < SPLITS; ++z) v += P[(size_t)z*NN*COUT + (size_t)n*COUT + c];
    h[(size_t)n*COUT + c] = v;
    s += v; s2 += v*v;
  }
  atomicAdd(&sums[c], s);
  atomicAdd(&sums[COUT + c], s2);
}

// ---------------- LSTM activation (+bias) -> A1 [hi|lo] + fp8 key table ----------------
__global__ void k_act(const float* __restrict__ gates, const float* __restrict__ bias0,
                      unsigned short* __restrict__ A1, unsigned char* __restrict__ h1k8){
  int i = blockIdx.x*256 + threadIdx.x;
  if(i >= NN*FF) return;
  int n = i >> 7, j = i & 127;
  const float* g = gates + (size_t)n*384;
  float ig = g[j]       + bias0[j];
  float gg = g[128 + j] + bias0[128 + j];
  float og = g[256 + j] + bias0[256 + j];
  float c  = sigf(ig) * tanhf(gg);
  float hv = sigf(og) * tanhf(c);
  unsigned short hu = f2bf(hv);
  unsigned short lu = f2bf(hv - bf2f(hu));
  unsigned short* r = A1 + (size_t)n*768;
  r[j] = hu; r[128 + j] = lu;
  h1k8[i] = fold8(f2f8(hv));
}

// ---------------- binned CSR build ----------------
__global__ void k_bcount(const int* __restrict__ dst, int* __restrict__ gbcnt){
  __shared__ int h[NBUCK];
  for(int i = threadIdx.x; i < NBUCK; i += 256) h[i] = 0;
  __syncthreads();
  int e0 = blockIdx.x*2048;
  #pragma unroll
  for(int k = 0; k < 8; ++k){
    int e = e0 + threadIdx.x + k*256;
    if(e < NE) atomicAdd(&h[dst[e] >> 7], 1);
  }
  __syncthreads();
  for(int i = threadIdx.x; i < NBUCK; i += 256) if(h[i]) atomicAdd(&gbcnt[i], h[i]);
}
__global__ void k_bscan(const int* __restrict__ gbcnt, int* __restrict__ gbase,
                        int* __restrict__ excl){
  if(threadIdx.x == 0){
    int s = 0;
    for(int i = 0; i < NBUCK; ++i){ gbase[i] = s; s += gbcnt[i]; }
    excl[NSEG] = s;                 // sentinel == NE
  }
}
__global__ __launch_bounds__(512)
void k_binscat(const int* __restrict__ src, const int* __restrict__ dst,
               const int* __restrict__ et, const int* __restrict__ gbase,
               int* __restrict__ gcursor, unsigned* __restrict__ gstage){
  __shared__ unsigned stage[4096];
  __shared__ unsigned char stgb[4096];
  __shared__ int lcnt[NBUCK], lexc[NBUCK], lcur[NBUCK], gofs[NBUCK];
  int tid = threadIdx.x;
  for(int i = tid; i < NBUCK; i += 512) lcnt[i] = 0;
  __syncthreads();
  int e0 = blockIdx.x*4096;
  int b_[8]; unsigned v_[8];
  #pragma unroll
  for(int k = 0; k < 8; ++k){
    int e = e0 + tid + k*512;
    if(e < NE){
      int d = dst[e]; int b = d >> 7;
      b_[k] = b;
      v_[k] = ((unsigned)((((d & 127) << 2) | et[e])) << 16) | (unsigned)src[e];
      atomicAdd(&lcnt[b], 1);
    } else b_[k] = -1;
  }
  __syncthreads();
  if(tid == 0){
    int s = 0;
    for(int i = 0; i < NBUCK; ++i){ lexc[i] = s; s += lcnt[i]; }
  }
  __syncthreads();
  if(tid < NBUCK){
    lcur[tid] = lexc[tid];
    if(lcnt[tid]) gofs[tid] = atomicAdd(&gcursor[tid], lcnt[tid]);
  }
  __syncthreads();
  #pragma unroll
  for(int k = 0; k < 8; ++k){
    if(b_[k] >= 0){
      int p = atomicAdd(&lcur[b_[k]], 1);
      stage[p] = v_[k]; stgb[p] = (unsigned char)b_[k];
    }
  }
  __syncthreads();
  int ne = NE - e0; if(ne > 4096) ne = 4096;
  for(int i = tid; i < ne; i += 512){
    int b = stgb[i];
    gstage[gbase[b] + gofs[b] + (i - lexc[b])] = stage[i];
  }
}
__global__ __launch_bounds__(512)
void k_fine(const unsigned* __restrict__ gstage, const int* __restrict__ gbcnt,
            const int* __restrict__ gbase, int* __restrict__ excl,
            unsigned short* __restrict__ elist){
  __shared__ int cnt[512], scn[512], cur[512];
  int t = threadIdx.x, bk = blockIdx.x;
  cnt[t] = 0;
  __syncthreads();
  int gB = gbase[bk], cE = gbcnt[bk];
  for(int i = t; i < cE; i += 512) atomicAdd(&cnt[gstage[gB + i] >> 16], 1);
  __syncthreads();
  scn[t] = cnt[t]; __syncthreads();
  for(int off = 1; off < 512; off <<= 1){
    int add = (t >= off) ? scn[t - off] : 0;
    __syncthreads();
    scn[t] += add;
    __syncthreads();
  }
  int ex = scn[t] - cnt[t];
  cur[t] = ex;
  int s = bk*512 + t;
  if(s < NSEG) excl[s] = gB + ex;
  __syncthreads();
  for(int i = t; i < cE; i += 512){
    unsigned v = gstage[gB + i];
    int p = atomicAdd(&cur[v >> 16], 1);
    elist[gB + p] = (unsigned short)(v & 0xFFFFu);
  }
}

// ---------------- per-segment max over fp8 keys ----------------
// coalesced elist + shuffle-broadcast edge ids + LDS decode LUT
template<int C, int AK>
__global__ __launch_bounds__(256)
void k_agg8(const unsigned char* __restrict__ keys, const unsigned short* __restrict__ elist,
            const int* __restrict__ excl, unsigned short* __restrict__ A){
  constexpr int NW = C/128;           // uints per lane (1 or 2)
  __shared__ unsigned short slut[256];
  if(threadIdx.x < 256) slut[threadIdx.x] = key8tobf((unsigned char)threadIdx.x);
  __syncthreads();
  int seg  = blockIdx.x*4 + (threadIdx.x >> 6);
  int l = threadIdx.x & 63, half = l >> 5, cl = l & 31;
  int start = excl[seg];
  int cnt   = excl[seg + 1] - start;
  const unsigned char* kp = keys + cl*(NW*4);
  unsigned me0 = 0, mo0 = 0, me1 = 0, mo1 = 0;
  for(int bb = 0; bb < cnt; bb += 64){
    int m = cnt - bb; if(m > 64) m = 64;
    int ee = (int)elist[start + bb + l];     // coalesced: 64 edge ids in one load
    int k = 0;
    for(; k + 8 <= m; k += 8){
      int e0 = __shfl(ee, k + half);
      int e1 = __shfl(ee, k + 2 + half);
      int e2 = __shfl(ee, k + 4 + half);
      int e3 = __shfl(ee, k + 6 + half);
      if constexpr(NW == 1){
        unsigned v0 = *(const unsigned*)(kp + (size_t)e0*C);
        unsigned v1 = *(const unsigned*)(kp + (size_t)e1*C);
        unsigned v2 = *(const unsigned*)(kp + (size_t)e2*C);
        unsigned v3 = *(const unsigned*)(kp + (size_t)e3*C);
        acc8(v0, me0, mo0); acc8(v1, me0, mo0);
        acc8(v2, me0, mo0); acc8(v3, me0, mo0);
      } else {
        uint2 v0 = *(const uint2*)(kp + (size_t)e0*C);
        uint2 v1 = *(const uint2*)(kp + (size_t)e1*C);
        uint2 v2 = *(const uint2*)(kp + (size_t)e2*C);
        uint2 v3 = *(const uint2*)(kp + (size_t)e3*C);
        acc8(v0.x, me0, mo0); acc8(v0.y, me1, mo1);
        acc8(v1.x, me0, mo0); acc8(v1.y, me1, mo1);
        acc8(v2.x, me0, mo0); acc8(v2.y, me1, mo1);
        acc8(v3.x, me0, mo0); acc8(v3.y, me1, mo1);
      }
    }
    for(; k + 2 <= m; k += 2){
      int e = __shfl(ee, k + half);
      if constexpr(NW == 1){
        acc8(*(const unsigned*)(kp + (size_t)e*C), me0, mo0);
      } else {
        uint2 v = *(const uint2*)(kp + (size_t)e*C);
        acc8(v.x, me0, mo0); acc8(v.y, me1, mo1);
      }
    }
    if(k < m){
      int e = __shfl(ee, k);
      if(half == 0){
        if constexpr(NW == 1){
          acc8(*(const unsigned*)(kp + (size_t)e*C), me0, mo0);
        } else {
          uint2 v = *(const uint2*)(kp + (size_t)e*C);
          acc8(v.x, me0, mo0); acc8(v.y, me1, mo1);
        }
      }
    }
  }
  // merge halves (lanes l and l^32 hold the same channels)
  me0 = maxsplit(me0, (unsigned)__shfl_xor((int)me0, 32));
  mo0 = maxsplit(mo0, (unsigned)__shfl_xor((int)mo0, 32));
  if constexpr(NW == 2){
    me1 = maxsplit(me1, (unsigned)__shfl_xor((int)me1, 32));
    mo1 = maxsplit(mo1, (unsigned)__shfl_xor((int)mo1, 32));
  }
  if(half == 0){
    int n = seg >> 2, t = seg & 3;
    unsigned short* op = A + (size_t)n*AK + 2*C + t*C + cl*(NW*4);
    // channels per uint j: [j*4+0]=me.lo, [j*4+1]=mo.lo, [j*4+2]=me.hi, [j*4+3]=mo.hi
    if constexpr(NW == 1){
      typedef unsigned short u4 __attribute__((ext_vector_type(4)));
      u4 o;
      o[0] = cnt ? slut[me0 & 0xFF] : (unsigned short)0;
      o[1] = cnt ? slut[mo0 & 0xFF] : (unsigned short)0;
      o[2] = cnt ? slut[(me0 >> 16) & 0xFF] : (unsigned short)0;
      o[3] = cnt ? slut[(mo0 >> 16) & 0xFF] : (unsigned short)0;
      *(u4*)op = o;
    } else {
      typedef unsigned short u8v __attribute__((ext_vector_type(8)));
      u8v o;
      o[0] = cnt ? slut[me0 & 0xFF] : (unsigned short)0;
      o[1] = cnt ? slut[mo0 & 0xFF] : (unsigned short)0;
      o[2] = cnt ? slut[(me0 >> 16) & 0xFF] : (unsigned short)0;
      o[3] = cnt ? slut[(mo0 >> 16) & 0xFF] : (unsigned short)0;
      o[4] = cnt ? slut[me1 & 0xFF] : (unsigned short)0;
      o[5] = cnt ? slut[mo1 & 0xFF] : (unsigned short)0;
      o[6] = cnt ? slut[(me1 >> 16) & 0xFF] : (unsigned short)0;
      o[7] = cnt ? slut[(mo1 >> 16) & 0xFF] : (unsigned short)0;
      *(u8v*)op = o;
    }
  }
}

// ---------------- BN1(inline finalize) + ReLU -> A2 [hi|lo] + fp8 key table ----------------
__global__ void k_bnrp(const float* __restrict__ h2, const float* __restrict__ sums,
                       const float* __restrict__ g, const float* __restrict__ bb,
                       unsigned short* __restrict__ A2, unsigned char* __restrict__ h2k8){
  int i = blockIdx.x*256 + threadIdx.x;
  if(i >= NN*FF2) return;
  int n = i >> 8, c = i & 255;
  float mean = sums[c] * (1.0f/NN);
  float var  = sums[256 + c] * (1.0f/NN) - mean*mean;
  float scale = g[c] / sqrtf(var + EPSBN);
  float shift = bb[c] - mean*scale;
  float v = fmaxf(h2[i]*scale + shift, 0.0f);
  unsigned short hu = f2bf(v);
  unsigned short lu = f2bf(v - bf2f(hu));
  unsigned short* r = A2 + (size_t)n*1536;
  r[c] = hu; r[256 + c] = lu;
  h2k8[i] = fold8(f2f8(v));
}

// ---------------- BN2(inline finalize) + sigmoid(x-10), in place ----------------
__global__ void k_bnsig(float* __restrict__ h, const float* __restrict__ sums,
                        const float* __restrict__ g, const float* __restrict__ bb){
  int i = blockIdx.x*256 + threadIdx.x;
  if(i >= NN*FF) return;
  int c = i & 127;
  float mean = sums[c] * (1.0f/NN);
  float var  = sums[128 + c] * (1.0f/NN) - mean*mean;
  float scale = g[c] / sqrtf(var + EPSBN);
  float shift = bb[c] - mean*scale;
  float v = h[i]*scale + shift - 10.0f;
  h[i] = 1.0f/(1.0f + expf(-v));
}

// ---------------- launch ----------------
extern "C" void kernel_launch(void* const* d_in, const int* in_sizes, int n_in,
                              void* d_out, int out_size, void* d_ws, size_t ws_size,
                              hipStream_t stream){
  (void)in_sizes; (void)n_in; (void)out_size; (void)ws_size;
  const float* x       = (const float*)d_in[0];
  const float* tbl     = (const float*)d_in[1];
  const int*   eidx    = (const int*)  d_in[2];
  const int*   etype   = (const int*)  d_in[3];
  const float* w_ih    = (const float*)d_in[4];
  const float* b_ih    = (const float*)d_in[6];
  const float* b_hh    = (const float*)d_in[7];
  const float* conv1_w = (const float*)d_in[8];
  const float* conv1_b = (const float*)d_in[9];
  const float* conv2_w = (const float*)d_in[10];
  const float* conv2_b = (const float*)d_in[11];
  const float* lin1_w  = (const float*)d_in[12];
  const float* lin1_b  = (const float*)d_in[13];
  const float* lin2_w  = (const float*)d_in[14];
  const float* lin2_b  = (const float*)d_in[15];
  const float* bn1_g   = (const float*)d_in[16];
  const float* bn1_b   = (const float*)d_in[17];
  const float* bn2_g   = (const float*)d_in[18];
  const float* bn2_b   = (const float*)d_in[19];
  float* out = (float*)d_out;

  char* base = (char*)d_ws;
  size_t off = 0;
  auto alloc = [&](size_t bytes){ char* p = base + off; off = (off + bytes + 255) & ~(size_t)255; return p; };

  unsigned short* A0 = (unsigned short*)alloc((size_t)MP * 256 * 2);   // 10.29 MB
  unsigned short* A1 = (unsigned short*)alloc((size_t)MP * 768 * 2);   // 30.87 MB
  unsigned short* A2 = (unsigned short*)alloc((size_t)MP * 1536 * 2);  // 61.73 MB
  float* h2raw = (float*)alloc((size_t)NN * 256 * 4);                  // 20.48 MB
  unsigned char* h1k8 = (unsigned char*)alloc((size_t)NN * 128);       // 2.56 MB
  unsigned char* h2k8 = (unsigned char*)alloc((size_t)NN * 256);       // 5.12 MB
  unsigned short* Bp0 = (unsigned short*)alloc((size_t)384 * 384 * 2);
  unsigned short* Bp1 = (unsigned short*)alloc((size_t)896 * 256 * 2);
  unsigned short* Bp2 = (unsigned short*)alloc((size_t)1792 * 128 * 2);
  float* bias0 = (float*)alloc(384 * 4);
  float* bias1 = (float*)alloc(256 * 4);
  float* bias2 = (float*)alloc(128 * 4);
  int* excl    = (int*)alloc((NSEG + 1) * 4);
  float* bnsum1 = (float*)alloc(512 * 4);
  float* bnsum2 = (float*)alloc(256 * 4);
  int* gbcnt   = (int*)alloc(NBUCK * 4);
  int* gbase   = (int*)alloc(NBUCK * 4);
  int* gcursor = (int*)alloc(NBUCK * 4);
  unsigned* gstage = (unsigned*)alloc((size_t)NE * 4);
  unsigned short* elist = (unsigned short*)alloc((size_t)NE * 2 + 256); // +pad for coalesced tail

  // aliases (lifetimes disjoint)
  float* gates = (float*)A2;     // MP*384*4 = 30.9 MB, dead after k_act
  float* P1    = (float*)A2;     // 2*NN*256*4 = 41 MB, dead before k_bnrp writes A2
  float* P2    = (float*)A0;     // 4*NN*128*4 = 41 MB, spans A0+A1 (both dead by gemm2)

  const int* src = eidx;
  const int* dst = eidx + NE;

  // fused prep: pack B0/B1/B2, biases, zero counters/bn sums
  k_prep<<<(PB2 + 1850 + 255)/256, 256, 0, stream>>>(
      w_ih, lin1_w, conv1_w, lin2_w, conv2_w,
      b_ih, b_hh, lin1_b, conv1_b, lin2_b, conv2_b,
      Bp0, Bp1, Bp2, bias0, bias1, bias2, gbcnt, gcursor, bnsum1, bnsum2);

  k_osc_pack<<<(NN*FF + 255)/256, 256, 0, stream>>>(x, tbl, A0);

  // binned CSR build
  k_bcount<<<(NE + 2047)/2048, 256, 0, stream>>>(dst, gbcnt);
  k_bscan<<<1, 64, 0, stream>>>(gbcnt, gbase, excl);
  k_binscat<<<(NE + 4095)/4096, 512, 0, stream>>>(src, dst, etype, gbase, gcursor, gstage);
  k_fine<<<NBUCK, 512, 0, stream>>>(gstage, gbcnt, gbase, excl, elist);

  // LSTM: gates (i,g,o) = A0 x B0; bias+activation fused in k_act
  k_gemm<128, 384, 1, 256><<<dim3(157, 3, 1), 256, 0, stream>>>(A0, Bp0, gates);
  k_act<<<(NN*FF + 255)/256, 256, 0, stream>>>(gates, bias0, A1, h1k8);

  // layer 1
  k_agg8<128, 768><<<NSEG/4, 256, 0, stream>>>(h1k8, elist, excl, A1);
  k_gemm<128, 256, 2, 768><<<dim3(157, 2, 2), 256, 0, stream>>>(A1, Bp1, P1);
  k_reduce<256, 2><<<256, 256, 0, stream>>>(P1, bias1, h2raw, bnsum1);
  k_bnrp<<<(NN*FF2 + 255)/256, 256, 0, stream>>>(h2raw, bnsum1, bn1_g, bn1_b, A2, h2k8);

  // layer 2
  k_agg8<256, 1536><<<NSEG/4, 256, 0, stream>>>(h2k8, elist, excl, A2);
  k_gemm<256, 128, 4, 1536><<<dim3(157, 1, 4), 256, 0, stream>>>(A2, Bp2, P2);
  k_reduce<128, 4><<<256, 128, 0, stream>>>(P2, bias2, out, bnsum2);
  k_bnsig<<<(NN*FF + 255)/256, 256, 0, stream>>>(out, bnsum2, bn2_g, bn2_b);
}